// Round 6
// baseline (1055.425 us; speedup 1.0000x reference)
//
#include <hip/hip_runtime.h>

// GraphRegressorV2 — round 5 (resubmit after broker timeout): packed 16B CSR
// entry (kills scatter write amplification), gather edge_attr by eid
// (L3-resident), node_msg/x_emb bf16, fused proj+gemm0 and fused agg+gemm
// layers (xin never hits HBM).

typedef float f32x4 __attribute__((ext_vector_type(4)));
typedef short s16x8 __attribute__((ext_vector_type(8)));

__device__ __forceinline__ unsigned short f2bf(float f) {
  union { float f; unsigned u; } v{f};
  unsigned r = v.u + 0x7fff + ((v.u >> 16) & 1);  // RNE
  return (unsigned short)(r >> 16);
}
__device__ __forceinline__ float bf2f(unsigned short s) {
  union { unsigned u; float f; } v{(unsigned)s << 16};
  return v.f;
}
__device__ __forceinline__ float blo(unsigned u) {
  union { unsigned x; float f; } v{u << 16};
  return v.f;
}
__device__ __forceinline__ float bhi(unsigned u) {
  union { unsigned x; float f; } v{u & 0xffff0000u};
  return v.f;
}
__device__ __forceinline__ unsigned pk2(float a, float b) {
  return (unsigned)f2bf(a) | ((unsigned)f2bf(b) << 16);
}

// ---------------- node embedding -> bf16 x0 ----------------
__global__ void node_embed_kernel(const float* __restrict__ x,
                                  const float* __restrict__ coord_W, const float* __restrict__ coord_b,
                                  const float* __restrict__ node_W, const float* __restrict__ node_b,
                                  short* __restrict__ x0, int N) {
  int tid = threadIdx.x;
  int node = blockIdx.x * 8 + (tid >> 5);
  if (node >= N) return;
  int ch0 = (tid & 31) * 8;
  const float* xr = x + (size_t)node * 9;
  float a[8];
  if (ch0 < 128) {
    float4 b0 = *(const float4*)&coord_b[ch0];
    float4 b1 = *(const float4*)&coord_b[ch0 + 4];
    a[0]=b0.x; a[1]=b0.y; a[2]=b0.z; a[3]=b0.w; a[4]=b1.x; a[5]=b1.y; a[6]=b1.z; a[7]=b1.w;
#pragma unroll
    for (int k = 0; k < 3; k++) {
      float xv = xr[k];
      float4 w0 = *(const float4*)&coord_W[k * 128 + ch0];
      float4 w1 = *(const float4*)&coord_W[k * 128 + ch0 + 4];
      a[0] = fmaf(xv, w0.x, a[0]); a[1] = fmaf(xv, w0.y, a[1]);
      a[2] = fmaf(xv, w0.z, a[2]); a[3] = fmaf(xv, w0.w, a[3]);
      a[4] = fmaf(xv, w1.x, a[4]); a[5] = fmaf(xv, w1.y, a[5]);
      a[6] = fmaf(xv, w1.z, a[6]); a[7] = fmaf(xv, w1.w, a[7]);
    }
  } else {
    int c0 = ch0 - 128;
    float4 b0 = *(const float4*)&node_b[c0];
    float4 b1 = *(const float4*)&node_b[c0 + 4];
    a[0]=b0.x; a[1]=b0.y; a[2]=b0.z; a[3]=b0.w; a[4]=b1.x; a[5]=b1.y; a[6]=b1.z; a[7]=b1.w;
#pragma unroll
    for (int k = 0; k < 6; k++) {
      float xv = xr[3 + k];
      float4 w0 = *(const float4*)&node_W[k * 128 + c0];
      float4 w1 = *(const float4*)&node_W[k * 128 + c0 + 4];
      a[0] = fmaf(xv, w0.x, a[0]); a[1] = fmaf(xv, w0.y, a[1]);
      a[2] = fmaf(xv, w0.z, a[2]); a[3] = fmaf(xv, w0.w, a[3]);
      a[4] = fmaf(xv, w1.x, a[4]); a[5] = fmaf(xv, w1.y, a[5]);
      a[6] = fmaf(xv, w1.z, a[6]); a[7] = fmaf(xv, w1.w, a[7]);
    }
  }
  uint4 o;
  o.x = pk2(fmaxf(a[0], 0.f), fmaxf(a[1], 0.f));
  o.y = pk2(fmaxf(a[2], 0.f), fmaxf(a[3], 0.f));
  o.z = pk2(fmaxf(a[4], 0.f), fmaxf(a[5], 0.f));
  o.w = pk2(fmaxf(a[6], 0.f), fmaxf(a[7], 0.f));
  *(uint4*)&x0[(size_t)node * 256 + ch0] = o;
}

// ---------------- CSR build ----------------
__global__ void count_kernel(const int* __restrict__ col, int* __restrict__ cnt, int E) {
  int e = blockIdx.x * 256 + threadIdx.x;
  if (e < E) atomicAdd(&cnt[col[e]], 1);
}

__global__ void breduce_kernel(const int* __restrict__ cnt, int* __restrict__ partials, int N) {
  __shared__ int red[256];
  int t = threadIdx.x;
  int i = blockIdx.x * 256 + t;
  int v = (i < N) ? cnt[i] : 0;
  red[t] = v;
  __syncthreads();
  for (int off = 128; off; off >>= 1) {
    if (t < off) red[t] += red[t + off];
    __syncthreads();
  }
  if (t == 0) partials[blockIdx.x] = red[0];
}

__global__ void scan_partials_kernel(int* __restrict__ partials, int nb) {
  __shared__ int s[1024];
  int t = threadIdx.x;
  for (int i = t; i < nb; i += 256) s[i] = partials[i];
  __syncthreads();
  if (t == 0) {
    int run = 0;
    for (int i = 0; i < nb; i++) { int c = s[i]; s[i] = run; run += c; }
  }
  __syncthreads();
  for (int i = t; i < nb; i += 256) partials[i] = s[i];
}

__global__ void scan_apply_kernel(const int* __restrict__ cnt, const int* __restrict__ partials,
                                  int* __restrict__ rowstart, float* __restrict__ dnorm,
                                  int* __restrict__ cursor, int N) {
  __shared__ int red[256];
  int t = threadIdx.x;
  int i = blockIdx.x * 256 + t;
  int v = (i < N) ? cnt[i] : 0;
  red[t] = v;
  __syncthreads();
  for (int off = 1; off < 256; off <<= 1) {
    int x = (t >= off) ? red[t - off] : 0;
    __syncthreads();
    red[t] += x;
    __syncthreads();
  }
  if (i < N) {
    int ex = red[t] - v + partials[blockIdx.x];
    rowstart[i] = ex;
    dnorm[i] = rsqrtf((float)(v + 1));  // +1 self-loop
    cursor[i] = 0;
    if (i == N - 1) rowstart[N] = ex + v;
  }
}

// one packed 16B write per edge: {eid, row, efac_bits, 0}
__global__ void scatter_kernel(const int* __restrict__ row, const int* __restrict__ col,
                               const int* __restrict__ rowstart, int* __restrict__ cursor,
                               const float* __restrict__ dnorm,
                               int4* __restrict__ pk, int E) {
  int e = blockIdx.x * 256 + threadIdx.x;
  if (e >= E) return;
  int c = col[e], r = row[e];
  int p = atomicAdd(&cursor[c], 1);
  int slot = rowstart[c] + p;
  pk[slot] = make_int4(e, r, __float_as_int(dnorm[r] * dnorm[c]), 0);
}

// ---------------- weight transpose+bf16 ----------------
__global__ void wt_kernel(const float* __restrict__ gcn_W, const float* __restrict__ proj_W,
                          short* __restrict__ gcnWt, short* __restrict__ projWt) {
  int idx = blockIdx.x * 256 + threadIdx.x;
  if (idx < 3 * 65536) {
    int l = idx >> 16, r = idx & 65535, n = r >> 8, k = r & 255;
    gcnWt[idx] = (short)f2bf(gcn_W[l * 65536 + k * 256 + n]);
  } else {
    int j = idx - 3 * 65536;  // n*128+k
    int n = j >> 7, k = j & 127;
    projWt[j] = (short)f2bf(proj_W[k * 256 + n]);
  }
}

// ---------------- edge message aggregate (gather edge_attr by eid) ---------
__global__ void edge_msg_kernel(const float* __restrict__ edge_attr,
                                const int4* __restrict__ pk,
                                const int* __restrict__ rowstart,
                                const float* __restrict__ edge_W, const float* __restrict__ edge_b,
                                short* __restrict__ msg128, int N) {
  int node = blockIdx.x;
  int ch = threadIdx.x;  // 128
  __shared__ float sW[8 * 128];
  __shared__ float sb[128];
  for (int i = ch; i < 8 * 128; i += 128) sW[i] = edge_W[i];
  sb[ch] = edge_b[ch];
  __syncthreads();
  float acc = 0.f;
  int s0 = rowstart[node], s1 = rowstart[node + 1];
  for (int s = s0; s < s1; s++) {
    int eid = pk[s].x;
    const float4* ea = (const float4*)(edge_attr + (size_t)eid * 8);
    float4 e0 = ea[0], e1 = ea[1];
    float t = sb[ch];
    t = fmaf(e0.x, sW[0 * 128 + ch], t);
    t = fmaf(e0.y, sW[1 * 128 + ch], t);
    t = fmaf(e0.z, sW[2 * 128 + ch], t);
    t = fmaf(e0.w, sW[3 * 128 + ch], t);
    t = fmaf(e1.x, sW[4 * 128 + ch], t);
    t = fmaf(e1.y, sW[5 * 128 + ch], t);
    t = fmaf(e1.z, sW[6 * 128 + ch], t);
    t = fmaf(e1.w, sW[7 * 128 + ch], t);
    acc += fmaxf(t, 0.f);
  }
  msg128[(size_t)node * 128 + ch] = (short)f2bf(acc);
}

// ---------------- fused proj + gemm0 ----------------
// node_msg = msg128@projW + cnt*proj_b (write bf16); xin0 = x0+node_msg (LDS);
// h0 = xin0 @ W0.
__global__ void __launch_bounds__(256) fused_proj_gemm(
    const short* __restrict__ msg128, const short* __restrict__ projWt,
    const float* __restrict__ proj_b, const int* __restrict__ cnt,
    const short* __restrict__ x0, const short* __restrict__ W0t,
    short* __restrict__ node_msg, short* __restrict__ hout, int N) {
  __shared__ short As[64][136];
  __shared__ short Xs[64][264];
  int tid = threadIdx.x;
  int n0 = blockIdx.x * 64;
  for (int i = tid; i < 64 * 32; i += 256) {
    int r = i >> 5, c4 = (i & 31) << 2;
    int n = n0 + r;
    uint2 v = make_uint2(0, 0);
    if (n < N) v = *(const uint2*)&msg128[(size_t)n * 128 + c4];
    *(uint2*)&As[r][c4] = v;
  }
  __syncthreads();
  int wave = tid >> 6, lane = tid & 63;
  int mrow = wave * 16 + (lane & 15);
  int kgrp = (lane >> 4) * 8;
  f32x4 acc[16];
#pragma unroll
  for (int i = 0; i < 16; i++) acc[i] = (f32x4){0.f, 0.f, 0.f, 0.f};
  {
    const short* wbase = projWt + (size_t)(lane & 15) * 128 + kgrp;
#pragma unroll
    for (int kk = 0; kk < 4; kk++) {
      s16x8 a = *(const s16x8*)&As[mrow][kk * 32 + kgrp];
#pragma unroll
      for (int nf = 0; nf < 16; nf++) {
        s16x8 b = *(const s16x8*)&wbase[(size_t)nf * 16 * 128 + kk * 32];
        acc[nf] = __builtin_amdgcn_mfma_f32_16x16x32_bf16(a, b, acc[nf], 0, 0, 0);
      }
    }
  }
  int orow0 = wave * 16 + (lane >> 4) * 4;
  int ocol = lane & 15;
#pragma unroll
  for (int r = 0; r < 4; r++) {
    int i = orow0 + r;
    int n = n0 + i;
    if (n < N) {
      float cn = (float)cnt[n];
#pragma unroll
      for (int nf = 0; nf < 16; nf++) {
        int c = nf * 16 + ocol;
        float v = acc[nf][r] + cn * proj_b[c];
        unsigned short nm = f2bf(v);
        node_msg[(size_t)n * 256 + c] = (short)nm;
        Xs[i][c] = (short)f2bf(bf2f(nm) + bf2f((unsigned short)x0[(size_t)n * 256 + c]));
      }
    } else {
#pragma unroll
      for (int nf = 0; nf < 16; nf++) Xs[i][nf * 16 + ocol] = 0;
    }
  }
  __syncthreads();
#pragma unroll
  for (int i = 0; i < 16; i++) acc[i] = (f32x4){0.f, 0.f, 0.f, 0.f};
  {
    const short* wbase = W0t + (size_t)(lane & 15) * 256 + kgrp;
#pragma unroll
    for (int kk = 0; kk < 8; kk++) {
      s16x8 a = *(const s16x8*)&Xs[mrow][kk * 32 + kgrp];
#pragma unroll
      for (int nf = 0; nf < 16; nf++) {
        s16x8 b = *(const s16x8*)&wbase[(size_t)nf * 16 * 256 + kk * 32];
        acc[nf] = __builtin_amdgcn_mfma_f32_16x16x32_bf16(a, b, acc[nf], 0, 0, 0);
      }
    }
  }
#pragma unroll
  for (int nf = 0; nf < 16; nf++) {
#pragma unroll
    for (int r = 0; r < 4; r++) {
      int n = n0 + orow0 + r;
      if (n < N) hout[(size_t)n * 256 + nf * 16 + ocol] = (short)f2bf(acc[nf][r]);
    }
  }
}

// ---------------- fused agg + gemm (layers 1,2) ----------------
// xin = relu(agg(hprev)+bprev) + node_msg (built in LDS); hnext = xin @ Wl.
__global__ void __launch_bounds__(256) fused_layer(
    const short* __restrict__ hprev, const int4* __restrict__ pk,
    const int* __restrict__ rowstart, const float* __restrict__ dnorm,
    const float* __restrict__ bprev, const short* __restrict__ node_msg,
    const short* __restrict__ Wt, short* __restrict__ hnext, int N) {
  __shared__ short Xs[64][264];
  int tid = threadIdx.x;
  int n0 = blockIdx.x * 64;
  int wave = tid >> 6, lane = tid & 63;
  int ch0 = lane << 2;
  float4 bv = *(const float4*)&bprev[ch0];
  for (int i = wave * 16; i < wave * 16 + 16; i++) {
    int n = n0 + i;
    if (n >= N) {
      *(uint2*)&Xs[i][ch0] = make_uint2(0, 0);
      continue;
    }
    size_t rowb = (size_t)n * 256 + ch0;
    float dn = dnorm[n];
    float wgt = dn * dn;
    uint2 hv = *(const uint2*)&hprev[rowb];
    float a0 = blo(hv.x) * wgt, a1 = bhi(hv.x) * wgt;
    float a2 = blo(hv.y) * wgt, a3 = bhi(hv.y) * wgt;
    int s = rowstart[n], s1 = rowstart[n + 1];
    for (; s + 4 <= s1; s += 4) {
      int4 p0 = pk[s], p1 = pk[s + 1], p2 = pk[s + 2], p3 = pk[s + 3];
      float f0 = __int_as_float(p0.z), f1 = __int_as_float(p1.z);
      float f2 = __int_as_float(p2.z), f3 = __int_as_float(p3.z);
      uint2 v0 = *(const uint2*)&hprev[(size_t)p0.y * 256 + ch0];
      uint2 v1 = *(const uint2*)&hprev[(size_t)p1.y * 256 + ch0];
      uint2 v2 = *(const uint2*)&hprev[(size_t)p2.y * 256 + ch0];
      uint2 v3 = *(const uint2*)&hprev[(size_t)p3.y * 256 + ch0];
      a0 = fmaf(blo(v0.x), f0, a0); a1 = fmaf(bhi(v0.x), f0, a1);
      a2 = fmaf(blo(v0.y), f0, a2); a3 = fmaf(bhi(v0.y), f0, a3);
      a0 = fmaf(blo(v1.x), f1, a0); a1 = fmaf(bhi(v1.x), f1, a1);
      a2 = fmaf(blo(v1.y), f1, a2); a3 = fmaf(bhi(v1.y), f1, a3);
      a0 = fmaf(blo(v2.x), f2, a0); a1 = fmaf(bhi(v2.x), f2, a1);
      a2 = fmaf(blo(v2.y), f2, a2); a3 = fmaf(bhi(v2.y), f2, a3);
      a0 = fmaf(blo(v3.x), f3, a0); a1 = fmaf(bhi(v3.x), f3, a1);
      a2 = fmaf(blo(v3.y), f3, a2); a3 = fmaf(bhi(v3.y), f3, a3);
    }
    for (; s < s1; s++) {
      int4 p = pk[s];
      float f = __int_as_float(p.z);
      uint2 v = *(const uint2*)&hprev[(size_t)p.y * 256 + ch0];
      a0 = fmaf(blo(v.x), f, a0); a1 = fmaf(bhi(v.x), f, a1);
      a2 = fmaf(blo(v.y), f, a2); a3 = fmaf(bhi(v.y), f, a3);
    }
    uint2 mv = *(const uint2*)&node_msg[rowb];
    float y0 = fmaxf(a0 + bv.x, 0.f) + blo(mv.x);
    float y1 = fmaxf(a1 + bv.y, 0.f) + bhi(mv.x);
    float y2 = fmaxf(a2 + bv.z, 0.f) + blo(mv.y);
    float y3 = fmaxf(a3 + bv.w, 0.f) + bhi(mv.y);
    uint2 o;
    o.x = pk2(y0, y1);
    o.y = pk2(y2, y3);
    *(uint2*)&Xs[i][ch0] = o;
  }
  __syncthreads();
  int mrow = wave * 16 + (lane & 15);
  int kgrp = (lane >> 4) * 8;
  f32x4 acc[16];
#pragma unroll
  for (int i = 0; i < 16; i++) acc[i] = (f32x4){0.f, 0.f, 0.f, 0.f};
  const short* wbase = Wt + (size_t)(lane & 15) * 256 + kgrp;
#pragma unroll
  for (int kk = 0; kk < 8; kk++) {
    s16x8 a = *(const s16x8*)&Xs[mrow][kk * 32 + kgrp];
#pragma unroll
    for (int nf = 0; nf < 16; nf++) {
      s16x8 b = *(const s16x8*)&wbase[(size_t)nf * 16 * 256 + kk * 32];
      acc[nf] = __builtin_amdgcn_mfma_f32_16x16x32_bf16(a, b, acc[nf], 0, 0, 0);
    }
  }
  int orow0 = wave * 16 + (lane >> 4) * 4;
  int ocol = lane & 15;
#pragma unroll
  for (int nf = 0; nf < 16; nf++) {
#pragma unroll
    for (int r = 0; r < 4; r++) {
      int n = n0 + orow0 + r;
      if (n < N) hnext[(size_t)n * 256 + nf * 16 + ocol] = (short)f2bf(acc[nf][r]);
    }
  }
}

// ---------------- final aggregate -> x_emb bf16 + scores ----------------
__global__ void __launch_bounds__(256) final_agg_kernel(
    const short* __restrict__ h, const int4* __restrict__ pk,
    const int* __restrict__ rowstart, const float* __restrict__ dnorm,
    const float* __restrict__ b, short* __restrict__ x_emb,
    const float* __restrict__ attn_w, const float* __restrict__ attn_b,
    float* __restrict__ scores, int N) {
  int lane = threadIdx.x & 63;
  int node = blockIdx.x * 4 + (threadIdx.x >> 6);
  if (node >= N) return;
  int ch0 = lane << 2;
  size_t rowb = (size_t)node * 256 + ch0;
  float dn = dnorm[node];
  float wgt = dn * dn;
  uint2 hv = *(const uint2*)&h[rowb];
  float a0 = blo(hv.x) * wgt, a1 = bhi(hv.x) * wgt;
  float a2 = blo(hv.y) * wgt, a3 = bhi(hv.y) * wgt;
  int s = rowstart[node], s1 = rowstart[node + 1];
  for (; s + 4 <= s1; s += 4) {
    int4 p0 = pk[s], p1 = pk[s + 1], p2 = pk[s + 2], p3 = pk[s + 3];
    float f0 = __int_as_float(p0.z), f1 = __int_as_float(p1.z);
    float f2 = __int_as_float(p2.z), f3 = __int_as_float(p3.z);
    uint2 v0 = *(const uint2*)&h[(size_t)p0.y * 256 + ch0];
    uint2 v1 = *(const uint2*)&h[(size_t)p1.y * 256 + ch0];
    uint2 v2 = *(const uint2*)&h[(size_t)p2.y * 256 + ch0];
    uint2 v3 = *(const uint2*)&h[(size_t)p3.y * 256 + ch0];
    a0 = fmaf(blo(v0.x), f0, a0); a1 = fmaf(bhi(v0.x), f0, a1);
    a2 = fmaf(blo(v0.y), f0, a2); a3 = fmaf(bhi(v0.y), f0, a3);
    a0 = fmaf(blo(v1.x), f1, a0); a1 = fmaf(bhi(v1.x), f1, a1);
    a2 = fmaf(blo(v1.y), f1, a2); a3 = fmaf(bhi(v1.y), f1, a3);
    a0 = fmaf(blo(v2.x), f2, a0); a1 = fmaf(bhi(v2.x), f2, a1);
    a2 = fmaf(blo(v2.y), f2, a2); a3 = fmaf(bhi(v2.y), f2, a3);
    a0 = fmaf(blo(v3.x), f3, a0); a1 = fmaf(bhi(v3.x), f3, a1);
    a2 = fmaf(blo(v3.y), f3, a2); a3 = fmaf(bhi(v3.y), f3, a3);
  }
  for (; s < s1; s++) {
    int4 p = pk[s];
    float f = __int_as_float(p.z);
    uint2 v = *(const uint2*)&h[(size_t)p.y * 256 + ch0];
    a0 = fmaf(blo(v.x), f, a0); a1 = fmaf(bhi(v.x), f, a1);
    a2 = fmaf(blo(v.y), f, a2); a3 = fmaf(bhi(v.y), f, a3);
  }
  float4 bv = *(const float4*)&b[ch0];
  a0 += bv.x; a1 += bv.y; a2 += bv.z; a3 += bv.w;
  uint2 o;
  o.x = pk2(a0, a1);
  o.y = pk2(a2, a3);
  *(uint2*)&x_emb[rowb] = o;
  float4 aw = *(const float4*)&attn_w[ch0];
  float p = a0 * aw.x + a1 * aw.y + a2 * aw.z + a3 * aw.w;
#pragma unroll
  for (int off = 32; off; off >>= 1) p += __shfl_down(p, off);
  if (lane == 0) scores[node] = p + attn_b[0];
}

// ---------------- graph segment boundaries (batch sorted) ----------------
__global__ void gse_kernel(const int* __restrict__ batch, int* __restrict__ gs,
                           int* __restrict__ ge, int N) {
  int i = blockIdx.x * 256 + threadIdx.x;
  if (i >= N) return;
  int g = batch[i];
  if (i == 0) gs[g] = 0;
  else {
    int gp = batch[i - 1];
    if (gp != g) { gs[g] = i; ge[gp] = i - 1; }
  }
  if (i == N - 1) ge[g] = N - 1;
}

__global__ void softmax_kernel(const float* __restrict__ scores, const int* __restrict__ gs,
                               const int* __restrict__ ge, float* __restrict__ wnode) {
  int g = blockIdx.x;
  int tid = threadIdx.x;  // 256
  __shared__ float red[256];
  int s0 = gs[g], e1 = ge[g];
  if (s0 > e1) return;
  int s1 = e1 + 1;
  float m = -1e30f;
  for (int i = s0 + tid; i < s1; i += 256) m = fmaxf(m, scores[i]);
  red[tid] = m;
  __syncthreads();
  for (int off = 128; off; off >>= 1) {
    if (tid < off) red[tid] = fmaxf(red[tid], red[tid + off]);
    __syncthreads();
  }
  m = red[0];
  __syncthreads();
  float d = 0.f;
  for (int i = s0 + tid; i < s1; i += 256) d += expf(scores[i] - m);
  red[tid] = d;
  __syncthreads();
  for (int off = 128; off; off >>= 1) {
    if (tid < off) red[tid] += red[tid + off];
    __syncthreads();
  }
  float rd = 1.f / red[0];
  for (int i = s0 + tid; i < s1; i += 256) wnode[i] = expf(scores[i] - m) * rd;
}

__global__ void __launch_bounds__(256) pool_sum_kernel(
    const short* __restrict__ x_emb, const float* __restrict__ wnode,
    const int* __restrict__ batch, float* __restrict__ graph_emb, int N) {
  __shared__ int sb[256];
  __shared__ float sw[256];
  int ch = threadIdx.x;
  int i0 = blockIdx.x * 256;
  int lim = min(256, N - i0);
  if (ch < lim) { sb[ch] = batch[i0 + ch]; sw[ch] = wnode[i0 + ch]; }
  __syncthreads();
  int curg = sb[0];
  float acc = 0.f;
  for (int j = 0; j < lim; j++) {
    int g = sb[j];
    if (g != curg) {
      atomicAdd(&graph_emb[(size_t)curg * 256 + ch], acc);
      acc = 0.f;
      curg = g;
    }
    acc = fmaf(bf2f((unsigned short)x_emb[(size_t)(i0 + j) * 256 + ch]), sw[j], acc);
  }
  atomicAdd(&graph_emb[(size_t)curg * 256 + ch], acc);
}

// ---------------- head ----------------
__global__ void head_kernel(const float* __restrict__ global_x, const float* __restrict__ graph_emb,
                            const float* __restrict__ W1, const float* __restrict__ b1,
                            const float* __restrict__ W2, const float* __restrict__ b2,
                            const float* __restrict__ fW1, const float* __restrict__ fb1,
                            const float* __restrict__ fW2, const float* __restrict__ fb2,
                            float* __restrict__ out) {
  int g = blockIdx.x;
  int ch = threadIdx.x;  // 256
  __shared__ float t1[256], g2s[256], t3s[256];
  float a = b1[ch];
  const float* gx = global_x + g * 16;
#pragma unroll
  for (int k = 0; k < 16; k++) a = fmaf(gx[k], W1[k * 256 + ch], a);
  t1[ch] = fmaxf(a, 0.f);
  __syncthreads();
  float bb = b2[ch];
  for (int k = 0; k < 256; k++) bb = fmaf(t1[k], W2[k * 256 + ch], bb);
  g2s[ch] = bb;
  __syncthreads();
  float c = fb1[ch];
  const float* ger = graph_emb + (size_t)g * 256;
  for (int k = 0; k < 256; k++) c = fmaf(ger[k], fW1[k * 256 + ch], c);
  for (int k = 0; k < 256; k++) c = fmaf(g2s[k], fW1[(256 + k) * 256 + ch], c);
  t3s[ch] = fmaxf(c, 0.f);
  __syncthreads();
  t1[ch] = t3s[ch] * fW2[ch];
  __syncthreads();
  for (int off = 128; off; off >>= 1) {
    if (ch < off) t1[ch] += t1[ch + off];
    __syncthreads();
  }
  if (ch == 0) out[g] = t1[0] + fb2[0];
}

// ---------------- launch ----------------
extern "C" void kernel_launch(void* const* d_in, const int* in_sizes, int n_in,
                              void* d_out, int out_size, void* d_ws, size_t ws_size,
                              hipStream_t stream) {
  const float* x        = (const float*)d_in[0];
  const int*   ei       = (const int*)d_in[1];
  const int*   batch    = (const int*)d_in[2];
  const float* edge_attr= (const float*)d_in[3];
  const float* global_x = (const float*)d_in[4];
  const float* coord_W  = (const float*)d_in[5];
  const float* coord_b  = (const float*)d_in[6];
  const float* node_W   = (const float*)d_in[7];
  const float* node_b   = (const float*)d_in[8];
  const float* edge_W   = (const float*)d_in[9];
  const float* edge_b   = (const float*)d_in[10];
  const float* proj_W   = (const float*)d_in[11];
  const float* proj_b   = (const float*)d_in[12];
  const float* gcn_W    = (const float*)d_in[13];
  const float* gcn_b    = (const float*)d_in[14];
  const float* attn_w   = (const float*)d_in[15];
  const float* attn_b   = (const float*)d_in[16];
  const float* gmlp_W1  = (const float*)d_in[17];
  const float* gmlp_b1  = (const float*)d_in[18];
  const float* gmlp_W2  = (const float*)d_in[19];
  const float* gmlp_b2  = (const float*)d_in[20];
  const float* fc_W1    = (const float*)d_in[21];
  const float* fc_b1    = (const float*)d_in[22];
  const float* fc_W2    = (const float*)d_in[23];
  const float* fc_b2    = (const float*)d_in[24];

  const int N = in_sizes[0] / 9;
  const int E = in_sizes[3] / 8;
  const int G = in_sizes[4] / 16;
  const int NB = (N + 255) / 256;

  char* w = (char*)d_ws;
  auto alloc = [&](size_t bytes) -> char* {
    char* p = w;
    w += (bytes + 255) & ~(size_t)255;
    return p;
  };
  short* x0       = (short*)alloc((size_t)N * 256 * 2);
  short* node_msg = (short*)alloc((size_t)N * 256 * 2);
  short* hA       = (short*)alloc((size_t)N * 256 * 2);
  short* hB       = (short*)alloc((size_t)N * 256 * 2);
  short* x_emb    = (short*)alloc((size_t)N * 256 * 2);
  short* msg128   = x_emb;   // disjoint lifetime: msg128 consumed before x_emb written
  int4*  pk       = (int4*)alloc((size_t)E * 16);
  short* gcnWt    = (short*)alloc((size_t)3 * 65536 * 2);
  short* projWt   = (short*)alloc((size_t)256 * 128 * 2);
  int*   cnt      = (int*)alloc((size_t)N * 4);
  int*   rowstart = (int*)alloc((size_t)(N + 1) * 4);
  int*   cursor   = (int*)alloc((size_t)N * 4);
  float* dnorm    = (float*)alloc((size_t)N * 4);
  float* scores   = (float*)alloc((size_t)N * 4);
  float* wnode    = (float*)alloc((size_t)N * 4);
  int*   partials = (int*)alloc((size_t)NB * 4);
  int*   gs       = (int*)alloc((size_t)G * 4);
  int*   ge       = (int*)alloc((size_t)G * 4);
  float* graph_emb= (float*)alloc((size_t)G * 256 * 4);

  hipMemsetAsync(cnt, 0, (size_t)N * 4, stream);
  hipMemsetAsync(gs, 0x7f, (size_t)G * 4, stream);
  hipMemsetAsync(ge, 0xff, (size_t)G * 4, stream);
  hipMemsetAsync(graph_emb, 0, (size_t)G * 256 * 4, stream);

  wt_kernel<<<(3 * 65536 + 256 * 128 + 255) / 256, 256, 0, stream>>>(gcn_W, proj_W, gcnWt, projWt);
  node_embed_kernel<<<(N + 7) / 8, 256, 0, stream>>>(
      x, coord_W, coord_b, node_W, node_b, x0, N);
  count_kernel<<<(E + 255) / 256, 256, 0, stream>>>(ei + E, cnt, E);
  breduce_kernel<<<NB, 256, 0, stream>>>(cnt, partials, N);
  scan_partials_kernel<<<1, 256, 0, stream>>>(partials, NB);
  scan_apply_kernel<<<NB, 256, 0, stream>>>(cnt, partials, rowstart, dnorm, cursor, N);
  scatter_kernel<<<(E + 255) / 256, 256, 0, stream>>>(
      ei, ei + E, rowstart, cursor, dnorm, pk, E);
  edge_msg_kernel<<<N, 128, 0, stream>>>(edge_attr, pk, rowstart, edge_W, edge_b, msg128, N);
  fused_proj_gemm<<<(N + 63) / 64, 256, 0, stream>>>(
      msg128, projWt, proj_b, cnt, x0, gcnWt, node_msg, hA, N);
  fused_layer<<<(N + 63) / 64, 256, 0, stream>>>(
      hA, pk, rowstart, dnorm, gcn_b, node_msg, gcnWt + 65536, hB, N);
  fused_layer<<<(N + 63) / 64, 256, 0, stream>>>(
      hB, pk, rowstart, dnorm, gcn_b + 256, node_msg, gcnWt + 2 * 65536, hA, N);
  final_agg_kernel<<<(N + 3) / 4, 256, 0, stream>>>(
      hA, pk, rowstart, dnorm, gcn_b + 512, x_emb, attn_w, attn_b, scores, N);
  gse_kernel<<<(N + 255) / 256, 256, 0, stream>>>(batch, gs, ge, N);
  softmax_kernel<<<G, 256, 0, stream>>>(scores, gs, ge, wnode);
  pool_sum_kernel<<<NB, 256, 0, stream>>>(x_emb, wnode, batch, graph_emb, N);
  head_kernel<<<G, 256, 0, stream>>>(global_x, graph_emb, gmlp_W1, gmlp_b1, gmlp_W2, gmlp_b2,
                                     fc_W1, fc_b1, fc_W2, fc_b2, (float*)d_out);
}

// Round 7
// 928.333 us; speedup vs baseline: 1.1369x; 1.1369x over previous
//
#include <hip/hip_runtime.h>

// GraphRegressorV2 — round 7: DE-FUSE agg+gemm (round-6 fusion destroyed
// gather parallelism: 20% occupancy, 208µs/layer). Keep: packed 16B pk,
// bf16 node_msg/x_emb/h/xin, eid-gather edge_msg, fused proj+gemm0.

typedef float f32x4 __attribute__((ext_vector_type(4)));
typedef short s16x8 __attribute__((ext_vector_type(8)));

__device__ __forceinline__ unsigned short f2bf(float f) {
  union { float f; unsigned u; } v{f};
  unsigned r = v.u + 0x7fff + ((v.u >> 16) & 1);  // RNE
  return (unsigned short)(r >> 16);
}
__device__ __forceinline__ float bf2f(unsigned short s) {
  union { unsigned u; float f; } v{(unsigned)s << 16};
  return v.f;
}
__device__ __forceinline__ float blo(unsigned u) {
  union { unsigned x; float f; } v{u << 16};
  return v.f;
}
__device__ __forceinline__ float bhi(unsigned u) {
  union { unsigned x; float f; } v{u & 0xffff0000u};
  return v.f;
}
__device__ __forceinline__ unsigned pk2(float a, float b) {
  return (unsigned)f2bf(a) | ((unsigned)f2bf(b) << 16);
}

// ---------------- node embedding -> bf16 x0 ----------------
__global__ void node_embed_kernel(const float* __restrict__ x,
                                  const float* __restrict__ coord_W, const float* __restrict__ coord_b,
                                  const float* __restrict__ node_W, const float* __restrict__ node_b,
                                  short* __restrict__ x0, int N) {
  int tid = threadIdx.x;
  int node = blockIdx.x * 8 + (tid >> 5);
  if (node >= N) return;
  int ch0 = (tid & 31) * 8;
  const float* xr = x + (size_t)node * 9;
  float a[8];
  if (ch0 < 128) {
    float4 b0 = *(const float4*)&coord_b[ch0];
    float4 b1 = *(const float4*)&coord_b[ch0 + 4];
    a[0]=b0.x; a[1]=b0.y; a[2]=b0.z; a[3]=b0.w; a[4]=b1.x; a[5]=b1.y; a[6]=b1.z; a[7]=b1.w;
#pragma unroll
    for (int k = 0; k < 3; k++) {
      float xv = xr[k];
      float4 w0 = *(const float4*)&coord_W[k * 128 + ch0];
      float4 w1 = *(const float4*)&coord_W[k * 128 + ch0 + 4];
      a[0] = fmaf(xv, w0.x, a[0]); a[1] = fmaf(xv, w0.y, a[1]);
      a[2] = fmaf(xv, w0.z, a[2]); a[3] = fmaf(xv, w0.w, a[3]);
      a[4] = fmaf(xv, w1.x, a[4]); a[5] = fmaf(xv, w1.y, a[5]);
      a[6] = fmaf(xv, w1.z, a[6]); a[7] = fmaf(xv, w1.w, a[7]);
    }
  } else {
    int c0 = ch0 - 128;
    float4 b0 = *(const float4*)&node_b[c0];
    float4 b1 = *(const float4*)&node_b[c0 + 4];
    a[0]=b0.x; a[1]=b0.y; a[2]=b0.z; a[3]=b0.w; a[4]=b1.x; a[5]=b1.y; a[6]=b1.z; a[7]=b1.w;
#pragma unroll
    for (int k = 0; k < 6; k++) {
      float xv = xr[3 + k];
      float4 w0 = *(const float4*)&node_W[k * 128 + c0];
      float4 w1 = *(const float4*)&node_W[k * 128 + c0 + 4];
      a[0] = fmaf(xv, w0.x, a[0]); a[1] = fmaf(xv, w0.y, a[1]);
      a[2] = fmaf(xv, w0.z, a[2]); a[3] = fmaf(xv, w0.w, a[3]);
      a[4] = fmaf(xv, w1.x, a[4]); a[5] = fmaf(xv, w1.y, a[5]);
      a[6] = fmaf(xv, w1.z, a[6]); a[7] = fmaf(xv, w1.w, a[7]);
    }
  }
  uint4 o;
  o.x = pk2(fmaxf(a[0], 0.f), fmaxf(a[1], 0.f));
  o.y = pk2(fmaxf(a[2], 0.f), fmaxf(a[3], 0.f));
  o.z = pk2(fmaxf(a[4], 0.f), fmaxf(a[5], 0.f));
  o.w = pk2(fmaxf(a[6], 0.f), fmaxf(a[7], 0.f));
  *(uint4*)&x0[(size_t)node * 256 + ch0] = o;
}

// ---------------- CSR build ----------------
__global__ void count_kernel(const int* __restrict__ col, int* __restrict__ cnt, int E) {
  int e = blockIdx.x * 256 + threadIdx.x;
  if (e < E) atomicAdd(&cnt[col[e]], 1);
}

__global__ void breduce_kernel(const int* __restrict__ cnt, int* __restrict__ partials, int N) {
  __shared__ int red[256];
  int t = threadIdx.x;
  int i = blockIdx.x * 256 + t;
  int v = (i < N) ? cnt[i] : 0;
  red[t] = v;
  __syncthreads();
  for (int off = 128; off; off >>= 1) {
    if (t < off) red[t] += red[t + off];
    __syncthreads();
  }
  if (t == 0) partials[blockIdx.x] = red[0];
}

__global__ void scan_partials_kernel(int* __restrict__ partials, int nb) {
  __shared__ int s[1024];
  int t = threadIdx.x;
  for (int i = t; i < nb; i += 256) s[i] = partials[i];
  __syncthreads();
  if (t == 0) {
    int run = 0;
    for (int i = 0; i < nb; i++) { int c = s[i]; s[i] = run; run += c; }
  }
  __syncthreads();
  for (int i = t; i < nb; i += 256) partials[i] = s[i];
}

__global__ void scan_apply_kernel(const int* __restrict__ cnt, const int* __restrict__ partials,
                                  int* __restrict__ rowstart, float* __restrict__ dnorm,
                                  int* __restrict__ cursor, int N) {
  __shared__ int red[256];
  int t = threadIdx.x;
  int i = blockIdx.x * 256 + t;
  int v = (i < N) ? cnt[i] : 0;
  red[t] = v;
  __syncthreads();
  for (int off = 1; off < 256; off <<= 1) {
    int x = (t >= off) ? red[t - off] : 0;
    __syncthreads();
    red[t] += x;
    __syncthreads();
  }
  if (i < N) {
    int ex = red[t] - v + partials[blockIdx.x];
    rowstart[i] = ex;
    dnorm[i] = rsqrtf((float)(v + 1));  // +1 self-loop
    cursor[i] = 0;
    if (i == N - 1) rowstart[N] = ex + v;
  }
}

// one packed 16B write per edge: {eid, row, efac_bits, 0}
__global__ void scatter_kernel(const int* __restrict__ row, const int* __restrict__ col,
                               const int* __restrict__ rowstart, int* __restrict__ cursor,
                               const float* __restrict__ dnorm,
                               int4* __restrict__ pk, int E) {
  int e = blockIdx.x * 256 + threadIdx.x;
  if (e >= E) return;
  int c = col[e], r = row[e];
  int p = atomicAdd(&cursor[c], 1);
  int slot = rowstart[c] + p;
  pk[slot] = make_int4(e, r, __float_as_int(dnorm[r] * dnorm[c]), 0);
}

// ---------------- weight transpose+bf16 ----------------
__global__ void wt_kernel(const float* __restrict__ gcn_W, const float* __restrict__ proj_W,
                          short* __restrict__ gcnWt, short* __restrict__ projWt) {
  int idx = blockIdx.x * 256 + threadIdx.x;
  if (idx < 3 * 65536) {
    int l = idx >> 16, r = idx & 65535, n = r >> 8, k = r & 255;
    gcnWt[idx] = (short)f2bf(gcn_W[l * 65536 + k * 256 + n]);
  } else {
    int j = idx - 3 * 65536;  // n*128+k
    int n = j >> 7, k = j & 127;
    projWt[j] = (short)f2bf(proj_W[k * 256 + n]);
  }
}

// ---------------- edge message aggregate (gather edge_attr by eid) ---------
__global__ void edge_msg_kernel(const float* __restrict__ edge_attr,
                                const int4* __restrict__ pk,
                                const int* __restrict__ rowstart,
                                const float* __restrict__ edge_W, const float* __restrict__ edge_b,
                                short* __restrict__ msg128, int N) {
  int node = blockIdx.x;
  int ch = threadIdx.x;  // 128
  __shared__ float sW[8 * 128];
  __shared__ float sb[128];
  for (int i = ch; i < 8 * 128; i += 128) sW[i] = edge_W[i];
  sb[ch] = edge_b[ch];
  __syncthreads();
  float acc = 0.f;
  int s0 = rowstart[node], s1 = rowstart[node + 1];
  for (int s = s0; s < s1; s++) {
    int eid = pk[s].x;
    const float4* ea = (const float4*)(edge_attr + (size_t)eid * 8);
    float4 e0 = ea[0], e1 = ea[1];
    float t = sb[ch];
    t = fmaf(e0.x, sW[0 * 128 + ch], t);
    t = fmaf(e0.y, sW[1 * 128 + ch], t);
    t = fmaf(e0.z, sW[2 * 128 + ch], t);
    t = fmaf(e0.w, sW[3 * 128 + ch], t);
    t = fmaf(e1.x, sW[4 * 128 + ch], t);
    t = fmaf(e1.y, sW[5 * 128 + ch], t);
    t = fmaf(e1.z, sW[6 * 128 + ch], t);
    t = fmaf(e1.w, sW[7 * 128 + ch], t);
    acc += fmaxf(t, 0.f);
  }
  msg128[(size_t)node * 128 + ch] = (short)f2bf(acc);
}

// ---------------- fused proj + gemm0 (no gather inside — keep fused) -------
__global__ void __launch_bounds__(256) fused_proj_gemm(
    const short* __restrict__ msg128, const short* __restrict__ projWt,
    const float* __restrict__ proj_b, const int* __restrict__ cnt,
    const short* __restrict__ x0, const short* __restrict__ W0t,
    short* __restrict__ node_msg, short* __restrict__ hout, int N) {
  __shared__ short As[64][136];
  __shared__ short Xs[64][264];
  int tid = threadIdx.x;
  int n0 = blockIdx.x * 64;
  for (int i = tid; i < 64 * 32; i += 256) {
    int r = i >> 5, c4 = (i & 31) << 2;
    int n = n0 + r;
    uint2 v = make_uint2(0, 0);
    if (n < N) v = *(const uint2*)&msg128[(size_t)n * 128 + c4];
    *(uint2*)&As[r][c4] = v;
  }
  __syncthreads();
  int wave = tid >> 6, lane = tid & 63;
  int mrow = wave * 16 + (lane & 15);
  int kgrp = (lane >> 4) * 8;
  f32x4 acc[16];
#pragma unroll
  for (int i = 0; i < 16; i++) acc[i] = (f32x4){0.f, 0.f, 0.f, 0.f};
  {
    const short* wbase = projWt + (size_t)(lane & 15) * 128 + kgrp;
#pragma unroll
    for (int kk = 0; kk < 4; kk++) {
      s16x8 a = *(const s16x8*)&As[mrow][kk * 32 + kgrp];
#pragma unroll
      for (int nf = 0; nf < 16; nf++) {
        s16x8 b = *(const s16x8*)&wbase[(size_t)nf * 16 * 128 + kk * 32];
        acc[nf] = __builtin_amdgcn_mfma_f32_16x16x32_bf16(a, b, acc[nf], 0, 0, 0);
      }
    }
  }
  int orow0 = wave * 16 + (lane >> 4) * 4;
  int ocol = lane & 15;
#pragma unroll
  for (int r = 0; r < 4; r++) {
    int i = orow0 + r;
    int n = n0 + i;
    if (n < N) {
      float cn = (float)cnt[n];
#pragma unroll
      for (int nf = 0; nf < 16; nf++) {
        int c = nf * 16 + ocol;
        float v = acc[nf][r] + cn * proj_b[c];
        unsigned short nm = f2bf(v);
        node_msg[(size_t)n * 256 + c] = (short)nm;
        Xs[i][c] = (short)f2bf(bf2f(nm) + bf2f((unsigned short)x0[(size_t)n * 256 + c]));
      }
    } else {
#pragma unroll
      for (int nf = 0; nf < 16; nf++) Xs[i][nf * 16 + ocol] = 0;
    }
  }
  __syncthreads();
#pragma unroll
  for (int i = 0; i < 16; i++) acc[i] = (f32x4){0.f, 0.f, 0.f, 0.f};
  {
    const short* wbase = W0t + (size_t)(lane & 15) * 256 + kgrp;
#pragma unroll
    for (int kk = 0; kk < 8; kk++) {
      s16x8 a = *(const s16x8*)&Xs[mrow][kk * 32 + kgrp];
#pragma unroll
      for (int nf = 0; nf < 16; nf++) {
        s16x8 b = *(const s16x8*)&wbase[(size_t)nf * 16 * 256 + kk * 32];
        acc[nf] = __builtin_amdgcn_mfma_f32_16x16x32_bf16(a, b, acc[nf], 0, 0, 0);
      }
    }
  }
#pragma unroll
  for (int nf = 0; nf < 16; nf++) {
#pragma unroll
    for (int r = 0; r < 4; r++) {
      int n = n0 + orow0 + r;
      if (n < N) hout[(size_t)n * 256 + nf * 16 + ocol] = (short)f2bf(acc[nf][r]);
    }
  }
}

// ---------------- aggregate (wave per node): xin = relu(agg+b)+node_msg ----
__global__ void __launch_bounds__(256) gcn_agg_kernel(
    const short* __restrict__ h, const int4* __restrict__ pk,
    const int* __restrict__ rowstart, const float* __restrict__ dnorm,
    const float* __restrict__ b, const short* __restrict__ node_msg,
    short* __restrict__ xin, int N) {
  int lane = threadIdx.x & 63;
  int node = blockIdx.x * 4 + (threadIdx.x >> 6);
  if (node >= N) return;
  int ch0 = lane << 2;
  size_t rowb = (size_t)node * 256 + ch0;
  float dn = dnorm[node];
  float wgt = dn * dn;
  uint2 hv = *(const uint2*)&h[rowb];
  float a0 = blo(hv.x) * wgt, a1 = bhi(hv.x) * wgt;
  float a2 = blo(hv.y) * wgt, a3 = bhi(hv.y) * wgt;
  int s = rowstart[node], s1 = rowstart[node + 1];
  for (; s + 4 <= s1; s += 4) {
    int4 p0 = pk[s], p1 = pk[s + 1], p2 = pk[s + 2], p3 = pk[s + 3];
    float f0 = __int_as_float(p0.z), f1 = __int_as_float(p1.z);
    float f2 = __int_as_float(p2.z), f3 = __int_as_float(p3.z);
    uint2 v0 = *(const uint2*)&h[(size_t)p0.y * 256 + ch0];
    uint2 v1 = *(const uint2*)&h[(size_t)p1.y * 256 + ch0];
    uint2 v2 = *(const uint2*)&h[(size_t)p2.y * 256 + ch0];
    uint2 v3 = *(const uint2*)&h[(size_t)p3.y * 256 + ch0];
    a0 = fmaf(blo(v0.x), f0, a0); a1 = fmaf(bhi(v0.x), f0, a1);
    a2 = fmaf(blo(v0.y), f0, a2); a3 = fmaf(bhi(v0.y), f0, a3);
    a0 = fmaf(blo(v1.x), f1, a0); a1 = fmaf(bhi(v1.x), f1, a1);
    a2 = fmaf(blo(v1.y), f1, a2); a3 = fmaf(bhi(v1.y), f1, a3);
    a0 = fmaf(blo(v2.x), f2, a0); a1 = fmaf(bhi(v2.x), f2, a1);
    a2 = fmaf(blo(v2.y), f2, a2); a3 = fmaf(bhi(v2.y), f2, a3);
    a0 = fmaf(blo(v3.x), f3, a0); a1 = fmaf(bhi(v3.x), f3, a1);
    a2 = fmaf(blo(v3.y), f3, a2); a3 = fmaf(bhi(v3.y), f3, a3);
  }
  for (; s < s1; s++) {
    int4 p = pk[s];
    float f = __int_as_float(p.z);
    uint2 v = *(const uint2*)&h[(size_t)p.y * 256 + ch0];
    a0 = fmaf(blo(v.x), f, a0); a1 = fmaf(bhi(v.x), f, a1);
    a2 = fmaf(blo(v.y), f, a2); a3 = fmaf(bhi(v.y), f, a3);
  }
  float4 bv = *(const float4*)&b[ch0];
  uint2 mv = *(const uint2*)&node_msg[rowb];
  float y0 = fmaxf(a0 + bv.x, 0.f) + blo(mv.x);
  float y1 = fmaxf(a1 + bv.y, 0.f) + bhi(mv.x);
  float y2 = fmaxf(a2 + bv.z, 0.f) + blo(mv.y);
  float y3 = fmaxf(a3 + bv.w, 0.f) + bhi(mv.y);
  uint2 o;
  o.x = pk2(y0, y1);
  o.y = pk2(y2, y3);
  *(uint2*)&xin[rowb] = o;
}

// ---------------- GCN GEMM via bf16 MFMA: h = xin @ W ----------------
__global__ void __launch_bounds__(256) gcn_gemm_mfma(
    const short* __restrict__ Xin, const short* __restrict__ Wt,
    short* __restrict__ Hout, int N) {
  __shared__ short As[64][264];
  int tid = threadIdx.x;
  int n0 = blockIdx.x * 64;
  for (int i = tid; i < 64 * 64; i += 256) {
    int r = i >> 6, c4 = (i & 63) << 2;
    int n = n0 + r;
    uint2 v = make_uint2(0, 0);
    if (n < N) v = *(const uint2*)&Xin[(size_t)n * 256 + c4];
    *(uint2*)&As[r][c4] = v;
  }
  __syncthreads();
  int wave = tid >> 6, lane = tid & 63;
  int mrow = wave * 16 + (lane & 15);
  int kgrp = (lane >> 4) * 8;
  f32x4 acc[16];
#pragma unroll
  for (int i = 0; i < 16; i++) acc[i] = (f32x4){0.f, 0.f, 0.f, 0.f};
  const short* wbase = Wt + (size_t)(lane & 15) * 256 + kgrp;
#pragma unroll
  for (int kk = 0; kk < 8; kk++) {
    s16x8 a = *(const s16x8*)&As[mrow][kk * 32 + kgrp];
#pragma unroll
    for (int nf = 0; nf < 16; nf++) {
      s16x8 b = *(const s16x8*)&wbase[(size_t)nf * 16 * 256 + kk * 32];
      acc[nf] = __builtin_amdgcn_mfma_f32_16x16x32_bf16(a, b, acc[nf], 0, 0, 0);
    }
  }
  int orow0 = wave * 16 + (lane >> 4) * 4;
  int ocol = lane & 15;
#pragma unroll
  for (int nf = 0; nf < 16; nf++) {
#pragma unroll
    for (int r = 0; r < 4; r++) {
      int n = n0 + orow0 + r;
      if (n < N) Hout[(size_t)n * 256 + nf * 16 + ocol] = (short)f2bf(acc[nf][r]);
    }
  }
}

// ---------------- final aggregate -> x_emb bf16 + scores ----------------
__global__ void __launch_bounds__(256) final_agg_kernel(
    const short* __restrict__ h, const int4* __restrict__ pk,
    const int* __restrict__ rowstart, const float* __restrict__ dnorm,
    const float* __restrict__ b, short* __restrict__ x_emb,
    const float* __restrict__ attn_w, const float* __restrict__ attn_b,
    float* __restrict__ scores, int N) {
  int lane = threadIdx.x & 63;
  int node = blockIdx.x * 4 + (threadIdx.x >> 6);
  if (node >= N) return;
  int ch0 = lane << 2;
  size_t rowb = (size_t)node * 256 + ch0;
  float dn = dnorm[node];
  float wgt = dn * dn;
  uint2 hv = *(const uint2*)&h[rowb];
  float a0 = blo(hv.x) * wgt, a1 = bhi(hv.x) * wgt;
  float a2 = blo(hv.y) * wgt, a3 = bhi(hv.y) * wgt;
  int s = rowstart[node], s1 = rowstart[node + 1];
  for (; s + 4 <= s1; s += 4) {
    int4 p0 = pk[s], p1 = pk[s + 1], p2 = pk[s + 2], p3 = pk[s + 3];
    float f0 = __int_as_float(p0.z), f1 = __int_as_float(p1.z);
    float f2 = __int_as_float(p2.z), f3 = __int_as_float(p3.z);
    uint2 v0 = *(const uint2*)&h[(size_t)p0.y * 256 + ch0];
    uint2 v1 = *(const uint2*)&h[(size_t)p1.y * 256 + ch0];
    uint2 v2 = *(const uint2*)&h[(size_t)p2.y * 256 + ch0];
    uint2 v3 = *(const uint2*)&h[(size_t)p3.y * 256 + ch0];
    a0 = fmaf(blo(v0.x), f0, a0); a1 = fmaf(bhi(v0.x), f0, a1);
    a2 = fmaf(blo(v0.y), f0, a2); a3 = fmaf(bhi(v0.y), f0, a3);
    a0 = fmaf(blo(v1.x), f1, a0); a1 = fmaf(bhi(v1.x), f1, a1);
    a2 = fmaf(blo(v1.y), f1, a2); a3 = fmaf(bhi(v1.y), f1, a3);
    a0 = fmaf(blo(v2.x), f2, a0); a1 = fmaf(bhi(v2.x), f2, a1);
    a2 = fmaf(blo(v2.y), f2, a2); a3 = fmaf(bhi(v2.y), f2, a3);
    a0 = fmaf(blo(v3.x), f3, a0); a1 = fmaf(bhi(v3.x), f3, a1);
    a2 = fmaf(blo(v3.y), f3, a2); a3 = fmaf(bhi(v3.y), f3, a3);
  }
  for (; s < s1; s++) {
    int4 p = pk[s];
    float f = __int_as_float(p.z);
    uint2 v = *(const uint2*)&h[(size_t)p.y * 256 + ch0];
    a0 = fmaf(blo(v.x), f, a0); a1 = fmaf(bhi(v.x), f, a1);
    a2 = fmaf(blo(v.y), f, a2); a3 = fmaf(bhi(v.y), f, a3);
  }
  float4 bv = *(const float4*)&b[ch0];
  a0 += bv.x; a1 += bv.y; a2 += bv.z; a3 += bv.w;
  uint2 o;
  o.x = pk2(a0, a1);
  o.y = pk2(a2, a3);
  *(uint2*)&x_emb[rowb] = o;
  float4 aw = *(const float4*)&attn_w[ch0];
  float p = a0 * aw.x + a1 * aw.y + a2 * aw.z + a3 * aw.w;
#pragma unroll
  for (int off = 32; off; off >>= 1) p += __shfl_down(p, off);
  if (lane == 0) scores[node] = p + attn_b[0];
}

// ---------------- graph segment boundaries (batch sorted) ----------------
__global__ void gse_kernel(const int* __restrict__ batch, int* __restrict__ gs,
                           int* __restrict__ ge, int N) {
  int i = blockIdx.x * 256 + threadIdx.x;
  if (i >= N) return;
  int g = batch[i];
  if (i == 0) gs[g] = 0;
  else {
    int gp = batch[i - 1];
    if (gp != g) { gs[g] = i; ge[gp] = i - 1; }
  }
  if (i == N - 1) ge[g] = N - 1;
}

__global__ void softmax_kernel(const float* __restrict__ scores, const int* __restrict__ gs,
                               const int* __restrict__ ge, float* __restrict__ wnode) {
  int g = blockIdx.x;
  int tid = threadIdx.x;  // 256
  __shared__ float red[256];
  int s0 = gs[g], e1 = ge[g];
  if (s0 > e1) return;
  int s1 = e1 + 1;
  float m = -1e30f;
  for (int i = s0 + tid; i < s1; i += 256) m = fmaxf(m, scores[i]);
  red[tid] = m;
  __syncthreads();
  for (int off = 128; off; off >>= 1) {
    if (tid < off) red[tid] = fmaxf(red[tid], red[tid + off]);
    __syncthreads();
  }
  m = red[0];
  __syncthreads();
  float d = 0.f;
  for (int i = s0 + tid; i < s1; i += 256) d += expf(scores[i] - m);
  red[tid] = d;
  __syncthreads();
  for (int off = 128; off; off >>= 1) {
    if (tid < off) red[tid] += red[tid + off];
    __syncthreads();
  }
  float rd = 1.f / red[0];
  for (int i = s0 + tid; i < s1; i += 256) wnode[i] = expf(scores[i] - m) * rd;
}

__global__ void __launch_bounds__(256) pool_sum_kernel(
    const short* __restrict__ x_emb, const float* __restrict__ wnode,
    const int* __restrict__ batch, float* __restrict__ graph_emb, int N) {
  __shared__ int sb[256];
  __shared__ float sw[256];
  int ch = threadIdx.x;
  int i0 = blockIdx.x * 256;
  int lim = min(256, N - i0);
  if (ch < lim) { sb[ch] = batch[i0 + ch]; sw[ch] = wnode[i0 + ch]; }
  __syncthreads();
  int curg = sb[0];
  float acc = 0.f;
  for (int j = 0; j < lim; j++) {
    int g = sb[j];
    if (g != curg) {
      atomicAdd(&graph_emb[(size_t)curg * 256 + ch], acc);
      acc = 0.f;
      curg = g;
    }
    acc = fmaf(bf2f((unsigned short)x_emb[(size_t)(i0 + j) * 256 + ch]), sw[j], acc);
  }
  atomicAdd(&graph_emb[(size_t)curg * 256 + ch], acc);
}

// ---------------- head ----------------
__global__ void head_kernel(const float* __restrict__ global_x, const float* __restrict__ graph_emb,
                            const float* __restrict__ W1, const float* __restrict__ b1,
                            const float* __restrict__ W2, const float* __restrict__ b2,
                            const float* __restrict__ fW1, const float* __restrict__ fb1,
                            const float* __restrict__ fW2, const float* __restrict__ fb2,
                            float* __restrict__ out) {
  int g = blockIdx.x;
  int ch = threadIdx.x;  // 256
  __shared__ float t1[256], g2s[256], t3s[256];
  float a = b1[ch];
  const float* gx = global_x + g * 16;
#pragma unroll
  for (int k = 0; k < 16; k++) a = fmaf(gx[k], W1[k * 256 + ch], a);
  t1[ch] = fmaxf(a, 0.f);
  __syncthreads();
  float bb = b2[ch];
  for (int k = 0; k < 256; k++) bb = fmaf(t1[k], W2[k * 256 + ch], bb);
  g2s[ch] = bb;
  __syncthreads();
  float c = fb1[ch];
  const float* ger = graph_emb + (size_t)g * 256;
  for (int k = 0; k < 256; k++) c = fmaf(ger[k], fW1[k * 256 + ch], c);
  for (int k = 0; k < 256; k++) c = fmaf(g2s[k], fW1[(256 + k) * 256 + ch], c);
  t3s[ch] = fmaxf(c, 0.f);
  __syncthreads();
  t1[ch] = t3s[ch] * fW2[ch];
  __syncthreads();
  for (int off = 128; off; off >>= 1) {
    if (ch < off) t1[ch] += t1[ch + off];
    __syncthreads();
  }
  if (ch == 0) out[g] = t1[0] + fb2[0];
}

// ---------------- launch ----------------
extern "C" void kernel_launch(void* const* d_in, const int* in_sizes, int n_in,
                              void* d_out, int out_size, void* d_ws, size_t ws_size,
                              hipStream_t stream) {
  const float* x        = (const float*)d_in[0];
  const int*   ei       = (const int*)d_in[1];
  const int*   batch    = (const int*)d_in[2];
  const float* edge_attr= (const float*)d_in[3];
  const float* global_x = (const float*)d_in[4];
  const float* coord_W  = (const float*)d_in[5];
  const float* coord_b  = (const float*)d_in[6];
  const float* node_W   = (const float*)d_in[7];
  const float* node_b   = (const float*)d_in[8];
  const float* edge_W   = (const float*)d_in[9];
  const float* edge_b   = (const float*)d_in[10];
  const float* proj_W   = (const float*)d_in[11];
  const float* proj_b   = (const float*)d_in[12];
  const float* gcn_W    = (const float*)d_in[13];
  const float* gcn_b    = (const float*)d_in[14];
  const float* attn_w   = (const float*)d_in[15];
  const float* attn_b   = (const float*)d_in[16];
  const float* gmlp_W1  = (const float*)d_in[17];
  const float* gmlp_b1  = (const float*)d_in[18];
  const float* gmlp_W2  = (const float*)d_in[19];
  const float* gmlp_b2  = (const float*)d_in[20];
  const float* fc_W1    = (const float*)d_in[21];
  const float* fc_b1    = (const float*)d_in[22];
  const float* fc_W2    = (const float*)d_in[23];
  const float* fc_b2    = (const float*)d_in[24];

  const int N = in_sizes[0] / 9;
  const int E = in_sizes[3] / 8;
  const int G = in_sizes[4] / 16;
  const int NB = (N + 255) / 256;

  char* w = (char*)d_ws;
  auto alloc = [&](size_t bytes) -> char* {
    char* p = w;
    w += (bytes + 255) & ~(size_t)255;
    return p;
  };
  short* x0       = (short*)alloc((size_t)N * 256 * 2);
  short* node_msg = (short*)alloc((size_t)N * 256 * 2);
  short* hA       = (short*)alloc((size_t)N * 256 * 2);
  short* hB       = (short*)alloc((size_t)N * 256 * 2);
  short* xinBuf   = (short*)alloc((size_t)N * 256 * 2);
  short* x_emb    = (short*)alloc((size_t)N * 256 * 2);
  short* msg128   = x_emb;   // disjoint lifetime: msg128 consumed before x_emb written
  int4*  pk       = (int4*)alloc((size_t)E * 16);
  short* gcnWt    = (short*)alloc((size_t)3 * 65536 * 2);
  short* projWt   = (short*)alloc((size_t)256 * 128 * 2);
  int*   cnt      = (int*)alloc((size_t)N * 4);
  int*   rowstart = (int*)alloc((size_t)(N + 1) * 4);
  int*   cursor   = (int*)alloc((size_t)N * 4);
  float* dnorm    = (float*)alloc((size_t)N * 4);
  float* scores   = (float*)alloc((size_t)N * 4);
  float* wnode    = (float*)alloc((size_t)N * 4);
  int*   partials = (int*)alloc((size_t)NB * 4);
  int*   gs       = (int*)alloc((size_t)G * 4);
  int*   ge       = (int*)alloc((size_t)G * 4);
  float* graph_emb= (float*)alloc((size_t)G * 256 * 4);

  hipMemsetAsync(cnt, 0, (size_t)N * 4, stream);
  hipMemsetAsync(gs, 0x7f, (size_t)G * 4, stream);
  hipMemsetAsync(ge, 0xff, (size_t)G * 4, stream);
  hipMemsetAsync(graph_emb, 0, (size_t)G * 256 * 4, stream);

  wt_kernel<<<(3 * 65536 + 256 * 128 + 255) / 256, 256, 0, stream>>>(gcn_W, proj_W, gcnWt, projWt);
  node_embed_kernel<<<(N + 7) / 8, 256, 0, stream>>>(
      x, coord_W, coord_b, node_W, node_b, x0, N);
  count_kernel<<<(E + 255) / 256, 256, 0, stream>>>(ei + E, cnt, E);
  breduce_kernel<<<NB, 256, 0, stream>>>(cnt, partials, N);
  scan_partials_kernel<<<1, 256, 0, stream>>>(partials, NB);
  scan_apply_kernel<<<NB, 256, 0, stream>>>(cnt, partials, rowstart, dnorm, cursor, N);
  scatter_kernel<<<(E + 255) / 256, 256, 0, stream>>>(
      ei, ei + E, rowstart, cursor, dnorm, pk, E);
  edge_msg_kernel<<<N, 128, 0, stream>>>(edge_attr, pk, rowstart, edge_W, edge_b, msg128, N);
  fused_proj_gemm<<<(N + 63) / 64, 256, 0, stream>>>(
      msg128, projWt, proj_b, cnt, x0, gcnWt, node_msg, hA, N);
  // layer 1: agg(hA) -> xin ; gemm(xin, W1) -> hB
  gcn_agg_kernel<<<(N + 3) / 4, 256, 0, stream>>>(
      hA, pk, rowstart, dnorm, gcn_b, node_msg, xinBuf, N);
  gcn_gemm_mfma<<<(N + 63) / 64, 256, 0, stream>>>(
      xinBuf, gcnWt + 65536, hB, N);
  // layer 2: agg(hB) -> xin ; gemm(xin, W2) -> hA
  gcn_agg_kernel<<<(N + 3) / 4, 256, 0, stream>>>(
      hB, pk, rowstart, dnorm, gcn_b + 256, node_msg, xinBuf, N);
  gcn_gemm_mfma<<<(N + 63) / 64, 256, 0, stream>>>(
      xinBuf, gcnWt + 2 * 65536, hA, N);
  final_agg_kernel<<<(N + 3) / 4, 256, 0, stream>>>(
      hA, pk, rowstart, dnorm, gcn_b + 512, x_emb, attn_w, attn_b, scores, N);
  gse_kernel<<<(N + 255) / 256, 256, 0, stream>>>(batch, gs, ge, N);
  softmax_kernel<<<G, 256, 0, stream>>>(scores, gs, ge, wnode);
  pool_sum_kernel<<<NB, 256, 0, stream>>>(x_emb, wnode, batch, graph_emb, N);
  head_kernel<<<G, 256, 0, stream>>>(global_x, graph_emb, gmlp_W1, gmlp_b1, gmlp_W2, gmlp_b2,
                                     fc_W1, fc_b1, fc_W2, fc_b2, (float*)d_out);
}

// Round 8
// 923.416 us; speedup vs baseline: 1.1430x; 1.0053x over previous
//
#include <hip/hip_runtime.h>

// GraphRegressorV2 — round 8: edge_msg MLP×4 (batched independent loads,
// reg-resident weights, split eids[]/pk8[] CSR arrays), de-fused slim
// proj_gemm + gemm0_add (x0+node_msg folded into LDS staging).

typedef float f32x4 __attribute__((ext_vector_type(4)));
typedef short s16x8 __attribute__((ext_vector_type(8)));

__device__ __forceinline__ unsigned short f2bf(float f) {
  union { float f; unsigned u; } v{f};
  unsigned r = v.u + 0x7fff + ((v.u >> 16) & 1);  // RNE
  return (unsigned short)(r >> 16);
}
__device__ __forceinline__ float bf2f(unsigned short s) {
  union { unsigned u; float f; } v{(unsigned)s << 16};
  return v.f;
}
__device__ __forceinline__ float blo(unsigned u) {
  union { unsigned x; float f; } v{u << 16};
  return v.f;
}
__device__ __forceinline__ float bhi(unsigned u) {
  union { unsigned x; float f; } v{u & 0xffff0000u};
  return v.f;
}
__device__ __forceinline__ unsigned pk2(float a, float b) {
  return (unsigned)f2bf(a) | ((unsigned)f2bf(b) << 16);
}

// ---------------- node embedding -> bf16 x0 ----------------
__global__ void node_embed_kernel(const float* __restrict__ x,
                                  const float* __restrict__ coord_W, const float* __restrict__ coord_b,
                                  const float* __restrict__ node_W, const float* __restrict__ node_b,
                                  short* __restrict__ x0, int N) {
  int tid = threadIdx.x;
  int node = blockIdx.x * 8 + (tid >> 5);
  if (node >= N) return;
  int ch0 = (tid & 31) * 8;
  const float* xr = x + (size_t)node * 9;
  float a[8];
  if (ch0 < 128) {
    float4 b0 = *(const float4*)&coord_b[ch0];
    float4 b1 = *(const float4*)&coord_b[ch0 + 4];
    a[0]=b0.x; a[1]=b0.y; a[2]=b0.z; a[3]=b0.w; a[4]=b1.x; a[5]=b1.y; a[6]=b1.z; a[7]=b1.w;
#pragma unroll
    for (int k = 0; k < 3; k++) {
      float xv = xr[k];
      float4 w0 = *(const float4*)&coord_W[k * 128 + ch0];
      float4 w1 = *(const float4*)&coord_W[k * 128 + ch0 + 4];
      a[0] = fmaf(xv, w0.x, a[0]); a[1] = fmaf(xv, w0.y, a[1]);
      a[2] = fmaf(xv, w0.z, a[2]); a[3] = fmaf(xv, w0.w, a[3]);
      a[4] = fmaf(xv, w1.x, a[4]); a[5] = fmaf(xv, w1.y, a[5]);
      a[6] = fmaf(xv, w1.z, a[6]); a[7] = fmaf(xv, w1.w, a[7]);
    }
  } else {
    int c0 = ch0 - 128;
    float4 b0 = *(const float4*)&node_b[c0];
    float4 b1 = *(const float4*)&node_b[c0 + 4];
    a[0]=b0.x; a[1]=b0.y; a[2]=b0.z; a[3]=b0.w; a[4]=b1.x; a[5]=b1.y; a[6]=b1.z; a[7]=b1.w;
#pragma unroll
    for (int k = 0; k < 6; k++) {
      float xv = xr[3 + k];
      float4 w0 = *(const float4*)&node_W[k * 128 + c0];
      float4 w1 = *(const float4*)&node_W[k * 128 + c0 + 4];
      a[0] = fmaf(xv, w0.x, a[0]); a[1] = fmaf(xv, w0.y, a[1]);
      a[2] = fmaf(xv, w0.z, a[2]); a[3] = fmaf(xv, w0.w, a[3]);
      a[4] = fmaf(xv, w1.x, a[4]); a[5] = fmaf(xv, w1.y, a[5]);
      a[6] = fmaf(xv, w1.z, a[6]); a[7] = fmaf(xv, w1.w, a[7]);
    }
  }
  uint4 o;
  o.x = pk2(fmaxf(a[0], 0.f), fmaxf(a[1], 0.f));
  o.y = pk2(fmaxf(a[2], 0.f), fmaxf(a[3], 0.f));
  o.z = pk2(fmaxf(a[4], 0.f), fmaxf(a[5], 0.f));
  o.w = pk2(fmaxf(a[6], 0.f), fmaxf(a[7], 0.f));
  *(uint4*)&x0[(size_t)node * 256 + ch0] = o;
}

// ---------------- CSR build ----------------
__global__ void count_kernel(const int* __restrict__ col, int* __restrict__ cnt, int E) {
  int e = blockIdx.x * 256 + threadIdx.x;
  if (e < E) atomicAdd(&cnt[col[e]], 1);
}

__global__ void breduce_kernel(const int* __restrict__ cnt, int* __restrict__ partials, int N) {
  __shared__ int red[256];
  int t = threadIdx.x;
  int i = blockIdx.x * 256 + t;
  int v = (i < N) ? cnt[i] : 0;
  red[t] = v;
  __syncthreads();
  for (int off = 128; off; off >>= 1) {
    if (t < off) red[t] += red[t + off];
    __syncthreads();
  }
  if (t == 0) partials[blockIdx.x] = red[0];
}

__global__ void scan_partials_kernel(int* __restrict__ partials, int nb) {
  __shared__ int s[1024];
  int t = threadIdx.x;
  for (int i = t; i < nb; i += 256) s[i] = partials[i];
  __syncthreads();
  if (t == 0) {
    int run = 0;
    for (int i = 0; i < nb; i++) { int c = s[i]; s[i] = run; run += c; }
  }
  __syncthreads();
  for (int i = t; i < nb; i += 256) partials[i] = s[i];
}

__global__ void scan_apply_kernel(const int* __restrict__ cnt, const int* __restrict__ partials,
                                  int* __restrict__ rowstart, float* __restrict__ dnorm,
                                  int* __restrict__ cursor, int N) {
  __shared__ int red[256];
  int t = threadIdx.x;
  int i = blockIdx.x * 256 + t;
  int v = (i < N) ? cnt[i] : 0;
  red[t] = v;
  __syncthreads();
  for (int off = 1; off < 256; off <<= 1) {
    int x = (t >= off) ? red[t - off] : 0;
    __syncthreads();
    red[t] += x;
    __syncthreads();
  }
  if (i < N) {
    int ex = red[t] - v + partials[blockIdx.x];
    rowstart[i] = ex;
    dnorm[i] = rsqrtf((float)(v + 1));  // +1 self-loop
    cursor[i] = 0;
    if (i == N - 1) rowstart[N] = ex + v;
  }
}

// split CSR arrays: pk8 {row, efac_bits} (aggs), eids (edge_msg)
__global__ void scatter_kernel(const int* __restrict__ row, const int* __restrict__ col,
                               const int* __restrict__ rowstart, int* __restrict__ cursor,
                               const float* __restrict__ dnorm,
                               int2* __restrict__ pk8, int* __restrict__ eids, int E) {
  int e = blockIdx.x * 256 + threadIdx.x;
  if (e >= E) return;
  int c = col[e], r = row[e];
  int p = atomicAdd(&cursor[c], 1);
  int slot = rowstart[c] + p;
  pk8[slot] = make_int2(r, __float_as_int(dnorm[r] * dnorm[c]));
  eids[slot] = e;
}

// ---------------- weight transpose+bf16 ----------------
__global__ void wt_kernel(const float* __restrict__ gcn_W, const float* __restrict__ proj_W,
                          short* __restrict__ gcnWt, short* __restrict__ projWt) {
  int idx = blockIdx.x * 256 + threadIdx.x;
  if (idx < 3 * 65536) {
    int l = idx >> 16, r = idx & 65535, n = r >> 8, k = r & 255;
    gcnWt[idx] = (short)f2bf(gcn_W[l * 65536 + k * 256 + n]);
  } else {
    int j = idx - 3 * 65536;  // n*128+k
    int n = j >> 7, k = j & 127;
    projWt[j] = (short)f2bf(proj_W[k * 256 + n]);
  }
}

// ---------------- edge message aggregate: wave/node, reg weights, unroll-4 --
__global__ void __launch_bounds__(256) edge_msg_kernel(
    const float* __restrict__ edge_attr, const int* __restrict__ eids,
    const int* __restrict__ rowstart,
    const float* __restrict__ edge_W, const float* __restrict__ edge_b,
    unsigned* __restrict__ msg128u, int N) {
  int lane = threadIdx.x & 63;
  int node = blockIdx.x * 4 + (threadIdx.x >> 6);
  if (node >= N) return;
  int ch0 = lane * 2;  // lane owns channels ch0, ch0+1
  float wa[8], wb[8];
#pragma unroll
  for (int k = 0; k < 8; k++) {
    float2 w = *(const float2*)&edge_W[k * 128 + ch0];
    wa[k] = w.x; wb[k] = w.y;
  }
  float2 bb = *(const float2*)&edge_b[ch0];
  float acc0 = 0.f, acc1 = 0.f;
  int s = rowstart[node], s1 = rowstart[node + 1];
  const float4* ea4 = (const float4*)edge_attr;
  for (; s + 4 <= s1; s += 4) {
    int e0 = eids[s], e1 = eids[s + 1], e2 = eids[s + 2], e3 = eids[s + 3];
    float4 a00 = ea4[(size_t)e0 * 2], a01 = ea4[(size_t)e0 * 2 + 1];
    float4 a10 = ea4[(size_t)e1 * 2], a11 = ea4[(size_t)e1 * 2 + 1];
    float4 a20 = ea4[(size_t)e2 * 2], a21 = ea4[(size_t)e2 * 2 + 1];
    float4 a30 = ea4[(size_t)e3 * 2], a31 = ea4[(size_t)e3 * 2 + 1];
    float t0, t1;
#define EMLP(lo, hi)                                                        \
    t0 = bb.x; t1 = bb.y;                                                   \
    t0 = fmaf(lo.x, wa[0], t0); t1 = fmaf(lo.x, wb[0], t1);                 \
    t0 = fmaf(lo.y, wa[1], t0); t1 = fmaf(lo.y, wb[1], t1);                 \
    t0 = fmaf(lo.z, wa[2], t0); t1 = fmaf(lo.z, wb[2], t1);                 \
    t0 = fmaf(lo.w, wa[3], t0); t1 = fmaf(lo.w, wb[3], t1);                 \
    t0 = fmaf(hi.x, wa[4], t0); t1 = fmaf(hi.x, wb[4], t1);                 \
    t0 = fmaf(hi.y, wa[5], t0); t1 = fmaf(hi.y, wb[5], t1);                 \
    t0 = fmaf(hi.z, wa[6], t0); t1 = fmaf(hi.z, wb[6], t1);                 \
    t0 = fmaf(hi.w, wa[7], t0); t1 = fmaf(hi.w, wb[7], t1);                 \
    acc0 += fmaxf(t0, 0.f); acc1 += fmaxf(t1, 0.f);
    EMLP(a00, a01)
    EMLP(a10, a11)
    EMLP(a20, a21)
    EMLP(a30, a31)
  }
  for (; s < s1; s++) {
    int e = eids[s];
    float4 lo = ea4[(size_t)e * 2], hi = ea4[(size_t)e * 2 + 1];
    float t0, t1;
    EMLP(lo, hi)
  }
#undef EMLP
  msg128u[(size_t)node * 64 + lane] = pk2(acc0, acc1);
}

// ---------------- proj via MFMA: node_msg = msg128@projW + cnt*pb (bf16) ---
__global__ void __launch_bounds__(256) proj_gemm_mfma(
    const short* __restrict__ msg128, const short* __restrict__ projWt,
    const float* __restrict__ proj_b, const int* __restrict__ cnt,
    short* __restrict__ node_msg, int N) {
  __shared__ short As[64][136];
  int tid = threadIdx.x;
  int n0 = blockIdx.x * 64;
  for (int i = tid; i < 64 * 32; i += 256) {
    int r = i >> 5, c4 = (i & 31) << 2;
    int n = n0 + r;
    uint2 v = make_uint2(0, 0);
    if (n < N) v = *(const uint2*)&msg128[(size_t)n * 128 + c4];
    *(uint2*)&As[r][c4] = v;
  }
  __syncthreads();
  int wave = tid >> 6, lane = tid & 63;
  int mrow = wave * 16 + (lane & 15);
  int kgrp = (lane >> 4) * 8;
  f32x4 acc[16];
#pragma unroll
  for (int i = 0; i < 16; i++) acc[i] = (f32x4){0.f, 0.f, 0.f, 0.f};
  const short* wbase = projWt + (size_t)(lane & 15) * 128 + kgrp;
#pragma unroll
  for (int kk = 0; kk < 4; kk++) {
    s16x8 a = *(const s16x8*)&As[mrow][kk * 32 + kgrp];
#pragma unroll
    for (int nf = 0; nf < 16; nf++) {
      s16x8 b = *(const s16x8*)&wbase[(size_t)nf * 16 * 128 + kk * 32];
      acc[nf] = __builtin_amdgcn_mfma_f32_16x16x32_bf16(a, b, acc[nf], 0, 0, 0);
    }
  }
  int orow0 = wave * 16 + (lane >> 4) * 4;
  int ocol = lane & 15;
#pragma unroll
  for (int r = 0; r < 4; r++) {
    int n = n0 + orow0 + r;
    if (n < N) {
      float cn = (float)cnt[n];
#pragma unroll
      for (int nf = 0; nf < 16; nf++) {
        int c = nf * 16 + ocol;
        node_msg[(size_t)n * 256 + c] = (short)f2bf(acc[nf][r] + cn * proj_b[c]);
      }
    }
  }
}

// ---------------- GEMM0: h = (x0 + node_msg) @ W0 (add in LDS staging) -----
__global__ void __launch_bounds__(256) gcn_gemm_add_mfma(
    const short* __restrict__ X, const short* __restrict__ M,
    const short* __restrict__ Wt, short* __restrict__ Hout, int N) {
  __shared__ short As[64][264];
  int tid = threadIdx.x;
  int n0 = blockIdx.x * 64;
  for (int i = tid; i < 64 * 64; i += 256) {
    int r = i >> 6, c4 = (i & 63) << 2;
    int n = n0 + r;
    uint2 o = make_uint2(0, 0);
    if (n < N) {
      uint2 xv = *(const uint2*)&X[(size_t)n * 256 + c4];
      uint2 mv = *(const uint2*)&M[(size_t)n * 256 + c4];
      o.x = pk2(blo(xv.x) + blo(mv.x), bhi(xv.x) + bhi(mv.x));
      o.y = pk2(blo(xv.y) + blo(mv.y), bhi(xv.y) + bhi(mv.y));
    }
    *(uint2*)&As[r][c4] = o;
  }
  __syncthreads();
  int wave = tid >> 6, lane = tid & 63;
  int mrow = wave * 16 + (lane & 15);
  int kgrp = (lane >> 4) * 8;
  f32x4 acc[16];
#pragma unroll
  for (int i = 0; i < 16; i++) acc[i] = (f32x4){0.f, 0.f, 0.f, 0.f};
  const short* wbase = Wt + (size_t)(lane & 15) * 256 + kgrp;
#pragma unroll
  for (int kk = 0; kk < 8; kk++) {
    s16x8 a = *(const s16x8*)&As[mrow][kk * 32 + kgrp];
#pragma unroll
    for (int nf = 0; nf < 16; nf++) {
      s16x8 b = *(const s16x8*)&wbase[(size_t)nf * 16 * 256 + kk * 32];
      acc[nf] = __builtin_amdgcn_mfma_f32_16x16x32_bf16(a, b, acc[nf], 0, 0, 0);
    }
  }
  int orow0 = wave * 16 + (lane >> 4) * 4;
  int ocol = lane & 15;
#pragma unroll
  for (int nf = 0; nf < 16; nf++) {
#pragma unroll
    for (int r = 0; r < 4; r++) {
      int n = n0 + orow0 + r;
      if (n < N) Hout[(size_t)n * 256 + nf * 16 + ocol] = (short)f2bf(acc[nf][r]);
    }
  }
}

// ---------------- aggregate (wave per node): xin = relu(agg+b)+node_msg ----
__global__ void __launch_bounds__(256) gcn_agg_kernel(
    const short* __restrict__ h, const int2* __restrict__ pk8,
    const int* __restrict__ rowstart, const float* __restrict__ dnorm,
    const float* __restrict__ b, const short* __restrict__ node_msg,
    short* __restrict__ xin, int N) {
  int lane = threadIdx.x & 63;
  int node = blockIdx.x * 4 + (threadIdx.x >> 6);
  if (node >= N) return;
  int ch0 = lane << 2;
  size_t rowb = (size_t)node * 256 + ch0;
  float dn = dnorm[node];
  float wgt = dn * dn;
  uint2 hv = *(const uint2*)&h[rowb];
  float a0 = blo(hv.x) * wgt, a1 = bhi(hv.x) * wgt;
  float a2 = blo(hv.y) * wgt, a3 = bhi(hv.y) * wgt;
  int s = rowstart[node], s1 = rowstart[node + 1];
  for (; s + 4 <= s1; s += 4) {
    int2 p0 = pk8[s], p1 = pk8[s + 1], p2 = pk8[s + 2], p3 = pk8[s + 3];
    float f0 = __int_as_float(p0.y), f1 = __int_as_float(p1.y);
    float f2 = __int_as_float(p2.y), f3 = __int_as_float(p3.y);
    uint2 v0 = *(const uint2*)&h[(size_t)p0.x * 256 + ch0];
    uint2 v1 = *(const uint2*)&h[(size_t)p1.x * 256 + ch0];
    uint2 v2 = *(const uint2*)&h[(size_t)p2.x * 256 + ch0];
    uint2 v3 = *(const uint2*)&h[(size_t)p3.x * 256 + ch0];
    a0 = fmaf(blo(v0.x), f0, a0); a1 = fmaf(bhi(v0.x), f0, a1);
    a2 = fmaf(blo(v0.y), f0, a2); a3 = fmaf(bhi(v0.y), f0, a3);
    a0 = fmaf(blo(v1.x), f1, a0); a1 = fmaf(bhi(v1.x), f1, a1);
    a2 = fmaf(blo(v1.y), f1, a2); a3 = fmaf(bhi(v1.y), f1, a3);
    a0 = fmaf(blo(v2.x), f2, a0); a1 = fmaf(bhi(v2.x), f2, a1);
    a2 = fmaf(blo(v2.y), f2, a2); a3 = fmaf(bhi(v2.y), f2, a3);
    a0 = fmaf(blo(v3.x), f3, a0); a1 = fmaf(bhi(v3.x), f3, a1);
    a2 = fmaf(blo(v3.y), f3, a2); a3 = fmaf(bhi(v3.y), f3, a3);
  }
  for (; s < s1; s++) {
    int2 p = pk8[s];
    float f = __int_as_float(p.y);
    uint2 v = *(const uint2*)&h[(size_t)p.x * 256 + ch0];
    a0 = fmaf(blo(v.x), f, a0); a1 = fmaf(bhi(v.x), f, a1);
    a2 = fmaf(blo(v.y), f, a2); a3 = fmaf(bhi(v.y), f, a3);
  }
  float4 bv = *(const float4*)&b[ch0];
  uint2 mv = *(const uint2*)&node_msg[rowb];
  float y0 = fmaxf(a0 + bv.x, 0.f) + blo(mv.x);
  float y1 = fmaxf(a1 + bv.y, 0.f) + bhi(mv.x);
  float y2 = fmaxf(a2 + bv.z, 0.f) + blo(mv.y);
  float y3 = fmaxf(a3 + bv.w, 0.f) + bhi(mv.y);
  uint2 o;
  o.x = pk2(y0, y1);
  o.y = pk2(y2, y3);
  *(uint2*)&xin[rowb] = o;
}

// ---------------- GCN GEMM via bf16 MFMA: h = xin @ W ----------------
__global__ void __launch_bounds__(256) gcn_gemm_mfma(
    const short* __restrict__ Xin, const short* __restrict__ Wt,
    short* __restrict__ Hout, int N) {
  __shared__ short As[64][264];
  int tid = threadIdx.x;
  int n0 = blockIdx.x * 64;
  for (int i = tid; i < 64 * 64; i += 256) {
    int r = i >> 6, c4 = (i & 63) << 2;
    int n = n0 + r;
    uint2 v = make_uint2(0, 0);
    if (n < N) v = *(const uint2*)&Xin[(size_t)n * 256 + c4];
    *(uint2*)&As[r][c4] = v;
  }
  __syncthreads();
  int wave = tid >> 6, lane = tid & 63;
  int mrow = wave * 16 + (lane & 15);
  int kgrp = (lane >> 4) * 8;
  f32x4 acc[16];
#pragma unroll
  for (int i = 0; i < 16; i++) acc[i] = (f32x4){0.f, 0.f, 0.f, 0.f};
  const short* wbase = Wt + (size_t)(lane & 15) * 256 + kgrp;
#pragma unroll
  for (int kk = 0; kk < 8; kk++) {
    s16x8 a = *(const s16x8*)&As[mrow][kk * 32 + kgrp];
#pragma unroll
    for (int nf = 0; nf < 16; nf++) {
      s16x8 b = *(const s16x8*)&wbase[(size_t)nf * 16 * 256 + kk * 32];
      acc[nf] = __builtin_amdgcn_mfma_f32_16x16x32_bf16(a, b, acc[nf], 0, 0, 0);
    }
  }
  int orow0 = wave * 16 + (lane >> 4) * 4;
  int ocol = lane & 15;
#pragma unroll
  for (int nf = 0; nf < 16; nf++) {
#pragma unroll
    for (int r = 0; r < 4; r++) {
      int n = n0 + orow0 + r;
      if (n < N) Hout[(size_t)n * 256 + nf * 16 + ocol] = (short)f2bf(acc[nf][r]);
    }
  }
}

// ---------------- final aggregate -> x_emb bf16 + scores ----------------
__global__ void __launch_bounds__(256) final_agg_kernel(
    const short* __restrict__ h, const int2* __restrict__ pk8,
    const int* __restrict__ rowstart, const float* __restrict__ dnorm,
    const float* __restrict__ b, short* __restrict__ x_emb,
    const float* __restrict__ attn_w, const float* __restrict__ attn_b,
    float* __restrict__ scores, int N) {
  int lane = threadIdx.x & 63;
  int node = blockIdx.x * 4 + (threadIdx.x >> 6);
  if (node >= N) return;
  int ch0 = lane << 2;
  size_t rowb = (size_t)node * 256 + ch0;
  float dn = dnorm[node];
  float wgt = dn * dn;
  uint2 hv = *(const uint2*)&h[rowb];
  float a0 = blo(hv.x) * wgt, a1 = bhi(hv.x) * wgt;
  float a2 = blo(hv.y) * wgt, a3 = bhi(hv.y) * wgt;
  int s = rowstart[node], s1 = rowstart[node + 1];
  for (; s + 4 <= s1; s += 4) {
    int2 p0 = pk8[s], p1 = pk8[s + 1], p2 = pk8[s + 2], p3 = pk8[s + 3];
    float f0 = __int_as_float(p0.y), f1 = __int_as_float(p1.y);
    float f2 = __int_as_float(p2.y), f3 = __int_as_float(p3.y);
    uint2 v0 = *(const uint2*)&h[(size_t)p0.x * 256 + ch0];
    uint2 v1 = *(const uint2*)&h[(size_t)p1.x * 256 + ch0];
    uint2 v2 = *(const uint2*)&h[(size_t)p2.x * 256 + ch0];
    uint2 v3 = *(const uint2*)&h[(size_t)p3.x * 256 + ch0];
    a0 = fmaf(blo(v0.x), f0, a0); a1 = fmaf(bhi(v0.x), f0, a1);
    a2 = fmaf(blo(v0.y), f0, a2); a3 = fmaf(bhi(v0.y), f0, a3);
    a0 = fmaf(blo(v1.x), f1, a0); a1 = fmaf(bhi(v1.x), f1, a1);
    a2 = fmaf(blo(v1.y), f1, a2); a3 = fmaf(bhi(v1.y), f1, a3);
    a0 = fmaf(blo(v2.x), f2, a0); a1 = fmaf(bhi(v2.x), f2, a1);
    a2 = fmaf(blo(v2.y), f2, a2); a3 = fmaf(bhi(v2.y), f2, a3);
    a0 = fmaf(blo(v3.x), f3, a0); a1 = fmaf(bhi(v3.x), f3, a1);
    a2 = fmaf(blo(v3.y), f3, a2); a3 = fmaf(bhi(v3.y), f3, a3);
  }
  for (; s < s1; s++) {
    int2 p = pk8[s];
    float f = __int_as_float(p.y);
    uint2 v = *(const uint2*)&h[(size_t)p.x * 256 + ch0];
    a0 = fmaf(blo(v.x), f, a0); a1 = fmaf(bhi(v.x), f, a1);
    a2 = fmaf(blo(v.y), f, a2); a3 = fmaf(bhi(v.y), f, a3);
  }
  float4 bv = *(const float4*)&b[ch0];
  a0 += bv.x; a1 += bv.y; a2 += bv.z; a3 += bv.w;
  uint2 o;
  o.x = pk2(a0, a1);
  o.y = pk2(a2, a3);
  *(uint2*)&x_emb[rowb] = o;
  float4 aw = *(const float4*)&attn_w[ch0];
  float p = a0 * aw.x + a1 * aw.y + a2 * aw.z + a3 * aw.w;
#pragma unroll
  for (int off = 32; off; off >>= 1) p += __shfl_down(p, off);
  if (lane == 0) scores[node] = p + attn_b[0];
}

// ---------------- graph segment boundaries (batch sorted) ----------------
__global__ void gse_kernel(const int* __restrict__ batch, int* __restrict__ gs,
                           int* __restrict__ ge, int N) {
  int i = blockIdx.x * 256 + threadIdx.x;
  if (i >= N) return;
  int g = batch[i];
  if (i == 0) gs[g] = 0;
  else {
    int gp = batch[i - 1];
    if (gp != g) { gs[g] = i; ge[gp] = i - 1; }
  }
  if (i == N - 1) ge[g] = N - 1;
}

__global__ void softmax_kernel(const float* __restrict__ scores, const int* __restrict__ gs,
                               const int* __restrict__ ge, float* __restrict__ wnode) {
  int g = blockIdx.x;
  int tid = threadIdx.x;  // 256
  __shared__ float red[256];
  int s0 = gs[g], e1 = ge[g];
  if (s0 > e1) return;
  int s1 = e1 + 1;
  float m = -1e30f;
  for (int i = s0 + tid; i < s1; i += 256) m = fmaxf(m, scores[i]);
  red[tid] = m;
  __syncthreads();
  for (int off = 128; off; off >>= 1) {
    if (tid < off) red[tid] = fmaxf(red[tid], red[tid + off]);
    __syncthreads();
  }
  m = red[0];
  __syncthreads();
  float d = 0.f;
  for (int i = s0 + tid; i < s1; i += 256) d += expf(scores[i] - m);
  red[tid] = d;
  __syncthreads();
  for (int off = 128; off; off >>= 1) {
    if (tid < off) red[tid] += red[tid + off];
    __syncthreads();
  }
  float rd = 1.f / red[0];
  for (int i = s0 + tid; i < s1; i += 256) wnode[i] = expf(scores[i] - m) * rd;
}

__global__ void __launch_bounds__(256) pool_sum_kernel(
    const short* __restrict__ x_emb, const float* __restrict__ wnode,
    const int* __restrict__ batch, float* __restrict__ graph_emb, int N) {
  __shared__ int sb[256];
  __shared__ float sw[256];
  int ch = threadIdx.x;
  int i0 = blockIdx.x * 256;
  int lim = min(256, N - i0);
  if (ch < lim) { sb[ch] = batch[i0 + ch]; sw[ch] = wnode[i0 + ch]; }
  __syncthreads();
  int curg = sb[0];
  float acc = 0.f;
  for (int j = 0; j < lim; j++) {
    int g = sb[j];
    if (g != curg) {
      atomicAdd(&graph_emb[(size_t)curg * 256 + ch], acc);
      acc = 0.f;
      curg = g;
    }
    acc = fmaf(bf2f((unsigned short)x_emb[(size_t)(i0 + j) * 256 + ch]), sw[j], acc);
  }
  atomicAdd(&graph_emb[(size_t)curg * 256 + ch], acc);
}

// ---------------- head ----------------
__global__ void head_kernel(const float* __restrict__ global_x, const float* __restrict__ graph_emb,
                            const float* __restrict__ W1, const float* __restrict__ b1,
                            const float* __restrict__ W2, const float* __restrict__ b2,
                            const float* __restrict__ fW1, const float* __restrict__ fb1,
                            const float* __restrict__ fW2, const float* __restrict__ fb2,
                            float* __restrict__ out) {
  int g = blockIdx.x;
  int ch = threadIdx.x;  // 256
  __shared__ float t1[256], g2s[256], t3s[256];
  float a = b1[ch];
  const float* gx = global_x + g * 16;
#pragma unroll
  for (int k = 0; k < 16; k++) a = fmaf(gx[k], W1[k * 256 + ch], a);
  t1[ch] = fmaxf(a, 0.f);
  __syncthreads();
  float bb = b2[ch];
  for (int k = 0; k < 256; k++) bb = fmaf(t1[k], W2[k * 256 + ch], bb);
  g2s[ch] = bb;
  __syncthreads();
  float c = fb1[ch];
  const float* ger = graph_emb + (size_t)g * 256;
  for (int k = 0; k < 256; k++) c = fmaf(ger[k], fW1[k * 256 + ch], c);
  for (int k = 0; k < 256; k++) c = fmaf(g2s[k], fW1[(256 + k) * 256 + ch], c);
  t3s[ch] = fmaxf(c, 0.f);
  __syncthreads();
  t1[ch] = t3s[ch] * fW2[ch];
  __syncthreads();
  for (int off = 128; off; off >>= 1) {
    if (ch < off) t1[ch] += t1[ch + off];
    __syncthreads();
  }
  if (ch == 0) out[g] = t1[0] + fb2[0];
}

// ---------------- launch ----------------
extern "C" void kernel_launch(void* const* d_in, const int* in_sizes, int n_in,
                              void* d_out, int out_size, void* d_ws, size_t ws_size,
                              hipStream_t stream) {
  const float* x        = (const float*)d_in[0];
  const int*   ei       = (const int*)d_in[1];
  const int*   batch    = (const int*)d_in[2];
  const float* edge_attr= (const float*)d_in[3];
  const float* global_x = (const float*)d_in[4];
  const float* coord_W  = (const float*)d_in[5];
  const float* coord_b  = (const float*)d_in[6];
  const float* node_W   = (const float*)d_in[7];
  const float* node_b   = (const float*)d_in[8];
  const float* edge_W   = (const float*)d_in[9];
  const float* edge_b   = (const float*)d_in[10];
  const float* proj_W   = (const float*)d_in[11];
  const float* proj_b   = (const float*)d_in[12];
  const float* gcn_W    = (const float*)d_in[13];
  const float* gcn_b    = (const float*)d_in[14];
  const float* attn_w   = (const float*)d_in[15];
  const float* attn_b   = (const float*)d_in[16];
  const float* gmlp_W1  = (const float*)d_in[17];
  const float* gmlp_b1  = (const float*)d_in[18];
  const float* gmlp_W2  = (const float*)d_in[19];
  const float* gmlp_b2  = (const float*)d_in[20];
  const float* fc_W1    = (const float*)d_in[21];
  const float* fc_b1    = (const float*)d_in[22];
  const float* fc_W2    = (const float*)d_in[23];
  const float* fc_b2    = (const float*)d_in[24];

  const int N = in_sizes[0] / 9;
  const int E = in_sizes[3] / 8;
  const int G = in_sizes[4] / 16;
  const int NB = (N + 255) / 256;

  char* w = (char*)d_ws;
  auto alloc = [&](size_t bytes) -> char* {
    char* p = w;
    w += (bytes + 255) & ~(size_t)255;
    return p;
  };
  short* x0       = (short*)alloc((size_t)N * 256 * 2);
  short* node_msg = (short*)alloc((size_t)N * 256 * 2);
  short* hA       = (short*)alloc((size_t)N * 256 * 2);
  short* hB       = (short*)alloc((size_t)N * 256 * 2);
  short* xinBuf   = (short*)alloc((size_t)N * 256 * 2);
  short* x_emb    = (short*)alloc((size_t)N * 256 * 2);
  short* msg128   = x_emb;   // disjoint lifetime: msg128 consumed before x_emb written
  int2*  pk8      = (int2*)alloc((size_t)E * 8);
  int*   eids     = (int*)alloc((size_t)E * 4);
  short* gcnWt    = (short*)alloc((size_t)3 * 65536 * 2);
  short* projWt   = (short*)alloc((size_t)256 * 128 * 2);
  int*   cnt      = (int*)alloc((size_t)N * 4);
  int*   rowstart = (int*)alloc((size_t)(N + 1) * 4);
  int*   cursor   = (int*)alloc((size_t)N * 4);
  float* dnorm    = (float*)alloc((size_t)N * 4);
  float* scores   = (float*)alloc((size_t)N * 4);
  float* wnode    = (float*)alloc((size_t)N * 4);
  int*   partials = (int*)alloc((size_t)NB * 4);
  int*   gs       = (int*)alloc((size_t)G * 4);
  int*   ge       = (int*)alloc((size_t)G * 4);
  float* graph_emb= (float*)alloc((size_t)G * 256 * 4);

  hipMemsetAsync(cnt, 0, (size_t)N * 4, stream);
  hipMemsetAsync(gs, 0x7f, (size_t)G * 4, stream);
  hipMemsetAsync(ge, 0xff, (size_t)G * 4, stream);
  hipMemsetAsync(graph_emb, 0, (size_t)G * 256 * 4, stream);

  wt_kernel<<<(3 * 65536 + 256 * 128 + 255) / 256, 256, 0, stream>>>(gcn_W, proj_W, gcnWt, projWt);
  node_embed_kernel<<<(N + 7) / 8, 256, 0, stream>>>(
      x, coord_W, coord_b, node_W, node_b, x0, N);
  count_kernel<<<(E + 255) / 256, 256, 0, stream>>>(ei + E, cnt, E);
  breduce_kernel<<<NB, 256, 0, stream>>>(cnt, partials, N);
  scan_partials_kernel<<<1, 256, 0, stream>>>(partials, NB);
  scan_apply_kernel<<<NB, 256, 0, stream>>>(cnt, partials, rowstart, dnorm, cursor, N);
  scatter_kernel<<<(E + 255) / 256, 256, 0, stream>>>(
      ei, ei + E, rowstart, cursor, dnorm, pk8, eids, E);
  edge_msg_kernel<<<(N + 3) / 4, 256, 0, stream>>>(
      edge_attr, eids, rowstart, edge_W, edge_b, (unsigned*)msg128, N);
  proj_gemm_mfma<<<(N + 63) / 64, 256, 0, stream>>>(
      msg128, projWt, proj_b, cnt, node_msg, N);
  gcn_gemm_add_mfma<<<(N + 63) / 64, 256, 0, stream>>>(
      x0, node_msg, gcnWt, hA, N);
  // layer 1: agg(hA) -> xin ; gemm(xin, W1) -> hB
  gcn_agg_kernel<<<(N + 3) / 4, 256, 0, stream>>>(
      hA, pk8, rowstart, dnorm, gcn_b, node_msg, xinBuf, N);
  gcn_gemm_mfma<<<(N + 63) / 64, 256, 0, stream>>>(
      xinBuf, gcnWt + 65536, hB, N);
  // layer 2: agg(hB) -> xin ; gemm(xin, W2) -> hA
  gcn_agg_kernel<<<(N + 3) / 4, 256, 0, stream>>>(
      hB, pk8, rowstart, dnorm, gcn_b + 256, node_msg, xinBuf, N);
  gcn_gemm_mfma<<<(N + 63) / 64, 256, 0, stream>>>(
      xinBuf, gcnWt + 2 * 65536, hA, N);
  final_agg_kernel<<<(N + 3) / 4, 256, 0, stream>>>(
      hA, pk8, rowstart, dnorm, gcn_b + 512, x_emb, attn_w, attn_b, scores, N);
  gse_kernel<<<(N + 255) / 256, 256, 0, stream>>>(batch, gs, ge, N);
  softmax_kernel<<<G, 256, 0, stream>>>(scores, gs, ge, wnode);
  pool_sum_kernel<<<NB, 256, 0, stream>>>(x_emb, wnode, batch, graph_emb, N);
  head_kernel<<<G, 256, 0, stream>>>(global_x, graph_emb, gmlp_W1, gmlp_b1, gmlp_W2, gmlp_b2,
                                     fc_W1, fc_b1, fc_W2, fc_b2, (float*)d_out);
}

// Round 10
// 867.141 us; speedup vs baseline: 1.2171x; 1.0649x over previous
//
#include <hip/hip_runtime.h>

// GraphRegressorV2 — round 9 (resubmit after broker timeout): GEMMs
// restructured to BM=64 x BN=64 tiles with BOTH operands LDS-staged (B was
// per-fragment L2 loads -> latency-bound at 71 TF, MfmaUtil 2.6%). Grid x4
// deeper via N-split. Rest as round 8.

typedef float f32x4 __attribute__((ext_vector_type(4)));
typedef short s16x8 __attribute__((ext_vector_type(8)));

__device__ __forceinline__ unsigned short f2bf(float f) {
  union { float f; unsigned u; } v{f};
  unsigned r = v.u + 0x7fff + ((v.u >> 16) & 1);  // RNE
  return (unsigned short)(r >> 16);
}
__device__ __forceinline__ float bf2f(unsigned short s) {
  union { unsigned u; float f; } v{(unsigned)s << 16};
  return v.f;
}
__device__ __forceinline__ float blo(unsigned u) {
  union { unsigned x; float f; } v{u << 16};
  return v.f;
}
__device__ __forceinline__ float bhi(unsigned u) {
  union { unsigned x; float f; } v{u & 0xffff0000u};
  return v.f;
}
__device__ __forceinline__ unsigned pk2(float a, float b) {
  return (unsigned)f2bf(a) | ((unsigned)f2bf(b) << 16);
}

// ---------------- node embedding -> bf16 x0 ----------------
__global__ void node_embed_kernel(const float* __restrict__ x,
                                  const float* __restrict__ coord_W, const float* __restrict__ coord_b,
                                  const float* __restrict__ node_W, const float* __restrict__ node_b,
                                  short* __restrict__ x0, int N) {
  int tid = threadIdx.x;
  int node = blockIdx.x * 8 + (tid >> 5);
  if (node >= N) return;
  int ch0 = (tid & 31) * 8;
  const float* xr = x + (size_t)node * 9;
  float a[8];
  if (ch0 < 128) {
    float4 b0 = *(const float4*)&coord_b[ch0];
    float4 b1 = *(const float4*)&coord_b[ch0 + 4];
    a[0]=b0.x; a[1]=b0.y; a[2]=b0.z; a[3]=b0.w; a[4]=b1.x; a[5]=b1.y; a[6]=b1.z; a[7]=b1.w;
#pragma unroll
    for (int k = 0; k < 3; k++) {
      float xv = xr[k];
      float4 w0 = *(const float4*)&coord_W[k * 128 + ch0];
      float4 w1 = *(const float4*)&coord_W[k * 128 + ch0 + 4];
      a[0] = fmaf(xv, w0.x, a[0]); a[1] = fmaf(xv, w0.y, a[1]);
      a[2] = fmaf(xv, w0.z, a[2]); a[3] = fmaf(xv, w0.w, a[3]);
      a[4] = fmaf(xv, w1.x, a[4]); a[5] = fmaf(xv, w1.y, a[5]);
      a[6] = fmaf(xv, w1.z, a[6]); a[7] = fmaf(xv, w1.w, a[7]);
    }
  } else {
    int c0 = ch0 - 128;
    float4 b0 = *(const float4*)&node_b[c0];
    float4 b1 = *(const float4*)&node_b[c0 + 4];
    a[0]=b0.x; a[1]=b0.y; a[2]=b0.z; a[3]=b0.w; a[4]=b1.x; a[5]=b1.y; a[6]=b1.z; a[7]=b1.w;
#pragma unroll
    for (int k = 0; k < 6; k++) {
      float xv = xr[3 + k];
      float4 w0 = *(const float4*)&node_W[k * 128 + c0];
      float4 w1 = *(const float4*)&node_W[k * 128 + c0 + 4];
      a[0] = fmaf(xv, w0.x, a[0]); a[1] = fmaf(xv, w0.y, a[1]);
      a[2] = fmaf(xv, w0.z, a[2]); a[3] = fmaf(xv, w0.w, a[3]);
      a[4] = fmaf(xv, w1.x, a[4]); a[5] = fmaf(xv, w1.y, a[5]);
      a[6] = fmaf(xv, w1.z, a[6]); a[7] = fmaf(xv, w1.w, a[7]);
    }
  }
  uint4 o;
  o.x = pk2(fmaxf(a[0], 0.f), fmaxf(a[1], 0.f));
  o.y = pk2(fmaxf(a[2], 0.f), fmaxf(a[3], 0.f));
  o.z = pk2(fmaxf(a[4], 0.f), fmaxf(a[5], 0.f));
  o.w = pk2(fmaxf(a[6], 0.f), fmaxf(a[7], 0.f));
  *(uint4*)&x0[(size_t)node * 256 + ch0] = o;
}

// ---------------- CSR build ----------------
__global__ void count_kernel(const int* __restrict__ col, int* __restrict__ cnt, int E) {
  int e = blockIdx.x * 256 + threadIdx.x;
  if (e < E) atomicAdd(&cnt[col[e]], 1);
}

__global__ void breduce_kernel(const int* __restrict__ cnt, int* __restrict__ partials, int N) {
  __shared__ int red[256];
  int t = threadIdx.x;
  int i = blockIdx.x * 256 + t;
  int v = (i < N) ? cnt[i] : 0;
  red[t] = v;
  __syncthreads();
  for (int off = 128; off; off >>= 1) {
    if (t < off) red[t] += red[t + off];
    __syncthreads();
  }
  if (t == 0) partials[blockIdx.x] = red[0];
}

__global__ void scan_partials_kernel(int* __restrict__ partials, int nb) {
  __shared__ int s[1024];
  int t = threadIdx.x;
  for (int i = t; i < nb; i += 256) s[i] = partials[i];
  __syncthreads();
  if (t == 0) {
    int run = 0;
    for (int i = 0; i < nb; i++) { int c = s[i]; s[i] = run; run += c; }
  }
  __syncthreads();
  for (int i = t; i < nb; i += 256) partials[i] = s[i];
}

__global__ void scan_apply_kernel(const int* __restrict__ cnt, const int* __restrict__ partials,
                                  int* __restrict__ rowstart, float* __restrict__ dnorm,
                                  int* __restrict__ cursor, int N) {
  __shared__ int red[256];
  int t = threadIdx.x;
  int i = blockIdx.x * 256 + t;
  int v = (i < N) ? cnt[i] : 0;
  red[t] = v;
  __syncthreads();
  for (int off = 1; off < 256; off <<= 1) {
    int x = (t >= off) ? red[t - off] : 0;
    __syncthreads();
    red[t] += x;
    __syncthreads();
  }
  if (i < N) {
    int ex = red[t] - v + partials[blockIdx.x];
    rowstart[i] = ex;
    dnorm[i] = rsqrtf((float)(v + 1));  // +1 self-loop
    cursor[i] = 0;
    if (i == N - 1) rowstart[N] = ex + v;
  }
}

// split CSR arrays: pk8 {row, efac_bits} (aggs), eids (edge_msg)
__global__ void scatter_kernel(const int* __restrict__ row, const int* __restrict__ col,
                               const int* __restrict__ rowstart, int* __restrict__ cursor,
                               const float* __restrict__ dnorm,
                               int2* __restrict__ pk8, int* __restrict__ eids, int E) {
  int e = blockIdx.x * 256 + threadIdx.x;
  if (e >= E) return;
  int c = col[e], r = row[e];
  int p = atomicAdd(&cursor[c], 1);
  int slot = rowstart[c] + p;
  pk8[slot] = make_int2(r, __float_as_int(dnorm[r] * dnorm[c]));
  eids[slot] = e;
}

// ---------------- weight transpose+bf16 ----------------
__global__ void wt_kernel(const float* __restrict__ gcn_W, const float* __restrict__ proj_W,
                          short* __restrict__ gcnWt, short* __restrict__ projWt) {
  int idx = blockIdx.x * 256 + threadIdx.x;
  if (idx < 3 * 65536) {
    int l = idx >> 16, r = idx & 65535, n = r >> 8, k = r & 255;
    gcnWt[idx] = (short)f2bf(gcn_W[l * 65536 + k * 256 + n]);
  } else {
    int j = idx - 3 * 65536;  // n*128+k
    int n = j >> 7, k = j & 127;
    projWt[j] = (short)f2bf(proj_W[k * 256 + n]);
  }
}

// ---------------- edge message aggregate: wave/node, reg weights, unroll-4 --
__global__ void __launch_bounds__(256) edge_msg_kernel(
    const float* __restrict__ edge_attr, const int* __restrict__ eids,
    const int* __restrict__ rowstart,
    const float* __restrict__ edge_W, const float* __restrict__ edge_b,
    unsigned* __restrict__ msg128u, int N) {
  int lane = threadIdx.x & 63;
  int node = blockIdx.x * 4 + (threadIdx.x >> 6);
  if (node >= N) return;
  int ch0 = lane * 2;
  float wa[8], wb[8];
#pragma unroll
  for (int k = 0; k < 8; k++) {
    float2 w = *(const float2*)&edge_W[k * 128 + ch0];
    wa[k] = w.x; wb[k] = w.y;
  }
  float2 bb = *(const float2*)&edge_b[ch0];
  float acc0 = 0.f, acc1 = 0.f;
  int s = rowstart[node], s1 = rowstart[node + 1];
  const float4* ea4 = (const float4*)edge_attr;
  for (; s + 4 <= s1; s += 4) {
    int e0 = eids[s], e1 = eids[s + 1], e2 = eids[s + 2], e3 = eids[s + 3];
    float4 a00 = ea4[(size_t)e0 * 2], a01 = ea4[(size_t)e0 * 2 + 1];
    float4 a10 = ea4[(size_t)e1 * 2], a11 = ea4[(size_t)e1 * 2 + 1];
    float4 a20 = ea4[(size_t)e2 * 2], a21 = ea4[(size_t)e2 * 2 + 1];
    float4 a30 = ea4[(size_t)e3 * 2], a31 = ea4[(size_t)e3 * 2 + 1];
    float t0, t1;
#define EMLP(lo, hi)                                                        \
    t0 = bb.x; t1 = bb.y;                                                   \
    t0 = fmaf(lo.x, wa[0], t0); t1 = fmaf(lo.x, wb[0], t1);                 \
    t0 = fmaf(lo.y, wa[1], t0); t1 = fmaf(lo.y, wb[1], t1);                 \
    t0 = fmaf(lo.z, wa[2], t0); t1 = fmaf(lo.z, wb[2], t1);                 \
    t0 = fmaf(lo.w, wa[3], t0); t1 = fmaf(lo.w, wb[3], t1);                 \
    t0 = fmaf(hi.x, wa[4], t0); t1 = fmaf(hi.x, wb[4], t1);                 \
    t0 = fmaf(hi.y, wa[5], t0); t1 = fmaf(hi.y, wb[5], t1);                 \
    t0 = fmaf(hi.z, wa[6], t0); t1 = fmaf(hi.z, wb[6], t1);                 \
    t0 = fmaf(hi.w, wa[7], t0); t1 = fmaf(hi.w, wb[7], t1);                 \
    acc0 += fmaxf(t0, 0.f); acc1 += fmaxf(t1, 0.f);
    EMLP(a00, a01)
    EMLP(a10, a11)
    EMLP(a20, a21)
    EMLP(a30, a31)
  }
  for (; s < s1; s++) {
    int e = eids[s];
    float4 lo = ea4[(size_t)e * 2], hi = ea4[(size_t)e * 2 + 1];
    float t0, t1;
    EMLP(lo, hi)
  }
#undef EMLP
  msg128u[(size_t)node * 64 + lane] = pk2(acc0, acc1);
}

// ---------------- proj via MFMA (BM=64 x BN=64, A+B in LDS, K=128) ---------
__global__ void __launch_bounds__(256) proj_gemm_mfma(
    const short* __restrict__ msg128, const short* __restrict__ projWt,
    const float* __restrict__ proj_b, const int* __restrict__ cnt,
    short* __restrict__ node_msg, int N) {
  __shared__ short As[64][136];
  __shared__ short Bs[64][136];
  int tid = threadIdx.x;
  int n0 = blockIdx.x * 64;
  int cb = blockIdx.y * 64;
  for (int i = tid; i < 64 * 32; i += 256) {
    int r = i >> 5, c4 = (i & 31) << 2;
    int n = n0 + r;
    uint2 v = make_uint2(0, 0);
    if (n < N) v = *(const uint2*)&msg128[(size_t)n * 128 + c4];
    *(uint2*)&As[r][c4] = v;
    *(uint2*)&Bs[r][c4] = *(const uint2*)&projWt[(size_t)(cb + r) * 128 + c4];
  }
  __syncthreads();
  int wave = tid >> 6, lane = tid & 63;
  int mrow = wave * 16 + (lane & 15);
  int brow = lane & 15;
  int kgrp = (lane >> 4) * 8;
  f32x4 acc[4];
#pragma unroll
  for (int i = 0; i < 4; i++) acc[i] = (f32x4){0.f, 0.f, 0.f, 0.f};
#pragma unroll
  for (int kk = 0; kk < 4; kk++) {
    s16x8 a = *(const s16x8*)&As[mrow][kk * 32 + kgrp];
#pragma unroll
    for (int nf = 0; nf < 4; nf++) {
      s16x8 b = *(const s16x8*)&Bs[nf * 16 + brow][kk * 32 + kgrp];
      acc[nf] = __builtin_amdgcn_mfma_f32_16x16x32_bf16(a, b, acc[nf], 0, 0, 0);
    }
  }
  int orow0 = wave * 16 + (lane >> 4) * 4;
  int ocol = lane & 15;
#pragma unroll
  for (int r = 0; r < 4; r++) {
    int n = n0 + orow0 + r;
    if (n < N) {
      float cn = (float)cnt[n];
#pragma unroll
      for (int nf = 0; nf < 4; nf++) {
        int c = cb + nf * 16 + ocol;
        node_msg[(size_t)n * 256 + c] = (short)f2bf(acc[nf][r] + cn * proj_b[c]);
      }
    }
  }
}

// ---------------- GEMM0: h = (x0+node_msg) @ W0 (BM=64 x BN=64, LDS A+B) ---
__global__ void __launch_bounds__(256) gcn_gemm_add_mfma(
    const short* __restrict__ X, const short* __restrict__ M,
    const short* __restrict__ Wt, short* __restrict__ Hout, int N) {
  __shared__ short As[64][264];
  __shared__ short Bs[64][264];
  int tid = threadIdx.x;
  int n0 = blockIdx.x * 64;
  int cb = blockIdx.y * 64;
  for (int i = tid; i < 64 * 64; i += 256) {
    int r = i >> 6, c4 = (i & 63) << 2;
    int n = n0 + r;
    uint2 o = make_uint2(0, 0);
    if (n < N) {
      uint2 xv = *(const uint2*)&X[(size_t)n * 256 + c4];
      uint2 mv = *(const uint2*)&M[(size_t)n * 256 + c4];
      o.x = pk2(blo(xv.x) + blo(mv.x), bhi(xv.x) + bhi(mv.x));
      o.y = pk2(blo(xv.y) + blo(mv.y), bhi(xv.y) + bhi(mv.y));
    }
    *(uint2*)&As[r][c4] = o;
    *(uint2*)&Bs[r][c4] = *(const uint2*)&Wt[(size_t)(cb + r) * 256 + c4];
  }
  __syncthreads();
  int wave = tid >> 6, lane = tid & 63;
  int mrow = wave * 16 + (lane & 15);
  int brow = lane & 15;
  int kgrp = (lane >> 4) * 8;
  f32x4 acc[4];
#pragma unroll
  for (int i = 0; i < 4; i++) acc[i] = (f32x4){0.f, 0.f, 0.f, 0.f};
#pragma unroll
  for (int kk = 0; kk < 8; kk++) {
    s16x8 a = *(const s16x8*)&As[mrow][kk * 32 + kgrp];
#pragma unroll
    for (int nf = 0; nf < 4; nf++) {
      s16x8 b = *(const s16x8*)&Bs[nf * 16 + brow][kk * 32 + kgrp];
      acc[nf] = __builtin_amdgcn_mfma_f32_16x16x32_bf16(a, b, acc[nf], 0, 0, 0);
    }
  }
  int orow0 = wave * 16 + (lane >> 4) * 4;
  int ocol = lane & 15;
#pragma unroll
  for (int nf = 0; nf < 4; nf++) {
#pragma unroll
    for (int r = 0; r < 4; r++) {
      int n = n0 + orow0 + r;
      if (n < N) Hout[(size_t)n * 256 + cb + nf * 16 + ocol] = (short)f2bf(acc[nf][r]);
    }
  }
}

// ---------------- GCN GEMM: h = xin @ W (BM=64 x BN=64, LDS A+B) -----------
__global__ void __launch_bounds__(256) gcn_gemm_mfma(
    const short* __restrict__ Xin, const short* __restrict__ Wt,
    short* __restrict__ Hout, int N) {
  __shared__ short As[64][264];
  __shared__ short Bs[64][264];
  int tid = threadIdx.x;
  int n0 = blockIdx.x * 64;
  int cb = blockIdx.y * 64;
  for (int i = tid; i < 64 * 64; i += 256) {
    int r = i >> 6, c4 = (i & 63) << 2;
    int n = n0 + r;
    uint2 v = make_uint2(0, 0);
    if (n < N) v = *(const uint2*)&Xin[(size_t)n * 256 + c4];
    *(uint2*)&As[r][c4] = v;
    *(uint2*)&Bs[r][c4] = *(const uint2*)&Wt[(size_t)(cb + r) * 256 + c4];
  }
  __syncthreads();
  int wave = tid >> 6, lane = tid & 63;
  int mrow = wave * 16 + (lane & 15);
  int brow = lane & 15;
  int kgrp = (lane >> 4) * 8;
  f32x4 acc[4];
#pragma unroll
  for (int i = 0; i < 4; i++) acc[i] = (f32x4){0.f, 0.f, 0.f, 0.f};
#pragma unroll
  for (int kk = 0; kk < 8; kk++) {
    s16x8 a = *(const s16x8*)&As[mrow][kk * 32 + kgrp];
#pragma unroll
    for (int nf = 0; nf < 4; nf++) {
      s16x8 b = *(const s16x8*)&Bs[nf * 16 + brow][kk * 32 + kgrp];
      acc[nf] = __builtin_amdgcn_mfma_f32_16x16x32_bf16(a, b, acc[nf], 0, 0, 0);
    }
  }
  int orow0 = wave * 16 + (lane >> 4) * 4;
  int ocol = lane & 15;
#pragma unroll
  for (int nf = 0; nf < 4; nf++) {
#pragma unroll
    for (int r = 0; r < 4; r++) {
      int n = n0 + orow0 + r;
      if (n < N) Hout[(size_t)n * 256 + cb + nf * 16 + ocol] = (short)f2bf(acc[nf][r]);
    }
  }
}

// ---------------- aggregate (wave per node): xin = relu(agg+b)+node_msg ----
__global__ void __launch_bounds__(256) gcn_agg_kernel(
    const short* __restrict__ h, const int2* __restrict__ pk8,
    const int* __restrict__ rowstart, const float* __restrict__ dnorm,
    const float* __restrict__ b, const short* __restrict__ node_msg,
    short* __restrict__ xin, int N) {
  int lane = threadIdx.x & 63;
  int node = blockIdx.x * 4 + (threadIdx.x >> 6);
  if (node >= N) return;
  int ch0 = lane << 2;
  size_t rowb = (size_t)node * 256 + ch0;
  float dn = dnorm[node];
  float wgt = dn * dn;
  uint2 hv = *(const uint2*)&h[rowb];
  float a0 = blo(hv.x) * wgt, a1 = bhi(hv.x) * wgt;
  float a2 = blo(hv.y) * wgt, a3 = bhi(hv.y) * wgt;
  int s = rowstart[node], s1 = rowstart[node + 1];
  for (; s + 4 <= s1; s += 4) {
    int2 p0 = pk8[s], p1 = pk8[s + 1], p2 = pk8[s + 2], p3 = pk8[s + 3];
    float f0 = __int_as_float(p0.y), f1 = __int_as_float(p1.y);
    float f2 = __int_as_float(p2.y), f3 = __int_as_float(p3.y);
    uint2 v0 = *(const uint2*)&h[(size_t)p0.x * 256 + ch0];
    uint2 v1 = *(const uint2*)&h[(size_t)p1.x * 256 + ch0];
    uint2 v2 = *(const uint2*)&h[(size_t)p2.x * 256 + ch0];
    uint2 v3 = *(const uint2*)&h[(size_t)p3.x * 256 + ch0];
    a0 = fmaf(blo(v0.x), f0, a0); a1 = fmaf(bhi(v0.x), f0, a1);
    a2 = fmaf(blo(v0.y), f0, a2); a3 = fmaf(bhi(v0.y), f0, a3);
    a0 = fmaf(blo(v1.x), f1, a0); a1 = fmaf(bhi(v1.x), f1, a1);
    a2 = fmaf(blo(v1.y), f1, a2); a3 = fmaf(bhi(v1.y), f1, a3);
    a0 = fmaf(blo(v2.x), f2, a0); a1 = fmaf(bhi(v2.x), f2, a1);
    a2 = fmaf(blo(v2.y), f2, a2); a3 = fmaf(bhi(v2.y), f2, a3);
    a0 = fmaf(blo(v3.x), f3, a0); a1 = fmaf(bhi(v3.x), f3, a1);
    a2 = fmaf(blo(v3.y), f3, a2); a3 = fmaf(bhi(v3.y), f3, a3);
  }
  for (; s < s1; s++) {
    int2 p = pk8[s];
    float f = __int_as_float(p.y);
    uint2 v = *(const uint2*)&h[(size_t)p.x * 256 + ch0];
    a0 = fmaf(blo(v.x), f, a0); a1 = fmaf(bhi(v.x), f, a1);
    a2 = fmaf(blo(v.y), f, a2); a3 = fmaf(bhi(v.y), f, a3);
  }
  float4 bv = *(const float4*)&b[ch0];
  uint2 mv = *(const uint2*)&node_msg[rowb];
  float y0 = fmaxf(a0 + bv.x, 0.f) + blo(mv.x);
  float y1 = fmaxf(a1 + bv.y, 0.f) + bhi(mv.x);
  float y2 = fmaxf(a2 + bv.z, 0.f) + blo(mv.y);
  float y3 = fmaxf(a3 + bv.w, 0.f) + bhi(mv.y);
  uint2 o;
  o.x = pk2(y0, y1);
  o.y = pk2(y2, y3);
  *(uint2*)&xin[rowb] = o;
}

// ---------------- final aggregate -> x_emb bf16 + scores ----------------
__global__ void __launch_bounds__(256) final_agg_kernel(
    const short* __restrict__ h, const int2* __restrict__ pk8,
    const int* __restrict__ rowstart, const float* __restrict__ dnorm,
    const float* __restrict__ b, short* __restrict__ x_emb,
    const float* __restrict__ attn_w, const float* __restrict__ attn_b,
    float* __restrict__ scores, int N) {
  int lane = threadIdx.x & 63;
  int node = blockIdx.x * 4 + (threadIdx.x >> 6);
  if (node >= N) return;
  int ch0 = lane << 2;
  size_t rowb = (size_t)node * 256 + ch0;
  float dn = dnorm[node];
  float wgt = dn * dn;
  uint2 hv = *(const uint2*)&h[rowb];
  float a0 = blo(hv.x) * wgt, a1 = bhi(hv.x) * wgt;
  float a2 = blo(hv.y) * wgt, a3 = bhi(hv.y) * wgt;
  int s = rowstart[node], s1 = rowstart[node + 1];
  for (; s + 4 <= s1; s += 4) {
    int2 p0 = pk8[s], p1 = pk8[s + 1], p2 = pk8[s + 2], p3 = pk8[s + 3];
    float f0 = __int_as_float(p0.y), f1 = __int_as_float(p1.y);
    float f2 = __int_as_float(p2.y), f3 = __int_as_float(p3.y);
    uint2 v0 = *(const uint2*)&h[(size_t)p0.x * 256 + ch0];
    uint2 v1 = *(const uint2*)&h[(size_t)p1.x * 256 + ch0];
    uint2 v2 = *(const uint2*)&h[(size_t)p2.x * 256 + ch0];
    uint2 v3 = *(const uint2*)&h[(size_t)p3.x * 256 + ch0];
    a0 = fmaf(blo(v0.x), f0, a0); a1 = fmaf(bhi(v0.x), f0, a1);
    a2 = fmaf(blo(v0.y), f0, a2); a3 = fmaf(bhi(v0.y), f0, a3);
    a0 = fmaf(blo(v1.x), f1, a0); a1 = fmaf(bhi(v1.x), f1, a1);
    a2 = fmaf(blo(v1.y), f1, a2); a3 = fmaf(bhi(v1.y), f1, a3);
    a0 = fmaf(blo(v2.x), f2, a0); a1 = fmaf(bhi(v2.x), f2, a1);
    a2 = fmaf(blo(v2.y), f2, a2); a3 = fmaf(bhi(v2.y), f2, a3);
    a0 = fmaf(blo(v3.x), f3, a0); a1 = fmaf(bhi(v3.x), f3, a1);
    a2 = fmaf(blo(v3.y), f3, a2); a3 = fmaf(bhi(v3.y), f3, a3);
  }
  for (; s < s1; s++) {
    int2 p = pk8[s];
    float f = __int_as_float(p.y);
    uint2 v = *(const uint2*)&h[(size_t)p.x * 256 + ch0];
    a0 = fmaf(blo(v.x), f, a0); a1 = fmaf(bhi(v.x), f, a1);
    a2 = fmaf(blo(v.y), f, a2); a3 = fmaf(bhi(v.y), f, a3);
  }
  float4 bv = *(const float4*)&b[ch0];
  a0 += bv.x; a1 += bv.y; a2 += bv.z; a3 += bv.w;
  uint2 o;
  o.x = pk2(a0, a1);
  o.y = pk2(a2, a3);
  *(uint2*)&x_emb[rowb] = o;
  float4 aw = *(const float4*)&attn_w[ch0];
  float p = a0 * aw.x + a1 * aw.y + a2 * aw.z + a3 * aw.w;
#pragma unroll
  for (int off = 32; off; off >>= 1) p += __shfl_down(p, off);
  if (lane == 0) scores[node] = p + attn_b[0];
}

// ---------------- graph segment boundaries (batch sorted) ----------------
__global__ void gse_kernel(const int* __restrict__ batch, int* __restrict__ gs,
                           int* __restrict__ ge, int N) {
  int i = blockIdx.x * 256 + threadIdx.x;
  if (i >= N) return;
  int g = batch[i];
  if (i == 0) gs[g] = 0;
  else {
    int gp = batch[i - 1];
    if (gp != g) { gs[g] = i; ge[gp] = i - 1; }
  }
  if (i == N - 1) ge[g] = N - 1;
}

__global__ void softmax_kernel(const float* __restrict__ scores, const int* __restrict__ gs,
                               const int* __restrict__ ge, float* __restrict__ wnode) {
  int g = blockIdx.x;
  int tid = threadIdx.x;  // 256
  __shared__ float red[256];
  int s0 = gs[g], e1 = ge[g];
  if (s0 > e1) return;
  int s1 = e1 + 1;
  float m = -1e30f;
  for (int i = s0 + tid; i < s1; i += 256) m = fmaxf(m, scores[i]);
  red[tid] = m;
  __syncthreads();
  for (int off = 128; off; off >>= 1) {
    if (tid < off) red[tid] = fmaxf(red[tid], red[tid + off]);
    __syncthreads();
  }
  m = red[0];
  __syncthreads();
  float d = 0.f;
  for (int i = s0 + tid; i < s1; i += 256) d += expf(scores[i] - m);
  red[tid] = d;
  __syncthreads();
  for (int off = 128; off; off >>= 1) {
    if (tid < off) red[tid] += red[tid + off];
    __syncthreads();
  }
  float rd = 1.f / red[0];
  for (int i = s0 + tid; i < s1; i += 256) wnode[i] = expf(scores[i] - m) * rd;
}

__global__ void __launch_bounds__(256) pool_sum_kernel(
    const short* __restrict__ x_emb, const float* __restrict__ wnode,
    const int* __restrict__ batch, float* __restrict__ graph_emb, int N) {
  __shared__ int sb[256];
  __shared__ float sw[256];
  int ch = threadIdx.x;
  int i0 = blockIdx.x * 256;
  int lim = min(256, N - i0);
  if (ch < lim) { sb[ch] = batch[i0 + ch]; sw[ch] = wnode[i0 + ch]; }
  __syncthreads();
  int curg = sb[0];
  float acc = 0.f;
  for (int j = 0; j < lim; j++) {
    int g = sb[j];
    if (g != curg) {
      atomicAdd(&graph_emb[(size_t)curg * 256 + ch], acc);
      acc = 0.f;
      curg = g;
    }
    acc = fmaf(bf2f((unsigned short)x_emb[(size_t)(i0 + j) * 256 + ch]), sw[j], acc);
  }
  atomicAdd(&graph_emb[(size_t)curg * 256 + ch], acc);
}

// ---------------- head ----------------
__global__ void head_kernel(const float* __restrict__ global_x, const float* __restrict__ graph_emb,
                            const float* __restrict__ W1, const float* __restrict__ b1,
                            const float* __restrict__ W2, const float* __restrict__ b2,
                            const float* __restrict__ fW1, const float* __restrict__ fb1,
                            const float* __restrict__ fW2, const float* __restrict__ fb2,
                            float* __restrict__ out) {
  int g = blockIdx.x;
  int ch = threadIdx.x;  // 256
  __shared__ float t1[256], g2s[256], t3s[256];
  float a = b1[ch];
  const float* gx = global_x + g * 16;
#pragma unroll
  for (int k = 0; k < 16; k++) a = fmaf(gx[k], W1[k * 256 + ch], a);
  t1[ch] = fmaxf(a, 0.f);
  __syncthreads();
  float bb = b2[ch];
  for (int k = 0; k < 256; k++) bb = fmaf(t1[k], W2[k * 256 + ch], bb);
  g2s[ch] = bb;
  __syncthreads();
  float c = fb1[ch];
  const float* ger = graph_emb + (size_t)g * 256;
  for (int k = 0; k < 256; k++) c = fmaf(ger[k], fW1[k * 256 + ch], c);
  for (int k = 0; k < 256; k++) c = fmaf(g2s[k], fW1[(256 + k) * 256 + ch], c);
  t3s[ch] = fmaxf(c, 0.f);
  __syncthreads();
  t1[ch] = t3s[ch] * fW2[ch];
  __syncthreads();
  for (int off = 128; off; off >>= 1) {
    if (ch < off) t1[ch] += t1[ch + off];
    __syncthreads();
  }
  if (ch == 0) out[g] = t1[0] + fb2[0];
}

// ---------------- launch ----------------
extern "C" void kernel_launch(void* const* d_in, const int* in_sizes, int n_in,
                              void* d_out, int out_size, void* d_ws, size_t ws_size,
                              hipStream_t stream) {
  const float* x        = (const float*)d_in[0];
  const int*   ei       = (const int*)d_in[1];
  const int*   batch    = (const int*)d_in[2];
  const float* edge_attr= (const float*)d_in[3];
  const float* global_x = (const float*)d_in[4];
  const float* coord_W  = (const float*)d_in[5];
  const float* coord_b  = (const float*)d_in[6];
  const float* node_W   = (const float*)d_in[7];
  const float* node_b   = (const float*)d_in[8];
  const float* edge_W   = (const float*)d_in[9];
  const float* edge_b   = (const float*)d_in[10];
  const float* proj_W   = (const float*)d_in[11];
  const float* proj_b   = (const float*)d_in[12];
  const float* gcn_W    = (const float*)d_in[13];
  const float* gcn_b    = (const float*)d_in[14];
  const float* attn_w   = (const float*)d_in[15];
  const float* attn_b   = (const float*)d_in[16];
  const float* gmlp_W1  = (const float*)d_in[17];
  const float* gmlp_b1  = (const float*)d_in[18];
  const float* gmlp_W2  = (const float*)d_in[19];
  const float* gmlp_b2  = (const float*)d_in[20];
  const float* fc_W1    = (const float*)d_in[21];
  const float* fc_b1    = (const float*)d_in[22];
  const float* fc_W2    = (const float*)d_in[23];
  const float* fc_b2    = (const float*)d_in[24];

  const int N = in_sizes[0] / 9;
  const int E = in_sizes[3] / 8;
  const int G = in_sizes[4] / 16;
  const int NB = (N + 255) / 256;
  const int NM = (N + 63) / 64;

  char* w = (char*)d_ws;
  auto alloc = [&](size_t bytes) -> char* {
    char* p = w;
    w += (bytes + 255) & ~(size_t)255;
    return p;
  };
  short* x0       = (short*)alloc((size_t)N * 256 * 2);
  short* node_msg = (short*)alloc((size_t)N * 256 * 2);
  short* hA       = (short*)alloc((size_t)N * 256 * 2);
  short* hB       = (short*)alloc((size_t)N * 256 * 2);
  short* xinBuf   = (short*)alloc((size_t)N * 256 * 2);
  short* x_emb    = (short*)alloc((size_t)N * 256 * 2);
  short* msg128   = x_emb;   // disjoint lifetime: msg128 consumed before x_emb written
  int2*  pk8      = (int2*)alloc((size_t)E * 8);
  int*   eids     = (int*)alloc((size_t)E * 4);
  short* gcnWt    = (short*)alloc((size_t)3 * 65536 * 2);
  short* projWt   = (short*)alloc((size_t)256 * 128 * 2);
  int*   cnt      = (int*)alloc((size_t)N * 4);
  int*   rowstart = (int*)alloc((size_t)(N + 1) * 4);
  int*   cursor   = (int*)alloc((size_t)N * 4);
  float* dnorm    = (float*)alloc((size_t)N * 4);
  float* scores   = (float*)alloc((size_t)N * 4);
  float* wnode    = (float*)alloc((size_t)N * 4);
  int*   partials = (int*)alloc((size_t)NB * 4);
  int*   gs       = (int*)alloc((size_t)G * 4);
  int*   ge       = (int*)alloc((size_t)G * 4);
  float* graph_emb= (float*)alloc((size_t)G * 256 * 4);

  hipMemsetAsync(cnt, 0, (size_t)N * 4, stream);
  hipMemsetAsync(gs, 0x7f, (size_t)G * 4, stream);
  hipMemsetAsync(ge, 0xff, (size_t)G * 4, stream);
  hipMemsetAsync(graph_emb, 0, (size_t)G * 256 * 4, stream);

  wt_kernel<<<(3 * 65536 + 256 * 128 + 255) / 256, 256, 0, stream>>>(gcn_W, proj_W, gcnWt, projWt);
  node_embed_kernel<<<(N + 7) / 8, 256, 0, stream>>>(
      x, coord_W, coord_b, node_W, node_b, x0, N);
  count_kernel<<<(E + 255) / 256, 256, 0, stream>>>(ei + E, cnt, E);
  breduce_kernel<<<NB, 256, 0, stream>>>(cnt, partials, N);
  scan_partials_kernel<<<1, 256, 0, stream>>>(partials, NB);
  scan_apply_kernel<<<NB, 256, 0, stream>>>(cnt, partials, rowstart, dnorm, cursor, N);
  scatter_kernel<<<(E + 255) / 256, 256, 0, stream>>>(
      ei, ei + E, rowstart, cursor, dnorm, pk8, eids, E);
  edge_msg_kernel<<<(N + 3) / 4, 256, 0, stream>>>(
      edge_attr, eids, rowstart, edge_W, edge_b, (unsigned*)msg128, N);
  proj_gemm_mfma<<<dim3(NM, 4), 256, 0, stream>>>(
      msg128, projWt, proj_b, cnt, node_msg, N);
  gcn_gemm_add_mfma<<<dim3(NM, 4), 256, 0, stream>>>(
      x0, node_msg, gcnWt, hA, N);
  // layer 1: agg(hA) -> xin ; gemm(xin, W1) -> hB
  gcn_agg_kernel<<<(N + 3) / 4, 256, 0, stream>>>(
      hA, pk8, rowstart, dnorm, gcn_b, node_msg, xinBuf, N);
  gcn_gemm_mfma<<<dim3(NM, 4), 256, 0, stream>>>(
      xinBuf, gcnWt + 65536, hB, N);
  // layer 2: agg(hB) -> xin ; gemm(xin, W2) -> hA
  gcn_agg_kernel<<<(N + 3) / 4, 256, 0, stream>>>(
      hB, pk8, rowstart, dnorm, gcn_b + 256, node_msg, xinBuf, N);
  gcn_gemm_mfma<<<dim3(NM, 4), 256, 0, stream>>>(
      xinBuf, gcnWt + 2 * 65536, hA, N);
  final_agg_kernel<<<(N + 3) / 4, 256, 0, stream>>>(
      hA, pk8, rowstart, dnorm, gcn_b + 512, x_emb, attn_w, attn_b, scores, N);
  gse_kernel<<<(N + 255) / 256, 256, 0, stream>>>(batch, gs, ge, N);
  softmax_kernel<<<G, 256, 0, stream>>>(scores, gs, ge, wnode);
  pool_sum_kernel<<<NB, 256, 0, stream>>>(x_emb, wnode, batch, graph_emb, N);
  head_kernel<<<G, 256, 0, stream>>>(global_x, graph_emb, gmlp_W1, gmlp_b1, gmlp_W2, gmlp_b2,
                                     fc_W1, fc_b1, fc_W2, fc_b2, (float*)d_out);
}

// Round 12
// 819.580 us; speedup vs baseline: 1.2878x; 1.0580x over previous
//
#include <hip/hip_runtime.h>

// GraphRegressorV2 — round 11 (resubmit after broker timeout): GEMMs as
// BM=64 x BN=256 with B chunk-staged through LDS (4 x 64-col chunks, one Bs
// buffer) and A fragments hoisted to registers. Fixes round-10's 4x A-refetch
// (FETCH 100MB->26MB) and halves LDS-read conflict volume.

typedef float f32x4 __attribute__((ext_vector_type(4)));
typedef short s16x8 __attribute__((ext_vector_type(8)));

__device__ __forceinline__ unsigned short f2bf(float f) {
  union { float f; unsigned u; } v{f};
  unsigned r = v.u + 0x7fff + ((v.u >> 16) & 1);  // RNE
  return (unsigned short)(r >> 16);
}
__device__ __forceinline__ float bf2f(unsigned short s) {
  union { unsigned u; float f; } v{(unsigned)s << 16};
  return v.f;
}
__device__ __forceinline__ float blo(unsigned u) {
  union { unsigned x; float f; } v{u << 16};
  return v.f;
}
__device__ __forceinline__ float bhi(unsigned u) {
  union { unsigned x; float f; } v{u & 0xffff0000u};
  return v.f;
}
__device__ __forceinline__ unsigned pk2(float a, float b) {
  return (unsigned)f2bf(a) | ((unsigned)f2bf(b) << 16);
}

// ---------------- node embedding -> bf16 x0 ----------------
__global__ void node_embed_kernel(const float* __restrict__ x,
                                  const float* __restrict__ coord_W, const float* __restrict__ coord_b,
                                  const float* __restrict__ node_W, const float* __restrict__ node_b,
                                  short* __restrict__ x0, int N) {
  int tid = threadIdx.x;
  int node = blockIdx.x * 8 + (tid >> 5);
  if (node >= N) return;
  int ch0 = (tid & 31) * 8;
  const float* xr = x + (size_t)node * 9;
  float a[8];
  if (ch0 < 128) {
    float4 b0 = *(const float4*)&coord_b[ch0];
    float4 b1 = *(const float4*)&coord_b[ch0 + 4];
    a[0]=b0.x; a[1]=b0.y; a[2]=b0.z; a[3]=b0.w; a[4]=b1.x; a[5]=b1.y; a[6]=b1.z; a[7]=b1.w;
#pragma unroll
    for (int k = 0; k < 3; k++) {
      float xv = xr[k];
      float4 w0 = *(const float4*)&coord_W[k * 128 + ch0];
      float4 w1 = *(const float4*)&coord_W[k * 128 + ch0 + 4];
      a[0] = fmaf(xv, w0.x, a[0]); a[1] = fmaf(xv, w0.y, a[1]);
      a[2] = fmaf(xv, w0.z, a[2]); a[3] = fmaf(xv, w0.w, a[3]);
      a[4] = fmaf(xv, w1.x, a[4]); a[5] = fmaf(xv, w1.y, a[5]);
      a[6] = fmaf(xv, w1.z, a[6]); a[7] = fmaf(xv, w1.w, a[7]);
    }
  } else {
    int c0 = ch0 - 128;
    float4 b0 = *(const float4*)&node_b[c0];
    float4 b1 = *(const float4*)&node_b[c0 + 4];
    a[0]=b0.x; a[1]=b0.y; a[2]=b0.z; a[3]=b0.w; a[4]=b1.x; a[5]=b1.y; a[6]=b1.z; a[7]=b1.w;
#pragma unroll
    for (int k = 0; k < 6; k++) {
      float xv = xr[3 + k];
      float4 w0 = *(const float4*)&node_W[k * 128 + c0];
      float4 w1 = *(const float4*)&node_W[k * 128 + c0 + 4];
      a[0] = fmaf(xv, w0.x, a[0]); a[1] = fmaf(xv, w0.y, a[1]);
      a[2] = fmaf(xv, w0.z, a[2]); a[3] = fmaf(xv, w0.w, a[3]);
      a[4] = fmaf(xv, w1.x, a[4]); a[5] = fmaf(xv, w1.y, a[5]);
      a[6] = fmaf(xv, w1.z, a[6]); a[7] = fmaf(xv, w1.w, a[7]);
    }
  }
  uint4 o;
  o.x = pk2(fmaxf(a[0], 0.f), fmaxf(a[1], 0.f));
  o.y = pk2(fmaxf(a[2], 0.f), fmaxf(a[3], 0.f));
  o.z = pk2(fmaxf(a[4], 0.f), fmaxf(a[5], 0.f));
  o.w = pk2(fmaxf(a[6], 0.f), fmaxf(a[7], 0.f));
  *(uint4*)&x0[(size_t)node * 256 + ch0] = o;
}

// ---------------- CSR build ----------------
__global__ void count_kernel(const int* __restrict__ col, int* __restrict__ cnt, int E) {
  int e = blockIdx.x * 256 + threadIdx.x;
  if (e < E) atomicAdd(&cnt[col[e]], 1);
}

__global__ void breduce_kernel(const int* __restrict__ cnt, int* __restrict__ partials, int N) {
  __shared__ int red[256];
  int t = threadIdx.x;
  int i = blockIdx.x * 256 + t;
  int v = (i < N) ? cnt[i] : 0;
  red[t] = v;
  __syncthreads();
  for (int off = 128; off; off >>= 1) {
    if (t < off) red[t] += red[t + off];
    __syncthreads();
  }
  if (t == 0) partials[blockIdx.x] = red[0];
}

__global__ void scan_partials_kernel(int* __restrict__ partials, int nb) {
  __shared__ int s[1024];
  int t = threadIdx.x;
  for (int i = t; i < nb; i += 256) s[i] = partials[i];
  __syncthreads();
  if (t == 0) {
    int run = 0;
    for (int i = 0; i < nb; i++) { int c = s[i]; s[i] = run; run += c; }
  }
  __syncthreads();
  for (int i = t; i < nb; i += 256) partials[i] = s[i];
}

__global__ void scan_apply_kernel(const int* __restrict__ cnt, const int* __restrict__ partials,
                                  int* __restrict__ rowstart, float* __restrict__ dnorm,
                                  int* __restrict__ cursor, int N) {
  __shared__ int red[256];
  int t = threadIdx.x;
  int i = blockIdx.x * 256 + t;
  int v = (i < N) ? cnt[i] : 0;
  red[t] = v;
  __syncthreads();
  for (int off = 1; off < 256; off <<= 1) {
    int x = (t >= off) ? red[t - off] : 0;
    __syncthreads();
    red[t] += x;
    __syncthreads();
  }
  if (i < N) {
    int ex = red[t] - v + partials[blockIdx.x];
    rowstart[i] = ex;
    dnorm[i] = rsqrtf((float)(v + 1));  // +1 self-loop
    cursor[i] = 0;
    if (i == N - 1) rowstart[N] = ex + v;
  }
}

// split CSR arrays: pk8 {row, efac_bits} (aggs), eids (edge_msg)
__global__ void scatter_kernel(const int* __restrict__ row, const int* __restrict__ col,
                               const int* __restrict__ rowstart, int* __restrict__ cursor,
                               const float* __restrict__ dnorm,
                               int2* __restrict__ pk8, int* __restrict__ eids, int E) {
  int e = blockIdx.x * 256 + threadIdx.x;
  if (e >= E) return;
  int c = col[e], r = row[e];
  int p = atomicAdd(&cursor[c], 1);
  int slot = rowstart[c] + p;
  pk8[slot] = make_int2(r, __float_as_int(dnorm[r] * dnorm[c]));
  eids[slot] = e;
}

// ---------------- weight transpose+bf16 ----------------
__global__ void wt_kernel(const float* __restrict__ gcn_W, const float* __restrict__ proj_W,
                          short* __restrict__ gcnWt, short* __restrict__ projWt) {
  int idx = blockIdx.x * 256 + threadIdx.x;
  if (idx < 3 * 65536) {
    int l = idx >> 16, r = idx & 65535, n = r >> 8, k = r & 255;
    gcnWt[idx] = (short)f2bf(gcn_W[l * 65536 + k * 256 + n]);
  } else {
    int j = idx - 3 * 65536;  // n*128+k
    int n = j >> 7, k = j & 127;
    projWt[j] = (short)f2bf(proj_W[k * 256 + n]);
  }
}

// ---------------- edge message aggregate: wave/node, reg weights, unroll-4 --
__global__ void __launch_bounds__(256) edge_msg_kernel(
    const float* __restrict__ edge_attr, const int* __restrict__ eids,
    const int* __restrict__ rowstart,
    const float* __restrict__ edge_W, const float* __restrict__ edge_b,
    unsigned* __restrict__ msg128u, int N) {
  int lane = threadIdx.x & 63;
  int node = blockIdx.x * 4 + (threadIdx.x >> 6);
  if (node >= N) return;
  int ch0 = lane * 2;
  float wa[8], wb[8];
#pragma unroll
  for (int k = 0; k < 8; k++) {
    float2 w = *(const float2*)&edge_W[k * 128 + ch0];
    wa[k] = w.x; wb[k] = w.y;
  }
  float2 bb = *(const float2*)&edge_b[ch0];
  float acc0 = 0.f, acc1 = 0.f;
  int s = rowstart[node], s1 = rowstart[node + 1];
  const float4* ea4 = (const float4*)edge_attr;
  for (; s + 4 <= s1; s += 4) {
    int e0 = eids[s], e1 = eids[s + 1], e2 = eids[s + 2], e3 = eids[s + 3];
    float4 a00 = ea4[(size_t)e0 * 2], a01 = ea4[(size_t)e0 * 2 + 1];
    float4 a10 = ea4[(size_t)e1 * 2], a11 = ea4[(size_t)e1 * 2 + 1];
    float4 a20 = ea4[(size_t)e2 * 2], a21 = ea4[(size_t)e2 * 2 + 1];
    float4 a30 = ea4[(size_t)e3 * 2], a31 = ea4[(size_t)e3 * 2 + 1];
    float t0, t1;
#define EMLP(lo, hi)                                                        \
    t0 = bb.x; t1 = bb.y;                                                   \
    t0 = fmaf(lo.x, wa[0], t0); t1 = fmaf(lo.x, wb[0], t1);                 \
    t0 = fmaf(lo.y, wa[1], t0); t1 = fmaf(lo.y, wb[1], t1);                 \
    t0 = fmaf(lo.z, wa[2], t0); t1 = fmaf(lo.z, wb[2], t1);                 \
    t0 = fmaf(lo.w, wa[3], t0); t1 = fmaf(lo.w, wb[3], t1);                 \
    t0 = fmaf(hi.x, wa[4], t0); t1 = fmaf(hi.x, wb[4], t1);                 \
    t0 = fmaf(hi.y, wa[5], t0); t1 = fmaf(hi.y, wb[5], t1);                 \
    t0 = fmaf(hi.z, wa[6], t0); t1 = fmaf(hi.z, wb[6], t1);                 \
    t0 = fmaf(hi.w, wa[7], t0); t1 = fmaf(hi.w, wb[7], t1);                 \
    acc0 += fmaxf(t0, 0.f); acc1 += fmaxf(t1, 0.f);
    EMLP(a00, a01)
    EMLP(a10, a11)
    EMLP(a20, a21)
    EMLP(a30, a31)
  }
  for (; s < s1; s++) {
    int e = eids[s];
    float4 lo = ea4[(size_t)e * 2], hi = ea4[(size_t)e * 2 + 1];
    float t0, t1;
    EMLP(lo, hi)
  }
#undef EMLP
  msg128u[(size_t)node * 64 + lane] = pk2(acc0, acc1);
}

// ---------------- proj via MFMA (BM=64, BN=256, B chunked, K=128) ----------
__global__ void __launch_bounds__(256) proj_gemm_mfma(
    const short* __restrict__ msg128, const short* __restrict__ projWt,
    const float* __restrict__ proj_b, const int* __restrict__ cnt,
    short* __restrict__ node_msg, int N) {
  __shared__ short As[64][136];
  __shared__ short Bs[64][136];
  int tid = threadIdx.x;
  int n0 = blockIdx.x * 64;
  for (int i = tid; i < 64 * 32; i += 256) {
    int r = i >> 5, c4 = (i & 31) << 2;
    int n = n0 + r;
    uint2 v = make_uint2(0, 0);
    if (n < N) v = *(const uint2*)&msg128[(size_t)n * 128 + c4];
    *(uint2*)&As[r][c4] = v;
  }
  __syncthreads();
  int wave = tid >> 6, lane = tid & 63;
  int mrow = wave * 16 + (lane & 15);
  int brow = lane & 15;
  int kgrp = (lane >> 4) * 8;
  s16x8 areg[4];
#pragma unroll
  for (int kk = 0; kk < 4; kk++) areg[kk] = *(const s16x8*)&As[mrow][kk * 32 + kgrp];
  int orow0 = wave * 16 + (lane >> 4) * 4;
  int ocol = lane & 15;
  float cn[4];
#pragma unroll
  for (int r = 0; r < 4; r++) {
    int n = n0 + orow0 + r;
    cn[r] = (n < N) ? (float)cnt[n] : 0.f;
  }
  for (int cb = 0; cb < 4; cb++) {
    __syncthreads();  // prev chunk's Bs reads done (or As reads at cb=0)
    for (int i = tid; i < 64 * 32; i += 256) {
      int r = i >> 5, c4 = (i & 31) << 2;
      *(uint2*)&Bs[r][c4] = *(const uint2*)&projWt[(size_t)(cb * 64 + r) * 128 + c4];
    }
    __syncthreads();
    f32x4 acc[4];
#pragma unroll
    for (int i = 0; i < 4; i++) acc[i] = (f32x4){0.f, 0.f, 0.f, 0.f};
#pragma unroll
    for (int kk = 0; kk < 4; kk++) {
#pragma unroll
      for (int nf = 0; nf < 4; nf++) {
        s16x8 b = *(const s16x8*)&Bs[nf * 16 + brow][kk * 32 + kgrp];
        acc[nf] = __builtin_amdgcn_mfma_f32_16x16x32_bf16(areg[kk], b, acc[nf], 0, 0, 0);
      }
    }
#pragma unroll
    for (int r = 0; r < 4; r++) {
      int n = n0 + orow0 + r;
      if (n < N) {
#pragma unroll
        for (int nf = 0; nf < 4; nf++) {
          int c = cb * 64 + nf * 16 + ocol;
          node_msg[(size_t)n * 256 + c] = (short)f2bf(acc[nf][r] + cn[r] * proj_b[c]);
        }
      }
    }
  }
}

// ---------------- GEMM0: h = (x0+node_msg) @ W0 (BN=256, B chunked) --------
__global__ void __launch_bounds__(256) gcn_gemm_add_mfma(
    const short* __restrict__ X, const short* __restrict__ M,
    const short* __restrict__ Wt, short* __restrict__ Hout, int N) {
  __shared__ short As[64][264];
  __shared__ short Bs[64][264];
  int tid = threadIdx.x;
  int n0 = blockIdx.x * 64;
  for (int i = tid; i < 64 * 64; i += 256) {
    int r = i >> 6, c4 = (i & 63) << 2;
    int n = n0 + r;
    uint2 o = make_uint2(0, 0);
    if (n < N) {
      uint2 xv = *(const uint2*)&X[(size_t)n * 256 + c4];
      uint2 mv = *(const uint2*)&M[(size_t)n * 256 + c4];
      o.x = pk2(blo(xv.x) + blo(mv.x), bhi(xv.x) + bhi(mv.x));
      o.y = pk2(blo(xv.y) + blo(mv.y), bhi(xv.y) + bhi(mv.y));
    }
    *(uint2*)&As[r][c4] = o;
  }
  __syncthreads();
  int wave = tid >> 6, lane = tid & 63;
  int mrow = wave * 16 + (lane & 15);
  int brow = lane & 15;
  int kgrp = (lane >> 4) * 8;
  s16x8 areg[8];
#pragma unroll
  for (int kk = 0; kk < 8; kk++) areg[kk] = *(const s16x8*)&As[mrow][kk * 32 + kgrp];
  int orow0 = wave * 16 + (lane >> 4) * 4;
  int ocol = lane & 15;
  for (int cb = 0; cb < 4; cb++) {
    __syncthreads();
    for (int i = tid; i < 64 * 64; i += 256) {
      int r = i >> 6, c4 = (i & 63) << 2;
      *(uint2*)&Bs[r][c4] = *(const uint2*)&Wt[(size_t)(cb * 64 + r) * 256 + c4];
    }
    __syncthreads();
    f32x4 acc[4];
#pragma unroll
    for (int i = 0; i < 4; i++) acc[i] = (f32x4){0.f, 0.f, 0.f, 0.f};
#pragma unroll
    for (int kk = 0; kk < 8; kk++) {
#pragma unroll
      for (int nf = 0; nf < 4; nf++) {
        s16x8 b = *(const s16x8*)&Bs[nf * 16 + brow][kk * 32 + kgrp];
        acc[nf] = __builtin_amdgcn_mfma_f32_16x16x32_bf16(areg[kk], b, acc[nf], 0, 0, 0);
      }
    }
#pragma unroll
    for (int nf = 0; nf < 4; nf++) {
#pragma unroll
      for (int r = 0; r < 4; r++) {
        int n = n0 + orow0 + r;
        if (n < N) Hout[(size_t)n * 256 + cb * 64 + nf * 16 + ocol] = (short)f2bf(acc[nf][r]);
      }
    }
  }
}

// ---------------- GCN GEMM: h = xin @ W (BN=256, B chunked) ----------------
__global__ void __launch_bounds__(256) gcn_gemm_mfma(
    const short* __restrict__ Xin, const short* __restrict__ Wt,
    short* __restrict__ Hout, int N) {
  __shared__ short As[64][264];
  __shared__ short Bs[64][264];
  int tid = threadIdx.x;
  int n0 = blockIdx.x * 64;
  for (int i = tid; i < 64 * 64; i += 256) {
    int r = i >> 6, c4 = (i & 63) << 2;
    int n = n0 + r;
    uint2 v = make_uint2(0, 0);
    if (n < N) v = *(const uint2*)&Xin[(size_t)n * 256 + c4];
    *(uint2*)&As[r][c4] = v;
  }
  __syncthreads();
  int wave = tid >> 6, lane = tid & 63;
  int mrow = wave * 16 + (lane & 15);
  int brow = lane & 15;
  int kgrp = (lane >> 4) * 8;
  s16x8 areg[8];
#pragma unroll
  for (int kk = 0; kk < 8; kk++) areg[kk] = *(const s16x8*)&As[mrow][kk * 32 + kgrp];
  int orow0 = wave * 16 + (lane >> 4) * 4;
  int ocol = lane & 15;
  for (int cb = 0; cb < 4; cb++) {
    __syncthreads();
    for (int i = tid; i < 64 * 64; i += 256) {
      int r = i >> 6, c4 = (i & 63) << 2;
      *(uint2*)&Bs[r][c4] = *(const uint2*)&Wt[(size_t)(cb * 64 + r) * 256 + c4];
    }
    __syncthreads();
    f32x4 acc[4];
#pragma unroll
    for (int i = 0; i < 4; i++) acc[i] = (f32x4){0.f, 0.f, 0.f, 0.f};
#pragma unroll
    for (int kk = 0; kk < 8; kk++) {
#pragma unroll
      for (int nf = 0; nf < 4; nf++) {
        s16x8 b = *(const s16x8*)&Bs[nf * 16 + brow][kk * 32 + kgrp];
        acc[nf] = __builtin_amdgcn_mfma_f32_16x16x32_bf16(areg[kk], b, acc[nf], 0, 0, 0);
      }
    }
#pragma unroll
    for (int nf = 0; nf < 4; nf++) {
#pragma unroll
      for (int r = 0; r < 4; r++) {
        int n = n0 + orow0 + r;
        if (n < N) Hout[(size_t)n * 256 + cb * 64 + nf * 16 + ocol] = (short)f2bf(acc[nf][r]);
      }
    }
  }
}

// ---------------- aggregate (wave per node): xin = relu(agg+b)+node_msg ----
__global__ void __launch_bounds__(256) gcn_agg_kernel(
    const short* __restrict__ h, const int2* __restrict__ pk8,
    const int* __restrict__ rowstart, const float* __restrict__ dnorm,
    const float* __restrict__ b, const short* __restrict__ node_msg,
    short* __restrict__ xin, int N) {
  int lane = threadIdx.x & 63;
  int node = blockIdx.x * 4 + (threadIdx.x >> 6);
  if (node >= N) return;
  int ch0 = lane << 2;
  size_t rowb = (size_t)node * 256 + ch0;
  float dn = dnorm[node];
  float wgt = dn * dn;
  uint2 hv = *(const uint2*)&h[rowb];
  float a0 = blo(hv.x) * wgt, a1 = bhi(hv.x) * wgt;
  float a2 = blo(hv.y) * wgt, a3 = bhi(hv.y) * wgt;
  int s = rowstart[node], s1 = rowstart[node + 1];
  for (; s + 4 <= s1; s += 4) {
    int2 p0 = pk8[s], p1 = pk8[s + 1], p2 = pk8[s + 2], p3 = pk8[s + 3];
    float f0 = __int_as_float(p0.y), f1 = __int_as_float(p1.y);
    float f2 = __int_as_float(p2.y), f3 = __int_as_float(p3.y);
    uint2 v0 = *(const uint2*)&h[(size_t)p0.x * 256 + ch0];
    uint2 v1 = *(const uint2*)&h[(size_t)p1.x * 256 + ch0];
    uint2 v2 = *(const uint2*)&h[(size_t)p2.x * 256 + ch0];
    uint2 v3 = *(const uint2*)&h[(size_t)p3.x * 256 + ch0];
    a0 = fmaf(blo(v0.x), f0, a0); a1 = fmaf(bhi(v0.x), f0, a1);
    a2 = fmaf(blo(v0.y), f0, a2); a3 = fmaf(bhi(v0.y), f0, a3);
    a0 = fmaf(blo(v1.x), f1, a0); a1 = fmaf(bhi(v1.x), f1, a1);
    a2 = fmaf(blo(v1.y), f1, a2); a3 = fmaf(bhi(v1.y), f1, a3);
    a0 = fmaf(blo(v2.x), f2, a0); a1 = fmaf(bhi(v2.x), f2, a1);
    a2 = fmaf(blo(v2.y), f2, a2); a3 = fmaf(bhi(v2.y), f2, a3);
    a0 = fmaf(blo(v3.x), f3, a0); a1 = fmaf(bhi(v3.x), f3, a1);
    a2 = fmaf(blo(v3.y), f3, a2); a3 = fmaf(bhi(v3.y), f3, a3);
  }
  for (; s < s1; s++) {
    int2 p = pk8[s];
    float f = __int_as_float(p.y);
    uint2 v = *(const uint2*)&h[(size_t)p.x * 256 + ch0];
    a0 = fmaf(blo(v.x), f, a0); a1 = fmaf(bhi(v.x), f, a1);
    a2 = fmaf(blo(v.y), f, a2); a3 = fmaf(bhi(v.y), f, a3);
  }
  float4 bv = *(const float4*)&b[ch0];
  uint2 mv = *(const uint2*)&node_msg[rowb];
  float y0 = fmaxf(a0 + bv.x, 0.f) + blo(mv.x);
  float y1 = fmaxf(a1 + bv.y, 0.f) + bhi(mv.x);
  float y2 = fmaxf(a2 + bv.z, 0.f) + blo(mv.y);
  float y3 = fmaxf(a3 + bv.w, 0.f) + bhi(mv.y);
  uint2 o;
  o.x = pk2(y0, y1);
  o.y = pk2(y2, y3);
  *(uint2*)&xin[rowb] = o;
}

// ---------------- final aggregate -> x_emb bf16 + scores ----------------
__global__ void __launch_bounds__(256) final_agg_kernel(
    const short* __restrict__ h, const int2* __restrict__ pk8,
    const int* __restrict__ rowstart, const float* __restrict__ dnorm,
    const float* __restrict__ b, short* __restrict__ x_emb,
    const float* __restrict__ attn_w, const float* __restrict__ attn_b,
    float* __restrict__ scores, int N) {
  int lane = threadIdx.x & 63;
  int node = blockIdx.x * 4 + (threadIdx.x >> 6);
  if (node >= N) return;
  int ch0 = lane << 2;
  size_t rowb = (size_t)node * 256 + ch0;
  float dn = dnorm[node];
  float wgt = dn * dn;
  uint2 hv = *(const uint2*)&h[rowb];
  float a0 = blo(hv.x) * wgt, a1 = bhi(hv.x) * wgt;
  float a2 = blo(hv.y) * wgt, a3 = bhi(hv.y) * wgt;
  int s = rowstart[node], s1 = rowstart[node + 1];
  for (; s + 4 <= s1; s += 4) {
    int2 p0 = pk8[s], p1 = pk8[s + 1], p2 = pk8[s + 2], p3 = pk8[s + 3];
    float f0 = __int_as_float(p0.y), f1 = __int_as_float(p1.y);
    float f2 = __int_as_float(p2.y), f3 = __int_as_float(p3.y);
    uint2 v0 = *(const uint2*)&h[(size_t)p0.x * 256 + ch0];
    uint2 v1 = *(const uint2*)&h[(size_t)p1.x * 256 + ch0];
    uint2 v2 = *(const uint2*)&h[(size_t)p2.x * 256 + ch0];
    uint2 v3 = *(const uint2*)&h[(size_t)p3.x * 256 + ch0];
    a0 = fmaf(blo(v0.x), f0, a0); a1 = fmaf(bhi(v0.x), f0, a1);
    a2 = fmaf(blo(v0.y), f0, a2); a3 = fmaf(bhi(v0.y), f0, a3);
    a0 = fmaf(blo(v1.x), f1, a0); a1 = fmaf(bhi(v1.x), f1, a1);
    a2 = fmaf(blo(v1.y), f1, a2); a3 = fmaf(bhi(v1.y), f1, a3);
    a0 = fmaf(blo(v2.x), f2, a0); a1 = fmaf(bhi(v2.x), f2, a1);
    a2 = fmaf(blo(v2.y), f2, a2); a3 = fmaf(bhi(v2.y), f2, a3);
    a0 = fmaf(blo(v3.x), f3, a0); a1 = fmaf(bhi(v3.x), f3, a1);
    a2 = fmaf(blo(v3.y), f3, a2); a3 = fmaf(bhi(v3.y), f3, a3);
  }
  for (; s < s1; s++) {
    int2 p = pk8[s];
    float f = __int_as_float(p.y);
    uint2 v = *(const uint2*)&h[(size_t)p.x * 256 + ch0];
    a0 = fmaf(blo(v.x), f, a0); a1 = fmaf(bhi(v.x), f, a1);
    a2 = fmaf(blo(v.y), f, a2); a3 = fmaf(bhi(v.y), f, a3);
  }
  float4 bv = *(const float4*)&b[ch0];
  a0 += bv.x; a1 += bv.y; a2 += bv.z; a3 += bv.w;
  uint2 o;
  o.x = pk2(a0, a1);
  o.y = pk2(a2, a3);
  *(uint2*)&x_emb[rowb] = o;
  float4 aw = *(const float4*)&attn_w[ch0];
  float p = a0 * aw.x + a1 * aw.y + a2 * aw.z + a3 * aw.w;
#pragma unroll
  for (int off = 32; off; off >>= 1) p += __shfl_down(p, off);
  if (lane == 0) scores[node] = p + attn_b[0];
}

// ---------------- graph segment boundaries (batch sorted) ----------------
__global__ void gse_kernel(const int* __restrict__ batch, int* __restrict__ gs,
                           int* __restrict__ ge, int N) {
  int i = blockIdx.x * 256 + threadIdx.x;
  if (i >= N) return;
  int g = batch[i];
  if (i == 0) gs[g] = 0;
  else {
    int gp = batch[i - 1];
    if (gp != g) { gs[g] = i; ge[gp] = i - 1; }
  }
  if (i == N - 1) ge[g] = N - 1;
}

__global__ void softmax_kernel(const float* __restrict__ scores, const int* __restrict__ gs,
                               const int* __restrict__ ge, float* __restrict__ wnode) {
  int g = blockIdx.x;
  int tid = threadIdx.x;  // 256
  __shared__ float red[256];
  int s0 = gs[g], e1 = ge[g];
  if (s0 > e1) return;
  int s1 = e1 + 1;
  float m = -1e30f;
  for (int i = s0 + tid; i < s1; i += 256) m = fmaxf(m, scores[i]);
  red[tid] = m;
  __syncthreads();
  for (int off = 128; off; off >>= 1) {
    if (tid < off) red[tid] = fmaxf(red[tid], red[tid + off]);
    __syncthreads();
  }
  m = red[0];
  __syncthreads();
  float d = 0.f;
  for (int i = s0 + tid; i < s1; i += 256) d += expf(scores[i] - m);
  red[tid] = d;
  __syncthreads();
  for (int off = 128; off; off >>= 1) {
    if (tid < off) red[tid] += red[tid + off];
    __syncthreads();
  }
  float rd = 1.f / red[0];
  for (int i = s0 + tid; i < s1; i += 256) wnode[i] = expf(scores[i] - m) * rd;
}

__global__ void __launch_bounds__(256) pool_sum_kernel(
    const short* __restrict__ x_emb, const float* __restrict__ wnode,
    const int* __restrict__ batch, float* __restrict__ graph_emb, int N) {
  __shared__ int sb[256];
  __shared__ float sw[256];
  int ch = threadIdx.x;
  int i0 = blockIdx.x * 256;
  int lim = min(256, N - i0);
  if (ch < lim) { sb[ch] = batch[i0 + ch]; sw[ch] = wnode[i0 + ch]; }
  __syncthreads();
  int curg = sb[0];
  float acc = 0.f;
  for (int j = 0; j < lim; j++) {
    int g = sb[j];
    if (g != curg) {
      atomicAdd(&graph_emb[(size_t)curg * 256 + ch], acc);
      acc = 0.f;
      curg = g;
    }
    acc = fmaf(bf2f((unsigned short)x_emb[(size_t)(i0 + j) * 256 + ch]), sw[j], acc);
  }
  atomicAdd(&graph_emb[(size_t)curg * 256 + ch], acc);
}

// ---------------- head ----------------
__global__ void head_kernel(const float* __restrict__ global_x, const float* __restrict__ graph_emb,
                            const float* __restrict__ W1, const float* __restrict__ b1,
                            const float* __restrict__ W2, const float* __restrict__ b2,
                            const float* __restrict__ fW1, const float* __restrict__ fb1,
                            const float* __restrict__ fW2, const float* __restrict__ fb2,
                            float* __restrict__ out) {
  int g = blockIdx.x;
  int ch = threadIdx.x;  // 256
  __shared__ float t1[256], g2s[256], t3s[256];
  float a = b1[ch];
  const float* gx = global_x + g * 16;
#pragma unroll
  for (int k = 0; k < 16; k++) a = fmaf(gx[k], W1[k * 256 + ch], a);
  t1[ch] = fmaxf(a, 0.f);
  __syncthreads();
  float bb = b2[ch];
  for (int k = 0; k < 256; k++) bb = fmaf(t1[k], W2[k * 256 + ch], bb);
  g2s[ch] = bb;
  __syncthreads();
  float c = fb1[ch];
  const float* ger = graph_emb + (size_t)g * 256;
  for (int k = 0; k < 256; k++) c = fmaf(ger[k], fW1[k * 256 + ch], c);
  for (int k = 0; k < 256; k++) c = fmaf(g2s[k], fW1[(256 + k) * 256 + ch], c);
  t3s[ch] = fmaxf(c, 0.f);
  __syncthreads();
  t1[ch] = t3s[ch] * fW2[ch];
  __syncthreads();
  for (int off = 128; off; off >>= 1) {
    if (ch < off) t1[ch] += t1[ch + off];
    __syncthreads();
  }
  if (ch == 0) out[g] = t1[0] + fb2[0];
}

// ---------------- launch ----------------
extern "C" void kernel_launch(void* const* d_in, const int* in_sizes, int n_in,
                              void* d_out, int out_size, void* d_ws, size_t ws_size,
                              hipStream_t stream) {
  const float* x        = (const float*)d_in[0];
  const int*   ei       = (const int*)d_in[1];
  const int*   batch    = (const int*)d_in[2];
  const float* edge_attr= (const float*)d_in[3];
  const float* global_x = (const float*)d_in[4];
  const float* coord_W  = (const float*)d_in[5];
  const float* coord_b  = (const float*)d_in[6];
  const float* node_W   = (const float*)d_in[7];
  const float* node_b   = (const float*)d_in[8];
  const float* edge_W   = (const float*)d_in[9];
  const float* edge_b   = (const float*)d_in[10];
  const float* proj_W   = (const float*)d_in[11];
  const float* proj_b   = (const float*)d_in[12];
  const float* gcn_W    = (const float*)d_in[13];
  const float* gcn_b    = (const float*)d_in[14];
  const float* attn_w   = (const float*)d_in[15];
  const float* attn_b   = (const float*)d_in[16];
  const float* gmlp_W1  = (const float*)d_in[17];
  const float* gmlp_b1  = (const float*)d_in[18];
  const float* gmlp_W2  = (const float*)d_in[19];
  const float* gmlp_b2  = (const float*)d_in[20];
  const float* fc_W1    = (const float*)d_in[21];
  const float* fc_b1    = (const float*)d_in[22];
  const float* fc_W2    = (const float*)d_in[23];
  const float* fc_b2    = (const float*)d_in[24];

  const int N = in_sizes[0] / 9;
  const int E = in_sizes[3] / 8;
  const int G = in_sizes[4] / 16;
  const int NB = (N + 255) / 256;
  const int NM = (N + 63) / 64;

  char* w = (char*)d_ws;
  auto alloc = [&](size_t bytes) -> char* {
    char* p = w;
    w += (bytes + 255) & ~(size_t)255;
    return p;
  };
  short* x0       = (short*)alloc((size_t)N * 256 * 2);
  short* node_msg = (short*)alloc((size_t)N * 256 * 2);
  short* hA       = (short*)alloc((size_t)N * 256 * 2);
  short* hB       = (short*)alloc((size_t)N * 256 * 2);
  short* xinBuf   = (short*)alloc((size_t)N * 256 * 2);
  short* x_emb    = (short*)alloc((size_t)N * 256 * 2);
  short* msg128   = x_emb;   // disjoint lifetime: msg128 consumed before x_emb written
  int2*  pk8      = (int2*)alloc((size_t)E * 8);
  int*   eids     = (int*)alloc((size_t)E * 4);
  short* gcnWt    = (short*)alloc((size_t)3 * 65536 * 2);
  short* projWt   = (short*)alloc((size_t)256 * 128 * 2);
  int*   cnt      = (int*)alloc((size_t)N * 4);
  int*   rowstart = (int*)alloc((size_t)(N + 1) * 4);
  int*   cursor   = (int*)alloc((size_t)N * 4);
  float* dnorm    = (float*)alloc((size_t)N * 4);
  float* scores   = (float*)alloc((size_t)N * 4);
  float* wnode    = (float*)alloc((size_t)N * 4);
  int*   partials = (int*)alloc((size_t)NB * 4);
  int*   gs       = (int*)alloc((size_t)G * 4);
  int*   ge       = (int*)alloc((size_t)G * 4);
  float* graph_emb= (float*)alloc((size_t)G * 256 * 4);

  hipMemsetAsync(cnt, 0, (size_t)N * 4, stream);
  hipMemsetAsync(gs, 0x7f, (size_t)G * 4, stream);
  hipMemsetAsync(ge, 0xff, (size_t)G * 4, stream);
  hipMemsetAsync(graph_emb, 0, (size_t)G * 256 * 4, stream);

  wt_kernel<<<(3 * 65536 + 256 * 128 + 255) / 256, 256, 0, stream>>>(gcn_W, proj_W, gcnWt, projWt);
  node_embed_kernel<<<(N + 7) / 8, 256, 0, stream>>>(
      x, coord_W, coord_b, node_W, node_b, x0, N);
  count_kernel<<<(E + 255) / 256, 256, 0, stream>>>(ei + E, cnt, E);
  breduce_kernel<<<NB, 256, 0, stream>>>(cnt, partials, N);
  scan_partials_kernel<<<1, 256, 0, stream>>>(partials, NB);
  scan_apply_kernel<<<NB, 256, 0, stream>>>(cnt, partials, rowstart, dnorm, cursor, N);
  scatter_kernel<<<(E + 255) / 256, 256, 0, stream>>>(
      ei, ei + E, rowstart, cursor, dnorm, pk8, eids, E);
  edge_msg_kernel<<<(N + 3) / 4, 256, 0, stream>>>(
      edge_attr, eids, rowstart, edge_W, edge_b, (unsigned*)msg128, N);
  proj_gemm_mfma<<<NM, 256, 0, stream>>>(
      msg128, projWt, proj_b, cnt, node_msg, N);
  gcn_gemm_add_mfma<<<NM, 256, 0, stream>>>(
      x0, node_msg, gcnWt, hA, N);
  // layer 1: agg(hA) -> xin ; gemm(xin, W1) -> hB
  gcn_agg_kernel<<<(N + 3) / 4, 256, 0, stream>>>(
      hA, pk8, rowstart, dnorm, gcn_b, node_msg, xinBuf, N);
  gcn_gemm_mfma<<<NM, 256, 0, stream>>>(
      xinBuf, gcnWt + 65536, hB, N);
  // layer 2: agg(hB) -> xin ; gemm(xin, W2) -> hA
  gcn_agg_kernel<<<(N + 3) / 4, 256, 0, stream>>>(
      hB, pk8, rowstart, dnorm, gcn_b + 256, node_msg, xinBuf, N);
  gcn_gemm_mfma<<<NM, 256, 0, stream>>>(
      xinBuf, gcnWt + 2 * 65536, hA, N);
  final_agg_kernel<<<(N + 3) / 4, 256, 0, stream>>>(
      hA, pk8, rowstart, dnorm, gcn_b + 512, x_emb, attn_w, attn_b, scores, N);
  gse_kernel<<<(N + 255) / 256, 256, 0, stream>>>(batch, gs, ge, N);
  softmax_kernel<<<G, 256, 0, stream>>>(scores, gs, ge, wnode);
  pool_sum_kernel<<<NB, 256, 0, stream>>>(x_emb, wnode, batch, graph_emb, N);
  head_kernel<<<G, 256, 0, stream>>>(global_x, graph_emb, gmlp_W1, gmlp_b1, gmlp_W2, gmlp_b2,
                                     fc_W1, fc_b1, fc_W2, fc_b2, (float*)d_out);
}

// Round 13
// 788.058 us; speedup vs baseline: 1.3393x; 1.0400x over previous
//
#include <hip/hip_runtime.h>

// GraphRegressorV2 — round 13: edge_msg + aggs unrolled x8 (latency chains,
// VALUBusy 42% @ 77us), node_embed fused into gemm_add staging (x0 never
// materialized), gse folded into scan_apply. GEMM structure from round 12.

typedef float f32x4 __attribute__((ext_vector_type(4)));
typedef short s16x8 __attribute__((ext_vector_type(8)));

__device__ __forceinline__ unsigned short f2bf(float f) {
  union { float f; unsigned u; } v{f};
  unsigned r = v.u + 0x7fff + ((v.u >> 16) & 1);  // RNE
  return (unsigned short)(r >> 16);
}
__device__ __forceinline__ float bf2f(unsigned short s) {
  union { unsigned u; float f; } v{(unsigned)s << 16};
  return v.f;
}
__device__ __forceinline__ float blo(unsigned u) {
  union { unsigned x; float f; } v{u << 16};
  return v.f;
}
__device__ __forceinline__ float bhi(unsigned u) {
  union { unsigned x; float f; } v{u & 0xffff0000u};
  return v.f;
}
__device__ __forceinline__ unsigned pk2(float a, float b) {
  return (unsigned)f2bf(a) | ((unsigned)f2bf(b) << 16);
}

// ---------------- CSR build ----------------
__global__ void count_kernel(const int* __restrict__ col, int* __restrict__ cnt, int E) {
  int e = blockIdx.x * 256 + threadIdx.x;
  if (e < E) atomicAdd(&cnt[col[e]], 1);
}

__global__ void breduce_kernel(const int* __restrict__ cnt, int* __restrict__ partials, int N) {
  __shared__ int red[256];
  int t = threadIdx.x;
  int i = blockIdx.x * 256 + t;
  int v = (i < N) ? cnt[i] : 0;
  red[t] = v;
  __syncthreads();
  for (int off = 128; off; off >>= 1) {
    if (t < off) red[t] += red[t + off];
    __syncthreads();
  }
  if (t == 0) partials[blockIdx.x] = red[0];
}

__global__ void scan_partials_kernel(int* __restrict__ partials, int nb) {
  __shared__ int s[1024];
  int t = threadIdx.x;
  for (int i = t; i < nb; i += 256) s[i] = partials[i];
  __syncthreads();
  if (t == 0) {
    int run = 0;
    for (int i = 0; i < nb; i++) { int c = s[i]; s[i] = run; run += c; }
  }
  __syncthreads();
  for (int i = t; i < nb; i += 256) partials[i] = s[i];
}

// exclusive scan + dnorm/cursor init + graph segment boundaries (batch sorted)
__global__ void scan_apply_kernel(const int* __restrict__ cnt, const int* __restrict__ partials,
                                  int* __restrict__ rowstart, float* __restrict__ dnorm,
                                  int* __restrict__ cursor,
                                  const int* __restrict__ batch, int* __restrict__ gs,
                                  int* __restrict__ ge, int N) {
  __shared__ int red[256];
  int t = threadIdx.x;
  int i = blockIdx.x * 256 + t;
  int v = (i < N) ? cnt[i] : 0;
  red[t] = v;
  __syncthreads();
  for (int off = 1; off < 256; off <<= 1) {
    int x = (t >= off) ? red[t - off] : 0;
    __syncthreads();
    red[t] += x;
    __syncthreads();
  }
  if (i < N) {
    int ex = red[t] - v + partials[blockIdx.x];
    rowstart[i] = ex;
    dnorm[i] = rsqrtf((float)(v + 1));  // +1 self-loop
    cursor[i] = 0;
    if (i == N - 1) rowstart[N] = ex + v;
    // graph boundaries
    int g = batch[i];
    if (i == 0) gs[g] = 0;
    else {
      int gp = batch[i - 1];
      if (gp != g) { gs[g] = i; ge[gp] = i - 1; }
    }
    if (i == N - 1) ge[g] = N - 1;
  }
}

// split CSR arrays: pk8 {row, efac_bits} (aggs), eids (edge_msg)
__global__ void scatter_kernel(const int* __restrict__ row, const int* __restrict__ col,
                               const int* __restrict__ rowstart, int* __restrict__ cursor,
                               const float* __restrict__ dnorm,
                               int2* __restrict__ pk8, int* __restrict__ eids, int E) {
  int e = blockIdx.x * 256 + threadIdx.x;
  if (e >= E) return;
  int c = col[e], r = row[e];
  int p = atomicAdd(&cursor[c], 1);
  int slot = rowstart[c] + p;
  pk8[slot] = make_int2(r, __float_as_int(dnorm[r] * dnorm[c]));
  eids[slot] = e;
}

// ---------------- weight transpose+bf16 ----------------
__global__ void wt_kernel(const float* __restrict__ gcn_W, const float* __restrict__ proj_W,
                          short* __restrict__ gcnWt, short* __restrict__ projWt) {
  int idx = blockIdx.x * 256 + threadIdx.x;
  if (idx < 3 * 65536) {
    int l = idx >> 16, r = idx & 65535, n = r >> 8, k = r & 255;
    gcnWt[idx] = (short)f2bf(gcn_W[l * 65536 + k * 256 + n]);
  } else {
    int j = idx - 3 * 65536;  // n*128+k
    int n = j >> 7, k = j & 127;
    projWt[j] = (short)f2bf(proj_W[k * 256 + n]);
  }
}

// ---------------- edge message aggregate: wave/node, reg weights, unroll-8 --
__global__ void __launch_bounds__(256) edge_msg_kernel(
    const float* __restrict__ edge_attr, const int* __restrict__ eids,
    const int* __restrict__ rowstart,
    const float* __restrict__ edge_W, const float* __restrict__ edge_b,
    unsigned* __restrict__ msg128u, int N) {
  int lane = threadIdx.x & 63;
  int node = blockIdx.x * 4 + (threadIdx.x >> 6);
  if (node >= N) return;
  int ch0 = lane * 2;
  float wa[8], wb[8];
#pragma unroll
  for (int k = 0; k < 8; k++) {
    float2 w = *(const float2*)&edge_W[k * 128 + ch0];
    wa[k] = w.x; wb[k] = w.y;
  }
  float2 bb = *(const float2*)&edge_b[ch0];
  float acc0 = 0.f, acc1 = 0.f;
  int s = rowstart[node], s1 = rowstart[node + 1];
  const float4* ea4 = (const float4*)edge_attr;
  float t0, t1;
#define EMLP(lo, hi)                                                        \
    t0 = bb.x; t1 = bb.y;                                                   \
    t0 = fmaf(lo.x, wa[0], t0); t1 = fmaf(lo.x, wb[0], t1);                 \
    t0 = fmaf(lo.y, wa[1], t0); t1 = fmaf(lo.y, wb[1], t1);                 \
    t0 = fmaf(lo.z, wa[2], t0); t1 = fmaf(lo.z, wb[2], t1);                 \
    t0 = fmaf(lo.w, wa[3], t0); t1 = fmaf(lo.w, wb[3], t1);                 \
    t0 = fmaf(hi.x, wa[4], t0); t1 = fmaf(hi.x, wb[4], t1);                 \
    t0 = fmaf(hi.y, wa[5], t0); t1 = fmaf(hi.y, wb[5], t1);                 \
    t0 = fmaf(hi.z, wa[6], t0); t1 = fmaf(hi.z, wb[6], t1);                 \
    t0 = fmaf(hi.w, wa[7], t0); t1 = fmaf(hi.w, wb[7], t1);                 \
    acc0 += fmaxf(t0, 0.f); acc1 += fmaxf(t1, 0.f);
  for (; s + 8 <= s1; s += 8) {
    int e0 = eids[s],     e1 = eids[s + 1], e2 = eids[s + 2], e3 = eids[s + 3];
    int e4 = eids[s + 4], e5 = eids[s + 5], e6 = eids[s + 6], e7 = eids[s + 7];
    float4 a00 = ea4[(size_t)e0 * 2], a01 = ea4[(size_t)e0 * 2 + 1];
    float4 a10 = ea4[(size_t)e1 * 2], a11 = ea4[(size_t)e1 * 2 + 1];
    float4 a20 = ea4[(size_t)e2 * 2], a21 = ea4[(size_t)e2 * 2 + 1];
    float4 a30 = ea4[(size_t)e3 * 2], a31 = ea4[(size_t)e3 * 2 + 1];
    float4 a40 = ea4[(size_t)e4 * 2], a41 = ea4[(size_t)e4 * 2 + 1];
    float4 a50 = ea4[(size_t)e5 * 2], a51 = ea4[(size_t)e5 * 2 + 1];
    float4 a60 = ea4[(size_t)e6 * 2], a61 = ea4[(size_t)e6 * 2 + 1];
    float4 a70 = ea4[(size_t)e7 * 2], a71 = ea4[(size_t)e7 * 2 + 1];
    EMLP(a00, a01) EMLP(a10, a11) EMLP(a20, a21) EMLP(a30, a31)
    EMLP(a40, a41) EMLP(a50, a51) EMLP(a60, a61) EMLP(a70, a71)
  }
  for (; s + 4 <= s1; s += 4) {
    int e0 = eids[s], e1 = eids[s + 1], e2 = eids[s + 2], e3 = eids[s + 3];
    float4 a00 = ea4[(size_t)e0 * 2], a01 = ea4[(size_t)e0 * 2 + 1];
    float4 a10 = ea4[(size_t)e1 * 2], a11 = ea4[(size_t)e1 * 2 + 1];
    float4 a20 = ea4[(size_t)e2 * 2], a21 = ea4[(size_t)e2 * 2 + 1];
    float4 a30 = ea4[(size_t)e3 * 2], a31 = ea4[(size_t)e3 * 2 + 1];
    EMLP(a00, a01) EMLP(a10, a11) EMLP(a20, a21) EMLP(a30, a31)
  }
  for (; s < s1; s++) {
    int e = eids[s];
    float4 lo = ea4[(size_t)e * 2], hi = ea4[(size_t)e * 2 + 1];
    EMLP(lo, hi)
  }
#undef EMLP
  msg128u[(size_t)node * 64 + lane] = pk2(acc0, acc1);
}

// ---------------- proj via MFMA (BM=64, BN=256, B chunked, K=128) ----------
__global__ void __launch_bounds__(256) proj_gemm_mfma(
    const short* __restrict__ msg128, const short* __restrict__ projWt,
    const float* __restrict__ proj_b, const int* __restrict__ cnt,
    short* __restrict__ node_msg, int N) {
  __shared__ short As[64][136];
  __shared__ short Bs[64][136];
  int tid = threadIdx.x;
  int n0 = blockIdx.x * 64;
  for (int i = tid; i < 64 * 32; i += 256) {
    int r = i >> 5, c4 = (i & 31) << 2;
    int n = n0 + r;
    uint2 v = make_uint2(0, 0);
    if (n < N) v = *(const uint2*)&msg128[(size_t)n * 128 + c4];
    *(uint2*)&As[r][c4] = v;
  }
  __syncthreads();
  int wave = tid >> 6, lane = tid & 63;
  int mrow = wave * 16 + (lane & 15);
  int brow = lane & 15;
  int kgrp = (lane >> 4) * 8;
  s16x8 areg[4];
#pragma unroll
  for (int kk = 0; kk < 4; kk++) areg[kk] = *(const s16x8*)&As[mrow][kk * 32 + kgrp];
  int orow0 = wave * 16 + (lane >> 4) * 4;
  int ocol = lane & 15;
  float cn[4];
#pragma unroll
  for (int r = 0; r < 4; r++) {
    int n = n0 + orow0 + r;
    cn[r] = (n < N) ? (float)cnt[n] : 0.f;
  }
  for (int cb = 0; cb < 4; cb++) {
    __syncthreads();
    for (int i = tid; i < 64 * 32; i += 256) {
      int r = i >> 5, c4 = (i & 31) << 2;
      *(uint2*)&Bs[r][c4] = *(const uint2*)&projWt[(size_t)(cb * 64 + r) * 128 + c4];
    }
    __syncthreads();
    f32x4 acc[4];
#pragma unroll
    for (int i = 0; i < 4; i++) acc[i] = (f32x4){0.f, 0.f, 0.f, 0.f};
#pragma unroll
    for (int kk = 0; kk < 4; kk++) {
#pragma unroll
      for (int nf = 0; nf < 4; nf++) {
        s16x8 b = *(const s16x8*)&Bs[nf * 16 + brow][kk * 32 + kgrp];
        acc[nf] = __builtin_amdgcn_mfma_f32_16x16x32_bf16(areg[kk], b, acc[nf], 0, 0, 0);
      }
    }
#pragma unroll
    for (int r = 0; r < 4; r++) {
      int n = n0 + orow0 + r;
      if (n < N) {
#pragma unroll
        for (int nf = 0; nf < 4; nf++) {
          int c = cb * 64 + nf * 16 + ocol;
          node_msg[(size_t)n * 256 + c] = (short)f2bf(acc[nf][r] + cn[r] * proj_b[c]);
        }
      }
    }
  }
}

// ---------------- GEMM0 + fused node embed:
// h = (relu(embed(x)) + node_msg) @ W0   (embed computed in staging)
__global__ void __launch_bounds__(256) gcn_gemm_embed_mfma(
    const float* __restrict__ x,
    const float* __restrict__ coord_W, const float* __restrict__ coord_b,
    const float* __restrict__ node_W, const float* __restrict__ node_b,
    const short* __restrict__ M, const short* __restrict__ Wt,
    short* __restrict__ Hout, int N) {
  __shared__ short As[64][264];
  __shared__ short Bs[64][264];
  int tid = threadIdx.x;
  int n0 = blockIdx.x * 64;
  for (int i = tid; i < 64 * 64; i += 256) {
    int r = i >> 6, c4 = (i & 63) << 2;
    int n = n0 + r;
    uint2 o = make_uint2(0, 0);
    if (n < N) {
      const float* xr = x + (size_t)n * 9;
      float e0, e1, e2, e3;
      if (c4 < 128) {
        float4 bb = *(const float4*)&coord_b[c4];
        e0 = bb.x; e1 = bb.y; e2 = bb.z; e3 = bb.w;
#pragma unroll
        for (int k = 0; k < 3; k++) {
          float xv = xr[k];
          float4 w = *(const float4*)&coord_W[k * 128 + c4];
          e0 = fmaf(xv, w.x, e0); e1 = fmaf(xv, w.y, e1);
          e2 = fmaf(xv, w.z, e2); e3 = fmaf(xv, w.w, e3);
        }
      } else {
        int c0 = c4 - 128;
        float4 bb = *(const float4*)&node_b[c0];
        e0 = bb.x; e1 = bb.y; e2 = bb.z; e3 = bb.w;
#pragma unroll
        for (int k = 0; k < 6; k++) {
          float xv = xr[3 + k];
          float4 w = *(const float4*)&node_W[k * 128 + c0];
          e0 = fmaf(xv, w.x, e0); e1 = fmaf(xv, w.y, e1);
          e2 = fmaf(xv, w.z, e2); e3 = fmaf(xv, w.w, e3);
        }
      }
      uint2 mv = *(const uint2*)&M[(size_t)n * 256 + c4];
      o.x = pk2(fmaxf(e0, 0.f) + blo(mv.x), fmaxf(e1, 0.f) + bhi(mv.x));
      o.y = pk2(fmaxf(e2, 0.f) + blo(mv.y), fmaxf(e3, 0.f) + bhi(mv.y));
    }
    *(uint2*)&As[r][c4] = o;
  }
  __syncthreads();
  int wave = tid >> 6, lane = tid & 63;
  int mrow = wave * 16 + (lane & 15);
  int brow = lane & 15;
  int kgrp = (lane >> 4) * 8;
  s16x8 areg[8];
#pragma unroll
  for (int kk = 0; kk < 8; kk++) areg[kk] = *(const s16x8*)&As[mrow][kk * 32 + kgrp];
  int orow0 = wave * 16 + (lane >> 4) * 4;
  int ocol = lane & 15;
  for (int cb = 0; cb < 4; cb++) {
    __syncthreads();
    for (int i = tid; i < 64 * 64; i += 256) {
      int r = i >> 6, c4 = (i & 63) << 2;
      *(uint2*)&Bs[r][c4] = *(const uint2*)&Wt[(size_t)(cb * 64 + r) * 256 + c4];
    }
    __syncthreads();
    f32x4 acc[4];
#pragma unroll
    for (int i = 0; i < 4; i++) acc[i] = (f32x4){0.f, 0.f, 0.f, 0.f};
#pragma unroll
    for (int kk = 0; kk < 8; kk++) {
#pragma unroll
      for (int nf = 0; nf < 4; nf++) {
        s16x8 b = *(const s16x8*)&Bs[nf * 16 + brow][kk * 32 + kgrp];
        acc[nf] = __builtin_amdgcn_mfma_f32_16x16x32_bf16(areg[kk], b, acc[nf], 0, 0, 0);
      }
    }
#pragma unroll
    for (int nf = 0; nf < 4; nf++) {
#pragma unroll
      for (int r = 0; r < 4; r++) {
        int n = n0 + orow0 + r;
        if (n < N) Hout[(size_t)n * 256 + cb * 64 + nf * 16 + ocol] = (short)f2bf(acc[nf][r]);
      }
    }
  }
}

// ---------------- GCN GEMM: h = xin @ W (BN=256, B chunked) ----------------
__global__ void __launch_bounds__(256) gcn_gemm_mfma(
    const short* __restrict__ Xin, const short* __restrict__ Wt,
    short* __restrict__ Hout, int N) {
  __shared__ short As[64][264];
  __shared__ short Bs[64][264];
  int tid = threadIdx.x;
  int n0 = blockIdx.x * 64;
  for (int i = tid; i < 64 * 64; i += 256) {
    int r = i >> 6, c4 = (i & 63) << 2;
    int n = n0 + r;
    uint2 v = make_uint2(0, 0);
    if (n < N) v = *(const uint2*)&Xin[(size_t)n * 256 + c4];
    *(uint2*)&As[r][c4] = v;
  }
  __syncthreads();
  int wave = tid >> 6, lane = tid & 63;
  int mrow = wave * 16 + (lane & 15);
  int brow = lane & 15;
  int kgrp = (lane >> 4) * 8;
  s16x8 areg[8];
#pragma unroll
  for (int kk = 0; kk < 8; kk++) areg[kk] = *(const s16x8*)&As[mrow][kk * 32 + kgrp];
  int orow0 = wave * 16 + (lane >> 4) * 4;
  int ocol = lane & 15;
  for (int cb = 0; cb < 4; cb++) {
    __syncthreads();
    for (int i = tid; i < 64 * 64; i += 256) {
      int r = i >> 6, c4 = (i & 63) << 2;
      *(uint2*)&Bs[r][c4] = *(const uint2*)&Wt[(size_t)(cb * 64 + r) * 256 + c4];
    }
    __syncthreads();
    f32x4 acc[4];
#pragma unroll
    for (int i = 0; i < 4; i++) acc[i] = (f32x4){0.f, 0.f, 0.f, 0.f};
#pragma unroll
    for (int kk = 0; kk < 8; kk++) {
#pragma unroll
      for (int nf = 0; nf < 4; nf++) {
        s16x8 b = *(const s16x8*)&Bs[nf * 16 + brow][kk * 32 + kgrp];
        acc[nf] = __builtin_amdgcn_mfma_f32_16x16x32_bf16(areg[kk], b, acc[nf], 0, 0, 0);
      }
    }
#pragma unroll
    for (int nf = 0; nf < 4; nf++) {
#pragma unroll
      for (int r = 0; r < 4; r++) {
        int n = n0 + orow0 + r;
        if (n < N) Hout[(size_t)n * 256 + cb * 64 + nf * 16 + ocol] = (short)f2bf(acc[nf][r]);
      }
    }
  }
}

// ---------------- aggregate (wave per node, unroll-8) ----------------
#define AGG_STEP(p, v)                                                      \
  { float f = __int_as_float(p.y);                                          \
    a0 = fmaf(blo(v.x), f, a0); a1 = fmaf(bhi(v.x), f, a1);                 \
    a2 = fmaf(blo(v.y), f, a2); a3 = fmaf(bhi(v.y), f, a3); }

__global__ void __launch_bounds__(256) gcn_agg_kernel(
    const short* __restrict__ h, const int2* __restrict__ pk8,
    const int* __restrict__ rowstart, const float* __restrict__ dnorm,
    const float* __restrict__ b, const short* __restrict__ node_msg,
    short* __restrict__ xin, int N) {
  int lane = threadIdx.x & 63;
  int node = blockIdx.x * 4 + (threadIdx.x >> 6);
  if (node >= N) return;
  int ch0 = lane << 2;
  size_t rowb = (size_t)node * 256 + ch0;
  float dn = dnorm[node];
  float wgt = dn * dn;
  uint2 hv = *(const uint2*)&h[rowb];
  float a0 = blo(hv.x) * wgt, a1 = bhi(hv.x) * wgt;
  float a2 = blo(hv.y) * wgt, a3 = bhi(hv.y) * wgt;
  int s = rowstart[node], s1 = rowstart[node + 1];
  for (; s + 8 <= s1; s += 8) {
    int2 p0 = pk8[s],     p1 = pk8[s + 1], p2 = pk8[s + 2], p3 = pk8[s + 3];
    int2 p4 = pk8[s + 4], p5 = pk8[s + 5], p6 = pk8[s + 6], p7 = pk8[s + 7];
    uint2 v0 = *(const uint2*)&h[(size_t)p0.x * 256 + ch0];
    uint2 v1 = *(const uint2*)&h[(size_t)p1.x * 256 + ch0];
    uint2 v2 = *(const uint2*)&h[(size_t)p2.x * 256 + ch0];
    uint2 v3 = *(const uint2*)&h[(size_t)p3.x * 256 + ch0];
    uint2 v4 = *(const uint2*)&h[(size_t)p4.x * 256 + ch0];
    uint2 v5 = *(const uint2*)&h[(size_t)p5.x * 256 + ch0];
    uint2 v6 = *(const uint2*)&h[(size_t)p6.x * 256 + ch0];
    uint2 v7 = *(const uint2*)&h[(size_t)p7.x * 256 + ch0];
    AGG_STEP(p0, v0) AGG_STEP(p1, v1) AGG_STEP(p2, v2) AGG_STEP(p3, v3)
    AGG_STEP(p4, v4) AGG_STEP(p5, v5) AGG_STEP(p6, v6) AGG_STEP(p7, v7)
  }
  for (; s + 4 <= s1; s += 4) {
    int2 p0 = pk8[s], p1 = pk8[s + 1], p2 = pk8[s + 2], p3 = pk8[s + 3];
    uint2 v0 = *(const uint2*)&h[(size_t)p0.x * 256 + ch0];
    uint2 v1 = *(const uint2*)&h[(size_t)p1.x * 256 + ch0];
    uint2 v2 = *(const uint2*)&h[(size_t)p2.x * 256 + ch0];
    uint2 v3 = *(const uint2*)&h[(size_t)p3.x * 256 + ch0];
    AGG_STEP(p0, v0) AGG_STEP(p1, v1) AGG_STEP(p2, v2) AGG_STEP(p3, v3)
  }
  for (; s < s1; s++) {
    int2 p = pk8[s];
    uint2 v = *(const uint2*)&h[(size_t)p.x * 256 + ch0];
    AGG_STEP(p, v)
  }
  float4 bv = *(const float4*)&b[ch0];
  uint2 mv = *(const uint2*)&node_msg[rowb];
  float y0 = fmaxf(a0 + bv.x, 0.f) + blo(mv.x);
  float y1 = fmaxf(a1 + bv.y, 0.f) + bhi(mv.x);
  float y2 = fmaxf(a2 + bv.z, 0.f) + blo(mv.y);
  float y3 = fmaxf(a3 + bv.w, 0.f) + bhi(mv.y);
  uint2 o;
  o.x = pk2(y0, y1);
  o.y = pk2(y2, y3);
  *(uint2*)&xin[rowb] = o;
}

// ---------------- final aggregate -> x_emb bf16 + scores (unroll-8) --------
__global__ void __launch_bounds__(256) final_agg_kernel(
    const short* __restrict__ h, const int2* __restrict__ pk8,
    const int* __restrict__ rowstart, const float* __restrict__ dnorm,
    const float* __restrict__ b, short* __restrict__ x_emb,
    const float* __restrict__ attn_w, const float* __restrict__ attn_b,
    float* __restrict__ scores, int N) {
  int lane = threadIdx.x & 63;
  int node = blockIdx.x * 4 + (threadIdx.x >> 6);
  if (node >= N) return;
  int ch0 = lane << 2;
  size_t rowb = (size_t)node * 256 + ch0;
  float dn = dnorm[node];
  float wgt = dn * dn;
  uint2 hv = *(const uint2*)&h[rowb];
  float a0 = blo(hv.x) * wgt, a1 = bhi(hv.x) * wgt;
  float a2 = blo(hv.y) * wgt, a3 = bhi(hv.y) * wgt;
  int s = rowstart[node], s1 = rowstart[node + 1];
  for (; s + 8 <= s1; s += 8) {
    int2 p0 = pk8[s],     p1 = pk8[s + 1], p2 = pk8[s + 2], p3 = pk8[s + 3];
    int2 p4 = pk8[s + 4], p5 = pk8[s + 5], p6 = pk8[s + 6], p7 = pk8[s + 7];
    uint2 v0 = *(const uint2*)&h[(size_t)p0.x * 256 + ch0];
    uint2 v1 = *(const uint2*)&h[(size_t)p1.x * 256 + ch0];
    uint2 v2 = *(const uint2*)&h[(size_t)p2.x * 256 + ch0];
    uint2 v3 = *(const uint2*)&h[(size_t)p3.x * 256 + ch0];
    uint2 v4 = *(const uint2*)&h[(size_t)p4.x * 256 + ch0];
    uint2 v5 = *(const uint2*)&h[(size_t)p5.x * 256 + ch0];
    uint2 v6 = *(const uint2*)&h[(size_t)p6.x * 256 + ch0];
    uint2 v7 = *(const uint2*)&h[(size_t)p7.x * 256 + ch0];
    AGG_STEP(p0, v0) AGG_STEP(p1, v1) AGG_STEP(p2, v2) AGG_STEP(p3, v3)
    AGG_STEP(p4, v4) AGG_STEP(p5, v5) AGG_STEP(p6, v6) AGG_STEP(p7, v7)
  }
  for (; s + 4 <= s1; s += 4) {
    int2 p0 = pk8[s], p1 = pk8[s + 1], p2 = pk8[s + 2], p3 = pk8[s + 3];
    uint2 v0 = *(const uint2*)&h[(size_t)p0.x * 256 + ch0];
    uint2 v1 = *(const uint2*)&h[(size_t)p1.x * 256 + ch0];
    uint2 v2 = *(const uint2*)&h[(size_t)p2.x * 256 + ch0];
    uint2 v3 = *(const uint2*)&h[(size_t)p3.x * 256 + ch0];
    AGG_STEP(p0, v0) AGG_STEP(p1, v1) AGG_STEP(p2, v2) AGG_STEP(p3, v3)
  }
  for (; s < s1; s++) {
    int2 p = pk8[s];
    uint2 v = *(const uint2*)&h[(size_t)p.x * 256 + ch0];
    AGG_STEP(p, v)
  }
  float4 bv = *(const float4*)&b[ch0];
  a0 += bv.x; a1 += bv.y; a2 += bv.z; a3 += bv.w;
  uint2 o;
  o.x = pk2(a0, a1);
  o.y = pk2(a2, a3);
  *(uint2*)&x_emb[rowb] = o;
  float4 aw = *(const float4*)&attn_w[ch0];
  float p = a0 * aw.x + a1 * aw.y + a2 * aw.z + a3 * aw.w;
#pragma unroll
  for (int off = 32; off; off >>= 1) p += __shfl_down(p, off);
  if (lane == 0) scores[node] = p + attn_b[0];
}
#undef AGG_STEP

// ---------------- softmax + pool + head ----------------
__global__ void softmax_kernel(const float* __restrict__ scores, const int* __restrict__ gs,
                               const int* __restrict__ ge, float* __restrict__ wnode) {
  int g = blockIdx.x;
  int tid = threadIdx.x;  // 256
  __shared__ float red[256];
  int s0 = gs[g], e1 = ge[g];
  if (s0 > e1) return;
  int s1 = e1 + 1;
  float m = -1e30f;
  for (int i = s0 + tid; i < s1; i += 256) m = fmaxf(m, scores[i]);
  red[tid] = m;
  __syncthreads();
  for (int off = 128; off; off >>= 1) {
    if (tid < off) red[tid] = fmaxf(red[tid], red[tid + off]);
    __syncthreads();
  }
  m = red[0];
  __syncthreads();
  float d = 0.f;
  for (int i = s0 + tid; i < s1; i += 256) d += expf(scores[i] - m);
  red[tid] = d;
  __syncthreads();
  for (int off = 128; off; off >>= 1) {
    if (tid < off) red[tid] += red[tid + off];
    __syncthreads();
  }
  float rd = 1.f / red[0];
  for (int i = s0 + tid; i < s1; i += 256) wnode[i] = expf(scores[i] - m) * rd;
}

__global__ void __launch_bounds__(256) pool_sum_kernel(
    const short* __restrict__ x_emb, const float* __restrict__ wnode,
    const int* __restrict__ batch, float* __restrict__ graph_emb, int N) {
  __shared__ int sb[256];
  __shared__ float sw[256];
  int ch = threadIdx.x;
  int i0 = blockIdx.x * 256;
  int lim = min(256, N - i0);
  if (ch < lim) { sb[ch] = batch[i0 + ch]; sw[ch] = wnode[i0 + ch]; }
  __syncthreads();
  int curg = sb[0];
  float acc = 0.f;
  for (int j = 0; j < lim; j++) {
    int g = sb[j];
    if (g != curg) {
      atomicAdd(&graph_emb[(size_t)curg * 256 + ch], acc);
      acc = 0.f;
      curg = g;
    }
    acc = fmaf(bf2f((unsigned short)x_emb[(size_t)(i0 + j) * 256 + ch]), sw[j], acc);
  }
  atomicAdd(&graph_emb[(size_t)curg * 256 + ch], acc);
}

__global__ void head_kernel(const float* __restrict__ global_x, const float* __restrict__ graph_emb,
                            const float* __restrict__ W1, const float* __restrict__ b1,
                            const float* __restrict__ W2, const float* __restrict__ b2,
                            const float* __restrict__ fW1, const float* __restrict__ fb1,
                            const float* __restrict__ fW2, const float* __restrict__ fb2,
                            float* __restrict__ out) {
  int g = blockIdx.x;
  int ch = threadIdx.x;  // 256
  __shared__ float t1[256], g2s[256], t3s[256];
  float a = b1[ch];
  const float* gx = global_x + g * 16;
#pragma unroll
  for (int k = 0; k < 16; k++) a = fmaf(gx[k], W1[k * 256 + ch], a);
  t1[ch] = fmaxf(a, 0.f);
  __syncthreads();
  float bb = b2[ch];
  for (int k = 0; k < 256; k++) bb = fmaf(t1[k], W2[k * 256 + ch], bb);
  g2s[ch] = bb;
  __syncthreads();
  float c = fb1[ch];
  const float* ger = graph_emb + (size_t)g * 256;
  for (int k = 0; k < 256; k++) c = fmaf(ger[k], fW1[k * 256 + ch], c);
  for (int k = 0; k < 256; k++) c = fmaf(g2s[k], fW1[(256 + k) * 256 + ch], c);
  t3s[ch] = fmaxf(c, 0.f);
  __syncthreads();
  t1[ch] = t3s[ch] * fW2[ch];
  __syncthreads();
  for (int off = 128; off; off >>= 1) {
    if (ch < off) t1[ch] += t1[ch + off];
    __syncthreads();
  }
  if (ch == 0) out[g] = t1[0] + fb2[0];
}

// ---------------- launch ----------------
extern "C" void kernel_launch(void* const* d_in, const int* in_sizes, int n_in,
                              void* d_out, int out_size, void* d_ws, size_t ws_size,
                              hipStream_t stream) {
  const float* x        = (const float*)d_in[0];
  const int*   ei       = (const int*)d_in[1];
  const int*   batch    = (const int*)d_in[2];
  const float* edge_attr= (const float*)d_in[3];
  const float* global_x = (const float*)d_in[4];
  const float* coord_W  = (const float*)d_in[5];
  const float* coord_b  = (const float*)d_in[6];
  const float* node_W   = (const float*)d_in[7];
  const float* node_b   = (const float*)d_in[8];
  const float* edge_W   = (const float*)d_in[9];
  const float* edge_b   = (const float*)d_in[10];
  const float* proj_W   = (const float*)d_in[11];
  const float* proj_b   = (const float*)d_in[12];
  const float* gcn_W    = (const float*)d_in[13];
  const float* gcn_b    = (const float*)d_in[14];
  const float* attn_w   = (const float*)d_in[15];
  const float* attn_b   = (const float*)d_in[16];
  const float* gmlp_W1  = (const float*)d_in[17];
  const float* gmlp_b1  = (const float*)d_in[18];
  const float* gmlp_W2  = (const float*)d_in[19];
  const float* gmlp_b2  = (const float*)d_in[20];
  const float* fc_W1    = (const float*)d_in[21];
  const float* fc_b1    = (const float*)d_in[22];
  const float* fc_W2    = (const float*)d_in[23];
  const float* fc_b2    = (const float*)d_in[24];

  const int N = in_sizes[0] / 9;
  const int E = in_sizes[3] / 8;
  const int G = in_sizes[4] / 16;
  const int NB = (N + 255) / 256;
  const int NM = (N + 63) / 64;

  char* w = (char*)d_ws;
  auto alloc = [&](size_t bytes) -> char* {
    char* p = w;
    w += (bytes + 255) & ~(size_t)255;
    return p;
  };
  short* node_msg = (short*)alloc((size_t)N * 256 * 2);
  short* hA       = (short*)alloc((size_t)N * 256 * 2);
  short* hB       = (short*)alloc((size_t)N * 256 * 2);
  short* xinBuf   = (short*)alloc((size_t)N * 256 * 2);
  short* x_emb    = (short*)alloc((size_t)N * 256 * 2);
  short* msg128   = x_emb;   // disjoint lifetime: msg128 consumed before x_emb written
  int2*  pk8      = (int2*)alloc((size_t)E * 8);
  int*   eids     = (int*)alloc((size_t)E * 4);
  short* gcnWt    = (short*)alloc((size_t)3 * 65536 * 2);
  short* projWt   = (short*)alloc((size_t)256 * 128 * 2);
  int*   cnt      = (int*)alloc((size_t)N * 4);
  int*   rowstart = (int*)alloc((size_t)(N + 1) * 4);
  int*   cursor   = (int*)alloc((size_t)N * 4);
  float* dnorm    = (float*)alloc((size_t)N * 4);
  float* scores   = (float*)alloc((size_t)N * 4);
  float* wnode    = (float*)alloc((size_t)N * 4);
  int*   partials = (int*)alloc((size_t)NB * 4);
  int*   gs       = (int*)alloc((size_t)G * 4);
  int*   ge       = (int*)alloc((size_t)G * 4);
  float* graph_emb= (float*)alloc((size_t)G * 256 * 4);

  hipMemsetAsync(cnt, 0, (size_t)N * 4, stream);
  hipMemsetAsync(gs, 0x7f, (size_t)G * 4, stream);
  hipMemsetAsync(ge, 0xff, (size_t)G * 4, stream);
  hipMemsetAsync(graph_emb, 0, (size_t)G * 256 * 4, stream);

  wt_kernel<<<(3 * 65536 + 256 * 128 + 255) / 256, 256, 0, stream>>>(gcn_W, proj_W, gcnWt, projWt);
  count_kernel<<<(E + 255) / 256, 256, 0, stream>>>(ei + E, cnt, E);
  breduce_kernel<<<NB, 256, 0, stream>>>(cnt, partials, N);
  scan_partials_kernel<<<1, 256, 0, stream>>>(partials, NB);
  scan_apply_kernel<<<NB, 256, 0, stream>>>(cnt, partials, rowstart, dnorm, cursor,
                                            batch, gs, ge, N);
  scatter_kernel<<<(E + 255) / 256, 256, 0, stream>>>(
      ei, ei + E, rowstart, cursor, dnorm, pk8, eids, E);
  edge_msg_kernel<<<(N + 3) / 4, 256, 0, stream>>>(
      edge_attr, eids, rowstart, edge_W, edge_b, (unsigned*)msg128, N);
  proj_gemm_mfma<<<NM, 256, 0, stream>>>(
      msg128, projWt, proj_b, cnt, node_msg, N);
  gcn_gemm_embed_mfma<<<NM, 256, 0, stream>>>(
      x, coord_W, coord_b, node_W, node_b, node_msg, gcnWt, hA, N);
  // layer 1: agg(hA) -> xin ; gemm(xin, W1) -> hB
  gcn_agg_kernel<<<(N + 3) / 4, 256, 0, stream>>>(
      hA, pk8, rowstart, dnorm, gcn_b, node_msg, xinBuf, N);
  gcn_gemm_mfma<<<NM, 256, 0, stream>>>(
      xinBuf, gcnWt + 65536, hB, N);
  // layer 2: agg(hB) -> xin ; gemm(xin, W2) -> hA
  gcn_agg_kernel<<<(N + 3) / 4, 256, 0, stream>>>(
      hB, pk8, rowstart, dnorm, gcn_b + 256, node_msg, xinBuf, N);
  gcn_gemm_mfma<<<NM, 256, 0, stream>>>(
      xinBuf, gcnWt + 2 * 65536, hA, N);
  final_agg_kernel<<<(N + 3) / 4, 256, 0, stream>>>(
      hA, pk8, rowstart, dnorm, gcn_b + 512, x_emb, attn_w, attn_b, scores, N);
  softmax_kernel<<<G, 256, 0, stream>>>(scores, gs, ge, wnode);
  pool_sum_kernel<<<NB, 256, 0, stream>>>(x_emb, wnode, batch, graph_emb, N);
  head_kernel<<<G, 256, 0, stream>>>(global_x, graph_emb, gmlp_W1, gmlp_b1, gmlp_W2, gmlp_b2,
                                     fc_W1, fc_b1, fc_W2, fc_b2, (float*)d_out);
}